// Round 6
// baseline (1099.405 us; speedup 1.0000x reference)
//
#include <hip/hip_runtime.h>
#include <hip/hip_bf16.h>
#include <stdint.h>

#define B_  32
#define E_  512
#define WN  2048
#define D_  1024

typedef __attribute__((ext_vector_type(8))) short short8;
typedef __attribute__((ext_vector_type(4))) float f32x4;

__device__ int g_mask_is_int;   // 1 if mask buffer is int32 per element, 0 if uint8

__device__ __forceinline__ unsigned short f2bf(float f) {
  unsigned int u = __float_as_uint(f);
  u += 0x7fffu + ((u >> 16) & 1u);   // round-to-nearest-even
  return (unsigned short)(u >> 16);
}
__device__ __forceinline__ float bf2f(unsigned short s) {
  return __uint_as_float(((unsigned int)s) << 16);
}
__device__ __forceinline__ float ftanh(float x) {
  float e = __expf(2.0f * x);
  return 1.0f - 2.0f / (e + 1.0f);
}
// XOR-swizzled byte offset within a [rows][128B] LDS plane
__device__ __forceinline__ int swz(int row, int kb) {
  return row * 128 + (kb ^ ((row & 7) << 4));
}
// XOR-swizzled byte offset within a [rows][64B] LDS plane (full 7-bit XOR:
// rows 0..7 at fixed chunk land in 8 distinct 16B slots of the 128B period)
__device__ __forceinline__ int swz64(int row, int kb) {
  return (row * 64 + kb) ^ ((row & 7) << 4);
}
__device__ __forceinline__ uint4 pack8(unsigned short a0, unsigned short a1,
                                       unsigned short a2, unsigned short a3,
                                       unsigned short a4, unsigned short a5,
                                       unsigned short a6, unsigned short a7) {
  uint4 v;
  v.x = (unsigned int)a0 | ((unsigned int)a1 << 16);
  v.y = (unsigned int)a2 | ((unsigned int)a3 << 16);
  v.z = (unsigned int)a4 | ((unsigned int)a5 << 16);
  v.w = (unsigned int)a6 | ((unsigned int)a7 << 16);
  return v;
}

// ---------------------------------------------------------------------------
// K0: detect mask dtype. int32 0/1 data => bytes at offset %4 != 0 are all 0.
// ---------------------------------------------------------------------------
__global__ void k_detect(const unsigned char* __restrict__ m) {
  if (threadIdx.x == 0) {
    int nz = 0;
    for (int i = 0; i < 1024; ++i)
      if ((i & 3) && m[i]) nz++;
    g_mask_is_int = (nz == 0) ? 1 : 0;
  }
}

// ===========================================================================
// FAST PATH
// ===========================================================================

// ---------------------------------------------------------------------------
// k_proj_mfma: proj = tanh(ems @ W^T + bias), split-bf16 3-term MFMA.
// (unchanged, verified)
// ---------------------------------------------------------------------------
__global__ __launch_bounds__(256, 2) void k_proj_mfma(
    const float* __restrict__ A, const float* __restrict__ W,
    const float* __restrict__ bias,
    unsigned short* __restrict__ outHi, unsigned short* __restrict__ outLo) {
  __shared__ unsigned short lds[32768];  // 64KB: Ahi|Alo|Bhi|Blo planes 16KB each
  char* const ldsb = (char*)lds;
  char* const pAhi = ldsb;
  char* const pAlo = ldsb + 16384;
  char* const pBhi = ldsb + 32768;
  char* const pBlo = ldsb + 49152;
  const int t = threadIdx.x, l = t & 63, wave = t >> 6;
  const int wm = (wave >> 1) * 64, wn = (wave & 1) * 64;
  const int m0 = blockIdx.x * 128, n0 = blockIdx.y * 128;
  const int r = t >> 1, h = t & 1;

  f32x4 acc[4][4];
#pragma unroll
  for (int i = 0; i < 4; ++i)
#pragma unroll
    for (int j = 0; j < 4; ++j) acc[i][j] = (f32x4){0.f, 0.f, 0.f, 0.f};

  f32x4 ar[8], br[8];

  auto load_stage = [&](int s) {
    const float* as = A + (size_t)(m0 + r) * 1024 + s * 64 + h * 32;
    const float* bs = W + (size_t)(n0 + r) * 1024 + s * 64 + h * 32;
#pragma unroll
    for (int i = 0; i < 8; ++i) {
      ar[i] = *(const f32x4*)(as + i * 4);
      br[i] = *(const f32x4*)(bs + i * 4);
    }
  };

  auto write_stage = [&]() {
    unsigned short hA[32], lA[32], hB[32], lB[32];
#pragma unroll
    for (int i = 0; i < 8; ++i)
#pragma unroll
      for (int j = 0; j < 4; ++j) {
        float x = ar[i][j];
        unsigned short hh = f2bf(x);
        hA[i * 4 + j] = hh;
        lA[i * 4 + j] = f2bf(x - bf2f(hh));
        float y = br[i][j];
        unsigned short hb = f2bf(y);
        hB[i * 4 + j] = hb;
        lB[i * 4 + j] = f2bf(y - bf2f(hb));
      }
#pragma unroll
    for (int i = 0; i < 4; ++i) {
      const int kb = h * 64 + i * 16;
      const int o = swz(r, kb);
      *(uint4*)(pAhi + o) = pack8(hA[i*8+0],hA[i*8+1],hA[i*8+2],hA[i*8+3],hA[i*8+4],hA[i*8+5],hA[i*8+6],hA[i*8+7]);
      *(uint4*)(pAlo + o) = pack8(lA[i*8+0],lA[i*8+1],lA[i*8+2],lA[i*8+3],lA[i*8+4],lA[i*8+5],lA[i*8+6],lA[i*8+7]);
      *(uint4*)(pBhi + o) = pack8(hB[i*8+0],hB[i*8+1],hB[i*8+2],hB[i*8+3],hB[i*8+4],hB[i*8+5],hB[i*8+6],hB[i*8+7]);
      *(uint4*)(pBlo + o) = pack8(lB[i*8+0],lB[i*8+1],lB[i*8+2],lB[i*8+3],lB[i*8+4],lB[i*8+5],lB[i*8+6],lB[i*8+7]);
    }
  };

  auto compute_stage = [&]() {
#pragma unroll
    for (int ks = 0; ks < 2; ++ks) {
      short8 ah[4], al[4], bh[4], bl[4];
      const int kb = ks * 64 + (l >> 4) * 16;
#pragma unroll
      for (int f = 0; f < 4; ++f) {
        const int oa = swz(wm + f * 16 + (l & 15), kb);
        ah[f] = *(const short8*)(pAhi + oa);
        al[f] = *(const short8*)(pAlo + oa);
        const int ob = swz(wn + f * 16 + (l & 15), kb);
        bh[f] = *(const short8*)(pBhi + ob);
        bl[f] = *(const short8*)(pBlo + ob);
      }
#pragma unroll
      for (int fm = 0; fm < 4; ++fm)
#pragma unroll
        for (int fn = 0; fn < 4; ++fn) {
          acc[fm][fn] = __builtin_amdgcn_mfma_f32_16x16x32_bf16(ah[fm], bh[fn], acc[fm][fn], 0, 0, 0);
          acc[fm][fn] = __builtin_amdgcn_mfma_f32_16x16x32_bf16(al[fm], bh[fn], acc[fm][fn], 0, 0, 0);
          acc[fm][fn] = __builtin_amdgcn_mfma_f32_16x16x32_bf16(ah[fm], bl[fn], acc[fm][fn], 0, 0, 0);
        }
    }
  };

  load_stage(0);
  write_stage();
  __syncthreads();
  for (int s = 0; s < 15; ++s) {
    load_stage(s + 1);
    compute_stage();
    __syncthreads();
    write_stage();
    __syncthreads();
  }
  compute_stage();

  float bcol[4];
#pragma unroll
  for (int fn = 0; fn < 4; ++fn) bcol[fn] = bias[n0 + wn + fn * 16 + (l & 15)];
#pragma unroll
  for (int fm = 0; fm < 4; ++fm)
#pragma unroll
    for (int fn = 0; fn < 4; ++fn)
#pragma unroll
      for (int q = 0; q < 4; ++q)
        acc[fm][fn][q] = ftanh(acc[fm][fn][q] + bcol[fn]);

  unsigned short* ldsT = lds;  // reused as [128][136]
  const int rr = t >> 1, ch = (t & 1) * 64;
  __syncthreads();
#pragma unroll
  for (int fm = 0; fm < 4; ++fm)
#pragma unroll
    for (int fn = 0; fn < 4; ++fn)
#pragma unroll
      for (int q = 0; q < 4; ++q) {
        const int rl = wm + fm * 16 + (l >> 4) * 4 + q;
        const int cl = wn + fn * 16 + (l & 15);
        ldsT[rl * 136 + cl] = f2bf(acc[fm][fn][q]);
      }
  __syncthreads();
#pragma unroll
  for (int i = 0; i < 8; ++i) {
    uint4 v = *(const uint4*)(ldsT + rr * 136 + ch + i * 8);
    *(uint4*)(outHi + (size_t)(m0 + rr) * 1024 + n0 + ch + i * 8) = v;
  }
  __syncthreads();
#pragma unroll
  for (int fm = 0; fm < 4; ++fm)
#pragma unroll
    for (int fn = 0; fn < 4; ++fn)
#pragma unroll
      for (int q = 0; q < 4; ++q) {
        const int rl = wm + fm * 16 + (l >> 4) * 4 + q;
        const int cl = wn + fn * 16 + (l & 15);
        const float x = acc[fm][fn][q];
        const unsigned short hh = f2bf(x);
        ldsT[rl * 136 + cl] = f2bf(x - bf2f(hh));
      }
  __syncthreads();
#pragma unroll
  for (int i = 0; i < 8; ++i) {
    uint4 v = *(const uint4*)(ldsT + rr * 136 + ch + i * 8);
    *(uint4*)(outLo + (size_t)(m0 + rr) * 1024 + n0 + ch + i * 8) = v;
  }
}

// ---------------------------------------------------------------------------
// k_scores_mfma: scores = proj @ words^T (split-bf16 3-term), f32 -> ws.
// v2: BM=512 (all E rows) x BN=128, BK=32, 512 thr / 8 waves (4m x 2n).
// LDS 80KB: Ahi|Alo [512][64B] + Bhi|Blo [128][64B], swz64 XOR swizzle.
// Grid 512 = 32 b x 16 n-tiles, XCD-pinned (b -> XCD b%8): proj[b] planes
// (2 MB) L2-resident; words tile split ONCE per (b,n0) (was 4x).
// ---------------------------------------------------------------------------
__global__ __launch_bounds__(512, 2) void k_scores_mfma(
    const unsigned short* __restrict__ pHi, const unsigned short* __restrict__ pLo,
    const float* __restrict__ words, float* __restrict__ sc) {
  __shared__ uint4 lds4[5120];   // 80 KB
  char* const pAhi = (char*)lds4;            // 32 KB: [512 rows][64B]
  char* const pAlo = (char*)lds4 + 32768;    // 32 KB
  char* const pBhi = (char*)lds4 + 65536;    //  8 KB: [128 rows][64B]
  char* const pBlo = (char*)lds4 + 73728;    //  8 KB

  const int g = blockIdx.x;
  const int xcd = g & 7;
  const int slot = g >> 3;              // 0..63
  const int b = xcd + 8 * (slot >> 4);  // bijective, b's 16 blocks on XCD b%8
  const int n0 = (slot & 15) * 128;

  const int t = threadIdx.x, l = t & 63, wv = t >> 6;
  const int wm4 = wv >> 1;    // 0..3 -> m base = wm4*128
  const int wn2 = wv & 1;     // 0..1 -> n base = wn2*64

  f32x4 acc[8][4];
#pragma unroll
  for (int i = 0; i < 8; ++i)
#pragma unroll
    for (int j = 0; j < 4; ++j) acc[i][j] = (f32x4){0.f, 0.f, 0.f, 0.f};

  uint4 avh[4], avl[4];       // A row t: 64B per plane
  f32x4 br0, br1;             // B: 8 f32 of words row (t&127)

  const int bn = t & 127;        // B n-row
  const int kc8 = (t >> 7) * 8;  // B k-chunk base (0,8,16,24)

  auto load_stage = [&](int s) {
    const unsigned short* ah_ = pHi + (size_t)(b * 512 + t) * 1024 + s * 32;
    const unsigned short* al_ = pLo + (size_t)(b * 512 + t) * 1024 + s * 32;
#pragma unroll
    for (int i = 0; i < 4; ++i) {
      avh[i] = ((const uint4*)ah_)[i];
      avl[i] = ((const uint4*)al_)[i];
    }
    const float* bs = words + (size_t)b * WN * D_ + (size_t)(n0 + bn) * 1024 + s * 32 + kc8;
    br0 = *(const f32x4*)(bs);
    br1 = *(const f32x4*)(bs + 4);
  };

  auto write_stage = [&]() {
#pragma unroll
    for (int c = 0; c < 4; ++c) {
      const int o = swz64(t, c * 16);
      *(uint4*)(pAhi + o) = avh[c];
      *(uint4*)(pAlo + o) = avl[c];
    }
    unsigned short hB[8], lB[8];
#pragma unroll
    for (int j = 0; j < 4; ++j) {
      float y0 = br0[j];
      unsigned short h0 = f2bf(y0);
      hB[j] = h0;
      lB[j] = f2bf(y0 - bf2f(h0));
      float y1 = br1[j];
      unsigned short h1 = f2bf(y1);
      hB[4 + j] = h1;
      lB[4 + j] = f2bf(y1 - bf2f(h1));
    }
    const int o = swz64(bn, kc8 * 2);
    *(uint4*)(pBhi + o) = pack8(hB[0], hB[1], hB[2], hB[3], hB[4], hB[5], hB[6], hB[7]);
    *(uint4*)(pBlo + o) = pack8(lB[0], lB[1], lB[2], lB[3], lB[4], lB[5], lB[6], lB[7]);
  };

  auto compute_stage = [&]() {
    const int kb = (l >> 4) * 16;
    short8 bh[4], bl[4];
#pragma unroll
    for (int f = 0; f < 4; ++f) {
      const int o = swz64(wn2 * 64 + f * 16 + (l & 15), kb);
      bh[f] = *(const short8*)(pBhi + o);
      bl[f] = *(const short8*)(pBlo + o);
    }
#pragma unroll
    for (int fm = 0; fm < 8; ++fm) {
      const int o = swz64(wm4 * 128 + fm * 16 + (l & 15), kb);
      const short8 ah = *(const short8*)(pAhi + o);
      const short8 al = *(const short8*)(pAlo + o);
#pragma unroll
      for (int fn = 0; fn < 4; ++fn) {
        acc[fm][fn] = __builtin_amdgcn_mfma_f32_16x16x32_bf16(ah, bh[fn], acc[fm][fn], 0, 0, 0);
        acc[fm][fn] = __builtin_amdgcn_mfma_f32_16x16x32_bf16(al, bh[fn], acc[fm][fn], 0, 0, 0);
        acc[fm][fn] = __builtin_amdgcn_mfma_f32_16x16x32_bf16(ah, bl[fn], acc[fm][fn], 0, 0, 0);
      }
    }
  };

  load_stage(0);
  write_stage();
  __syncthreads();
  for (int s = 0; s < 31; ++s) {
    load_stage(s + 1);
    compute_stage();
    __syncthreads();
    write_stage();
    __syncthreads();
  }
  compute_stage();

  // store f32 scores
#pragma unroll
  for (int fm = 0; fm < 8; ++fm)
#pragma unroll
    for (int fn = 0; fn < 4; ++fn)
#pragma unroll
      for (int q = 0; q < 4; ++q) {
        const int rl = wm4 * 128 + fm * 16 + (l >> 4) * 4 + q;
        const int cl = n0 + wn2 * 64 + fn * 16 + (l & 15);
        sc[((size_t)b * 512 + rl) * 2048 + cl] = acc[fm][fn][q];
      }
}

// ---------------------------------------------------------------------------
// k_softmax: unchanged (verified).
// ---------------------------------------------------------------------------
__global__ __launch_bounds__(256) void k_softmax(float* __restrict__ ws,
                                                 const void* __restrict__ mask) {
  __shared__ float red[8];
  const int row = blockIdx.x;
  const int t = threadIdx.x;
  const int wave = t >> 6;
  float* rp = ws + (size_t)row * 2048;
  float v[8];
  {
    f32x4 v0 = *(const f32x4*)(rp + t * 8);
    f32x4 v1 = *(const f32x4*)(rp + t * 8 + 4);
#pragma unroll
    for (int i = 0; i < 4; ++i) { v[i] = v0[i]; v[4 + i] = v1[i]; }
  }
  if (g_mask_is_int) {
    const int* mp = (const int*)mask + (size_t)row * 2048 + t * 8;
    const int4 m0 = *(const int4*)mp;
    const int4 m1 = *(const int4*)(mp + 4);
    if (m0.x) v[0] = -INFINITY;
    if (m0.y) v[1] = -INFINITY;
    if (m0.z) v[2] = -INFINITY;
    if (m0.w) v[3] = -INFINITY;
    if (m1.x) v[4] = -INFINITY;
    if (m1.y) v[5] = -INFINITY;
    if (m1.z) v[6] = -INFINITY;
    if (m1.w) v[7] = -INFINITY;
  } else {
    const unsigned char* mp = (const unsigned char*)mask + (size_t)row * 2048 + t * 8;
    const uchar4 m0 = *(const uchar4*)mp;
    const uchar4 m1 = *(const uchar4*)(mp + 4);
    if (m0.x) v[0] = -INFINITY;
    if (m0.y) v[1] = -INFINITY;
    if (m0.z) v[2] = -INFINITY;
    if (m0.w) v[3] = -INFINITY;
    if (m1.x) v[4] = -INFINITY;
    if (m1.y) v[5] = -INFINITY;
    if (m1.z) v[6] = -INFINITY;
    if (m1.w) v[7] = -INFINITY;
  }
  float mx = v[0];
#pragma unroll
  for (int i = 1; i < 8; ++i) mx = fmaxf(mx, v[i]);
#pragma unroll
  for (int off = 32; off > 0; off >>= 1) mx = fmaxf(mx, __shfl_xor(mx, off));
  if ((t & 63) == 0) red[wave] = mx;
  __syncthreads();
  mx = fmaxf(fmaxf(red[0], red[1]), fmaxf(red[2], red[3]));
  float e[8];
  float sum = 0.0f;
#pragma unroll
  for (int i = 0; i < 8; ++i) {
    e[i] = __expf(v[i] - mx);
    sum += e[i];
  }
#pragma unroll
  for (int off = 32; off > 0; off >>= 1) sum += __shfl_xor(sum, off);
  if ((t & 63) == 0) red[4 + wave] = sum;
  __syncthreads();
  const float tot = (red[4] + red[5]) + (red[6] + red[7]);
  const float rinv = 1.0f / tot;
  unsigned short* op = (unsigned short*)rp;
  ushort4 o0, o1;
  o0.x = f2bf(e[0] * rinv); o0.y = f2bf(e[1] * rinv);
  o0.z = f2bf(e[2] * rinv); o0.w = f2bf(e[3] * rinv);
  o1.x = f2bf(e[4] * rinv); o1.y = f2bf(e[5] * rinv);
  o1.z = f2bf(e[6] * rinv); o1.w = f2bf(e[7] * rinv);
  *(ushort4*)(op + t * 8) = o0;
  *(ushort4*)(op + t * 8 + 4) = o1;
}

// ---------------------------------------------------------------------------
// k_pv: unchanged (verified round 5).
// ---------------------------------------------------------------------------
__global__ __launch_bounds__(512, 2) void k_pv(
    const unsigned short* __restrict__ att, const float* __restrict__ words,
    float* __restrict__ out) {
  __shared__ uint4 lds4[5120];            // 80 KB: A 64KB | B 16KB
  char* const pA = (char*)lds4;
  char* const pB = (char*)lds4 + 65536;

  const int g = blockIdx.x;
  const int b = (g & 7) + 8 * (g >> 6);   // XCD-pinned batch
  const int wt = (g >> 3) & 7;
  const int w0 = wt * 128;

  const int t = threadIdx.x, l = t & 63, wv = t >> 6;
  const int wm4 = wv >> 1;
  const int wn2 = wv & 1;

  f32x4 acc[8][4];
#pragma unroll
  for (int i = 0; i < 8; ++i)
#pragma unroll
    for (int j = 0; j < 4; ++j) acc[i][j] = (f32x4){0.f, 0.f, 0.f, 0.f};

  uint4 avA[8];
  f32x4 bv0a, bv0b, bv1a, bv1b;

  const int np2 = (t & 31) * 2;
  const int wc = (t >> 5) * 8;

  auto load_stage = [&](int s) {
    const unsigned short* ab =
        att + ((size_t)(b * 512) + (t >> 3)) * 4096 + s * 64 + (t & 7) * 8;
#pragma unroll
    for (int i = 0; i < 8; ++i)
      avA[i] = *(const uint4*)(ab + (size_t)i * 64 * 4096);
    const float* wp = words + (size_t)b * WN * D_ +
                      (size_t)(s * 64 + np2) * 1024 + w0 + wc;
    bv0a = *(const f32x4*)(wp);
    bv0b = *(const f32x4*)(wp + 4);
    bv1a = *(const f32x4*)(wp + 1024);
    bv1b = *(const f32x4*)(wp + 1028);
  };

  auto write_stage = [&]() {
#pragma unroll
    for (int i = 0; i < 8; ++i) {
      const int row = (t >> 3) + i * 64;
      *(uint4*)(pA + row * 128 + (((t & 7) * 16) ^ ((row & 7) << 4))) = avA[i];
    }
#pragma unroll
    for (int i = 0; i < 8; ++i) {
      const int w = wc + i;
      const float x0 = (i < 4) ? bv0a[i & 3] : bv0b[i & 3];
      const float x1 = (i < 4) ? bv1a[i & 3] : bv1b[i & 3];
      const unsigned int pk =
          (unsigned int)f2bf(x0) | ((unsigned int)f2bf(x1) << 16);
      *(unsigned int*)(pB + w * 128 + ((np2 * 2) ^ ((w & 7) << 4))) = pk;
    }
  };

  auto compute_stage = [&]() {
#pragma unroll
    for (int ks = 0; ks < 2; ++ks) {
      short8 a[8];
      const int kb = ks * 64 + (l >> 4) * 16;
#pragma unroll
      for (int f = 0; f < 8; ++f) {
        const int row = wm4 * 128 + f * 16 + (l & 15);
        a[f] = *(const short8*)(pA + swz(row, kb));
      }
      short8 bb[4];
#pragma unroll
      for (int f = 0; f < 4; ++f) {
        const int row = wn2 * 64 + f * 16 + (l & 15);
        bb[f] = *(const short8*)(pB + swz(row, kb));
      }
#pragma unroll
      for (int fm = 0; fm < 8; ++fm)
#pragma unroll
        for (int fn = 0; fn < 4; ++fn)
          acc[fm][fn] = __builtin_amdgcn_mfma_f32_16x16x32_bf16(a[fm], bb[fn], acc[fm][fn], 0, 0, 0);
    }
  };

  load_stage(0);
  for (int s = 0; s < 32; ++s) {
    __syncthreads();
    write_stage();
    __syncthreads();
    if (s < 31) load_stage(s + 1);
    compute_stage();
  }

#pragma unroll
  for (int fm = 0; fm < 8; ++fm)
#pragma unroll
    for (int fn = 0; fn < 4; ++fn)
#pragma unroll
      for (int q = 0; q < 4; ++q) {
        const int row = wm4 * 128 + fm * 16 + (l >> 4) * 4 + q;
        const int col = w0 + wn2 * 64 + fn * 16 + (l & 15);
        out[((size_t)b * 512 + row) * 1024 + col] = acc[fm][fn][q];
      }
}

// ===========================================================================
// FALLBACK PATH (round-2 verified kernels; used if ws too small)
// ===========================================================================
__global__ __launch_bounds__(256, 4) void k_proj(const float* __restrict__ A,
                                                 const float* __restrict__ W,
                                                 const float* __restrict__ bias,
                                                 float* __restrict__ out) {
  __shared__ float As[32][132];
  __shared__ float Bs[32][132];
  const int t = threadIdx.x;
  const int m0 = blockIdx.x * 128;
  const int n0 = blockIdx.y * 128;
  const int tm = t >> 4;
  const int tn = t & 15;
  const int lrow = t >> 1;
  const int lk = (t & 1) * 16;

  float acc[8][8];
#pragma unroll
  for (int i = 0; i < 8; ++i)
#pragma unroll
    for (int j = 0; j < 8; ++j) acc[i][j] = 0.0f;

  const float* Arow = A + (size_t)(m0 + lrow) * D_ + lk;
  const float* Wrow = W + (size_t)(n0 + lrow) * D_ + lk;

  for (int k0 = 0; k0 < D_; k0 += 32) {
    __syncthreads();
#pragma unroll
    for (int j = 0; j < 4; ++j) {
      const float4 va = *(const float4*)(Arow + k0 + j * 4);
      As[lk + j * 4 + 0][lrow] = va.x;
      As[lk + j * 4 + 1][lrow] = va.y;
      As[lk + j * 4 + 2][lrow] = va.z;
      As[lk + j * 4 + 3][lrow] = va.w;
      const float4 vb = *(const float4*)(Wrow + k0 + j * 4);
      Bs[lk + j * 4 + 0][lrow] = vb.x;
      Bs[lk + j * 4 + 1][lrow] = vb.y;
      Bs[lk + j * 4 + 2][lrow] = vb.z;
      Bs[lk + j * 4 + 3][lrow] = vb.w;
    }
    __syncthreads();
#pragma unroll 8
    for (int k = 0; k < 32; ++k) {
      float a[8], bb[8];
      *(float4*)(a + 0) = *(const float4*)&As[k][tm * 4];
      *(float4*)(a + 4) = *(const float4*)&As[k][tm * 4 + 64];
      *(float4*)(bb + 0) = *(const float4*)&Bs[k][tn * 4];
      *(float4*)(bb + 4) = *(const float4*)&Bs[k][tn * 4 + 64];
#pragma unroll
      for (int i = 0; i < 8; ++i)
#pragma unroll
        for (int j = 0; j < 8; ++j) acc[i][j] = fmaf(a[i], bb[j], acc[i][j]);
    }
  }

  float bn[8];
#pragma unroll
  for (int j = 0; j < 8; ++j) bn[j] = bias[n0 + tn * 4 + (j & 3) + (j >> 2) * 64];
#pragma unroll
  for (int i = 0; i < 8; ++i) {
    const int m = m0 + tm * 4 + (i & 3) + (i >> 2) * 64;
    float4 v0, v1;
    v0.x = tanhf(acc[i][0] + bn[0]);
    v0.y = tanhf(acc[i][1] + bn[1]);
    v0.z = tanhf(acc[i][2] + bn[2]);
    v0.w = tanhf(acc[i][3] + bn[3]);
    v1.x = tanhf(acc[i][4] + bn[4]);
    v1.y = tanhf(acc[i][5] + bn[5]);
    v1.z = tanhf(acc[i][6] + bn[6]);
    v1.w = tanhf(acc[i][7] + bn[7]);
    *(float4*)(out + (size_t)m * D_ + n0 + tn * 4) = v0;
    *(float4*)(out + (size_t)m * D_ + n0 + tn * 4 + 64) = v1;
  }
}

__global__ __launch_bounds__(256) void k_scores(const float* __restrict__ words,
                                                const void* __restrict__ mask,
                                                float* __restrict__ pa) {
  __shared__ float Pt[1024][18];
  __shared__ float Ws[64][268];
  const int t = threadIdx.x;
  const int b = blockIdx.x >> 5;
  const int et = blockIdx.x & 31;
  const int e0 = et * 16;
  const int eg = t >> 5;
  const int ng = t & 31;
  const int mask_is_int = g_mask_is_int;
  const float* wbase = words + (size_t)b * WN * D_;

  {
    const int row = t >> 4;
    const int dj = (t & 15) * 4;
    const float* pr = pa + (size_t)(b * E_ + e0 + row) * D_;
#pragma unroll
    for (int rr = 0; rr < 16; ++rr) {
      const float4 v = *(const float4*)(pr + dj + rr * 64);
      Pt[dj + rr * 64 + 0][row] = v.x;
      Pt[dj + rr * 64 + 1][row] = v.y;
      Pt[dj + rr * 64 + 2][row] = v.z;
      Pt[dj + rr * 64 + 3][row] = v.w;
    }
  }

  float s[2][64];
#pragma unroll
  for (int i = 0; i < 2; ++i)
#pragma unroll
    for (int u = 0; u < 64; ++u) s[i][u] = 0.0f;

  const int nl = t >> 3;
  const int d4 = (t & 7) * 4;

  for (int dk = 0; dk < D_; dk += 64) {
#pragma unroll
    for (int nb = 0; nb < 8; ++nb) {
      __syncthreads();
#pragma unroll
      for (int rr = 0; rr < 8; ++rr) {
#pragma unroll
        for (int hh = 0; hh < 2; ++hh) {
          const int n = nl + rr * 32;
          const int d = d4 + hh * 32;
          const float4 v = *(const float4*)(wbase + (size_t)(nb * 256 + n) * D_ + dk + d);
          Ws[d + 0][n] = v.x;
          Ws[d + 1][n] = v.y;
          Ws[d + 2][n] = v.z;
          Ws[d + 3][n] = v.w;
        }
      }
      __syncthreads();
#pragma unroll 2
      for (int k = 0; k < 64; ++k) {
        const float2 a = *(const float2*)&Pt[dk + k][eg * 2];
        const float4 b0 = *(const float4*)&Ws[k][ng * 4];
        const float4 b1 = *(const float4*)&Ws[k][128 + ng * 4];
        const float aa[2] = {a.x, a.y};
        const float bb[8] = {b0.x, b0.y, b0.z, b0.w, b1.x, b1.y, b1.z, b1.w};
#pragma unroll
        for (int i = 0; i < 2; ++i)
#pragma unroll
          for (int u = 0; u < 8; ++u)
            s[i][nb * 8 + u] = fmaf(aa[i], bb[u], s[i][nb * 8 + u]);
      }
    }
  }

#pragma unroll
  for (int i = 0; i < 2; ++i) {
    const int e = e0 + eg * 2 + i;
#pragma unroll
    for (int nb = 0; nb < 8; ++nb)
#pragma unroll
      for (int q = 0; q < 2; ++q) {
        const size_t moff = (size_t)(b * E_ + e) * WN + nb * 256 + q * 128 + ng * 4;
        int mx, my, mz, mw;
        if (mask_is_int) {
          const int4 mv = *(const int4*)((const int*)mask + moff);
          mx = mv.x; my = mv.y; mz = mv.z; mw = mv.w;
        } else {
          const uchar4 mv = *(const uchar4*)((const unsigned char*)mask + moff);
          mx = mv.x; my = mv.y; mz = mv.z; mw = mv.w;
        }
        if (mx) s[i][nb * 8 + q * 4 + 0] = -1e30f;
        if (my) s[i][nb * 8 + q * 4 + 1] = -1e30f;
        if (mz) s[i][nb * 8 + q * 4 + 2] = -1e30f;
        if (mw) s[i][nb * 8 + q * 4 + 3] = -1e30f;
      }
    float m = -1e30f;
#pragma unroll
    for (int u = 0; u < 64; ++u) m = fmaxf(m, s[i][u]);
#pragma unroll
    for (int off = 16; off > 0; off >>= 1) m = fmaxf(m, __shfl_xor(m, off));
    float sum = 0.0f;
#pragma unroll
    for (int u = 0; u < 64; ++u) {
      const float p = __expf(s[i][u] - m);
      s[i][u] = p;
      sum += p;
    }
#pragma unroll
    for (int off = 16; off > 0; off >>= 1) sum += __shfl_xor(sum, off);
    const float rinv = 1.0f / sum;

    unsigned short* ar2 = (unsigned short*)(pa + (size_t)(b * E_ + e) * WN / 2);
#pragma unroll
    for (int nb = 0; nb < 8; ++nb)
#pragma unroll
      for (int q = 0; q < 2; ++q) {
        ushort4 pk;
        pk.x = f2bf(s[i][nb * 8 + q * 4 + 0] * rinv);
        pk.y = f2bf(s[i][nb * 8 + q * 4 + 1] * rinv);
        pk.z = f2bf(s[i][nb * 8 + q * 4 + 2] * rinv);
        pk.w = f2bf(s[i][nb * 8 + q * 4 + 3] * rinv);
        *(ushort4*)(ar2 + nb * 256 + q * 128 + ng * 4) = pk;
      }
  }
}

__global__ __launch_bounds__(256) void k_ctx(const float* __restrict__ words,
                                             float* __restrict__ pa) {
  __shared__ unsigned short att_s[16][2048];
  __shared__ unsigned short Wb[256][132];
  const int t = threadIdx.x;
  const int b = blockIdx.x >> 5;
  const int et = blockIdx.x & 31;
  const int e0 = et * 16;
  const int eg = t >> 5;
  const int wg = t & 31;
  const float* wbase = words + (size_t)b * WN * D_;

  {
    const int row = t >> 4;
    const int cj = t & 15;
    const uint4* pr = (const uint4*)(pa + (size_t)(b * E_ + e0 + row) * D_);
#pragma unroll
    for (int rr = 0; rr < 16; ++rr) {
      const int c = cj + rr * 16;
      const uint4 v = pr[c];
      *(uint4*)&att_s[row][c * 8] = v;
    }
  }

  float acc[2][32];
#pragma unroll
  for (int i = 0; i < 2; ++i)
#pragma unroll
    for (int u = 0; u < 32; ++u) acc[i][u] = 0.0f;

  const int nlg = t >> 5;
  const int w4 = (t & 31) * 4;

  for (int nb = 0; nb < 8; ++nb) {
#pragma unroll
    for (int q = 0; q < 8; ++q) {
      __syncthreads();
#pragma unroll
      for (int rr = 0; rr < 32; ++rr) {
        const int n = nlg + rr * 8;
        const float4 v = *(const float4*)(wbase + (size_t)(nb * 256 + n) * D_ + q * 128 + w4);
        ushort4 pk;
        pk.x = f2bf(v.x);
        pk.y = f2bf(v.y);
        pk.z = f2bf(v.z);
        pk.w = f2bf(v.w);
        *(ushort4*)&Wb[n][w4] = pk;
      }
      __syncthreads();
#pragma unroll 4
      for (int n2 = 0; n2 < 128; ++n2) {
        const int n = n2 * 2;
        const ushort4 r0 = *(const ushort4*)&Wb[n][wg * 4];
        const ushort4 r1 = *(const ushort4*)&Wb[n + 1][wg * 4];
        const float w0[4] = {bf2f(r0.x), bf2f(r0.y), bf2f(r0.z), bf2f(r0.w)};
        const float w1[4] = {bf2f(r1.x), bf2f(r1.y), bf2f(r1.z), bf2f(r1.w)};
#pragma unroll
        for (int i = 0; i < 2; ++i) {
          const unsigned int aw = *(const unsigned int*)&att_s[eg * 2 + i][nb * 256 + n];
          const float a0 = bf2f((unsigned short)(aw & 0xffffu));
          const float a1 = bf2f((unsigned short)(aw >> 16));
#pragma unroll
          for (int j = 0; j < 4; ++j)
            acc[i][q * 4 + j] = fmaf(a0, w0[j], fmaf(a1, w1[j], acc[i][q * 4 + j]));
        }
      }
    }
  }

#pragma unroll
  for (int i = 0; i < 2; ++i) {
    float* orow = pa + (size_t)(b * E_ + e0 + eg * 2 + i) * D_;
#pragma unroll
    for (int q = 0; q < 8; ++q) {
      float4 v;
      v.x = acc[i][q * 4 + 0];
      v.y = acc[i][q * 4 + 1];
      v.z = acc[i][q * 4 + 2];
      v.w = acc[i][q * 4 + 3];
      *(float4*)(orow + q * 128 + wg * 4) = v;
    }
  }
}

extern "C" void kernel_launch(void* const* d_in, const int* in_sizes, int n_in,
                              void* d_out, int out_size, void* d_ws, size_t ws_size,
                              hipStream_t stream) {
  const float* ems = (const float*)d_in[0];
  const float* words = (const float*)d_in[1];
  const void* mask = d_in[2];
  const float* w_weight = (const float*)d_in[3];
  const float* w_bias = (const float*)d_in[4];

  k_detect<<<1, 64, 0, stream>>>((const unsigned char*)mask);

  const size_t ws_need = (size_t)16384 * 2048 * 4;
  if (ws_size >= ws_need) {
    unsigned short* hiP = (unsigned short*)d_out;
    unsigned short* loP = hiP + (size_t)16384 * 1024;
    float* ws = (float*)d_ws;
    k_proj_mfma<<<dim3(128, 8), 256, 0, stream>>>(ems, w_weight, w_bias, hiP, loP);
    k_scores_mfma<<<dim3(512), 512, 0, stream>>>(hiP, loP, words, ws);
    k_softmax<<<dim3(16384), 256, 0, stream>>>(ws, mask);
    k_pv<<<dim3(256), 512, 0, stream>>>((const unsigned short*)d_ws, words,
                                        (float*)d_out);
  } else {
    float* out = (float*)d_out;
    k_proj<<<dim3(128, 8), 256, 0, stream>>>(ems, w_weight, w_bias, out);
    k_scores<<<dim3(B_ * (E_ / 16)), 256, 0, stream>>>(words, mask, out);
    k_ctx<<<dim3(B_ * (E_ / 16)), 256, 0, stream>>>(words, out);
  }
}

// Round 7
// 1012.566 us; speedup vs baseline: 1.0858x; 1.0858x over previous
//
#include <hip/hip_runtime.h>
#include <hip/hip_bf16.h>
#include <stdint.h>

#define B_  32
#define E_  512
#define WN  2048
#define D_  1024

typedef __attribute__((ext_vector_type(8))) short short8;
typedef __attribute__((ext_vector_type(4))) float f32x4;

__device__ int g_mask_is_int;   // 1 if mask buffer is int32 per element, 0 if uint8

__device__ __forceinline__ unsigned short f2bf(float f) {
  unsigned int u = __float_as_uint(f);
  u += 0x7fffu + ((u >> 16) & 1u);   // round-to-nearest-even
  return (unsigned short)(u >> 16);
}
__device__ __forceinline__ float bf2f(unsigned short s) {
  return __uint_as_float(((unsigned int)s) << 16);
}
__device__ __forceinline__ float ftanh(float x) {
  float e = __expf(2.0f * x);
  return 1.0f - 2.0f / (e + 1.0f);
}
// XOR-swizzled byte offset within a [rows][128B] LDS plane
__device__ __forceinline__ int swz(int row, int kb) {
  return row * 128 + (kb ^ ((row & 7) << 4));
}
// XOR-swizzled byte offset within a [rows][64B] LDS plane
__device__ __forceinline__ int swz64(int row, int kb) {
  return (row * 64 + kb) ^ ((row & 7) << 4);
}
__device__ __forceinline__ uint4 pack8(unsigned short a0, unsigned short a1,
                                       unsigned short a2, unsigned short a3,
                                       unsigned short a4, unsigned short a5,
                                       unsigned short a6, unsigned short a7) {
  uint4 v;
  v.x = (unsigned int)a0 | ((unsigned int)a1 << 16);
  v.y = (unsigned int)a2 | ((unsigned int)a3 << 16);
  v.z = (unsigned int)a4 | ((unsigned int)a5 << 16);
  v.w = (unsigned int)a6 | ((unsigned int)a7 << 16);
  return v;
}

// ---------------------------------------------------------------------------
// K0: detect mask dtype. int32 0/1 data => bytes at offset %4 != 0 are all 0.
// ---------------------------------------------------------------------------
__global__ void k_detect(const unsigned char* __restrict__ m) {
  if (threadIdx.x == 0) {
    int nz = 0;
    for (int i = 0; i < 1024; ++i)
      if ((i & 3) && m[i]) nz++;
    g_mask_is_int = (nz == 0) ? 1 : 0;
  }
}

// ===========================================================================
// FAST PATH
// ===========================================================================

// ---------------------------------------------------------------------------
// k_proj_mfma: proj = tanh(ems @ W^T + bias), split-bf16 3-term MFMA.
// (unchanged, verified)
// ---------------------------------------------------------------------------
__global__ __launch_bounds__(256, 2) void k_proj_mfma(
    const float* __restrict__ A, const float* __restrict__ W,
    const float* __restrict__ bias,
    unsigned short* __restrict__ outHi, unsigned short* __restrict__ outLo) {
  __shared__ unsigned short lds[32768];  // 64KB: Ahi|Alo|Bhi|Blo planes 16KB each
  char* const ldsb = (char*)lds;
  char* const pAhi = ldsb;
  char* const pAlo = ldsb + 16384;
  char* const pBhi = ldsb + 32768;
  char* const pBlo = ldsb + 49152;
  const int t = threadIdx.x, l = t & 63, wave = t >> 6;
  const int wm = (wave >> 1) * 64, wn = (wave & 1) * 64;
  const int m0 = blockIdx.x * 128, n0 = blockIdx.y * 128;
  const int r = t >> 1, h = t & 1;

  f32x4 acc[4][4];
#pragma unroll
  for (int i = 0; i < 4; ++i)
#pragma unroll
    for (int j = 0; j < 4; ++j) acc[i][j] = (f32x4){0.f, 0.f, 0.f, 0.f};

  f32x4 ar[8], br[8];

  auto load_stage = [&](int s) {
    const float* as = A + (size_t)(m0 + r) * 1024 + s * 64 + h * 32;
    const float* bs = W + (size_t)(n0 + r) * 1024 + s * 64 + h * 32;
#pragma unroll
    for (int i = 0; i < 8; ++i) {
      ar[i] = *(const f32x4*)(as + i * 4);
      br[i] = *(const f32x4*)(bs + i * 4);
    }
  };

  auto write_stage = [&]() {
    unsigned short hA[32], lA[32], hB[32], lB[32];
#pragma unroll
    for (int i = 0; i < 8; ++i)
#pragma unroll
      for (int j = 0; j < 4; ++j) {
        float x = ar[i][j];
        unsigned short hh = f2bf(x);
        hA[i * 4 + j] = hh;
        lA[i * 4 + j] = f2bf(x - bf2f(hh));
        float y = br[i][j];
        unsigned short hb = f2bf(y);
        hB[i * 4 + j] = hb;
        lB[i * 4 + j] = f2bf(y - bf2f(hb));
      }
#pragma unroll
    for (int i = 0; i < 4; ++i) {
      const int kb = h * 64 + i * 16;
      const int o = swz(r, kb);
      *(uint4*)(pAhi + o) = pack8(hA[i*8+0],hA[i*8+1],hA[i*8+2],hA[i*8+3],hA[i*8+4],hA[i*8+5],hA[i*8+6],hA[i*8+7]);
      *(uint4*)(pAlo + o) = pack8(lA[i*8+0],lA[i*8+1],lA[i*8+2],lA[i*8+3],lA[i*8+4],lA[i*8+5],lA[i*8+6],lA[i*8+7]);
      *(uint4*)(pBhi + o) = pack8(hB[i*8+0],hB[i*8+1],hB[i*8+2],hB[i*8+3],hB[i*8+4],hB[i*8+5],hB[i*8+6],hB[i*8+7]);
      *(uint4*)(pBlo + o) = pack8(lB[i*8+0],lB[i*8+1],lB[i*8+2],lB[i*8+3],lB[i*8+4],lB[i*8+5],lB[i*8+6],lB[i*8+7]);
    }
  };

  auto compute_stage = [&]() {
#pragma unroll
    for (int ks = 0; ks < 2; ++ks) {
      short8 ah[4], al[4], bh[4], bl[4];
      const int kb = ks * 64 + (l >> 4) * 16;
#pragma unroll
      for (int f = 0; f < 4; ++f) {
        const int oa = swz(wm + f * 16 + (l & 15), kb);
        ah[f] = *(const short8*)(pAhi + oa);
        al[f] = *(const short8*)(pAlo + oa);
        const int ob = swz(wn + f * 16 + (l & 15), kb);
        bh[f] = *(const short8*)(pBhi + ob);
        bl[f] = *(const short8*)(pBlo + ob);
      }
#pragma unroll
      for (int fm = 0; fm < 4; ++fm)
#pragma unroll
        for (int fn = 0; fn < 4; ++fn) {
          acc[fm][fn] = __builtin_amdgcn_mfma_f32_16x16x32_bf16(ah[fm], bh[fn], acc[fm][fn], 0, 0, 0);
          acc[fm][fn] = __builtin_amdgcn_mfma_f32_16x16x32_bf16(al[fm], bh[fn], acc[fm][fn], 0, 0, 0);
          acc[fm][fn] = __builtin_amdgcn_mfma_f32_16x16x32_bf16(ah[fm], bl[fn], acc[fm][fn], 0, 0, 0);
        }
    }
  };

  load_stage(0);
  write_stage();
  __syncthreads();
  for (int s = 0; s < 15; ++s) {
    load_stage(s + 1);
    compute_stage();
    __syncthreads();
    write_stage();
    __syncthreads();
  }
  compute_stage();

  float bcol[4];
#pragma unroll
  for (int fn = 0; fn < 4; ++fn) bcol[fn] = bias[n0 + wn + fn * 16 + (l & 15)];
#pragma unroll
  for (int fm = 0; fm < 4; ++fm)
#pragma unroll
    for (int fn = 0; fn < 4; ++fn)
#pragma unroll
      for (int q = 0; q < 4; ++q)
        acc[fm][fn][q] = ftanh(acc[fm][fn][q] + bcol[fn]);

  unsigned short* ldsT = lds;  // reused as [128][136]
  const int rr = t >> 1, ch = (t & 1) * 64;
  __syncthreads();
#pragma unroll
  for (int fm = 0; fm < 4; ++fm)
#pragma unroll
    for (int fn = 0; fn < 4; ++fn)
#pragma unroll
      for (int q = 0; q < 4; ++q) {
        const int rl = wm + fm * 16 + (l >> 4) * 4 + q;
        const int cl = wn + fn * 16 + (l & 15);
        ldsT[rl * 136 + cl] = f2bf(acc[fm][fn][q]);
      }
  __syncthreads();
#pragma unroll
  for (int i = 0; i < 8; ++i) {
    uint4 v = *(const uint4*)(ldsT + rr * 136 + ch + i * 8);
    *(uint4*)(outHi + (size_t)(m0 + rr) * 1024 + n0 + ch + i * 8) = v;
  }
  __syncthreads();
#pragma unroll
  for (int fm = 0; fm < 4; ++fm)
#pragma unroll
    for (int fn = 0; fn < 4; ++fn)
#pragma unroll
      for (int q = 0; q < 4; ++q) {
        const int rl = wm + fm * 16 + (l >> 4) * 4 + q;
        const int cl = wn + fn * 16 + (l & 15);
        const float x = acc[fm][fn][q];
        const unsigned short hh = f2bf(x);
        ldsT[rl * 136 + cl] = f2bf(x - bf2f(hh));
      }
  __syncthreads();
#pragma unroll
  for (int i = 0; i < 8; ++i) {
    uint4 v = *(const uint4*)(ldsT + rr * 136 + ch + i * 8);
    *(uint4*)(outLo + (size_t)(m0 + rr) * 1024 + n0 + ch + i * 8) = v;
  }
}

// ---------------------------------------------------------------------------
// k_scores_mfma: scores = proj @ words^T (split-bf16 3-term), f32 -> ws.
// Round-5 structure (128x128 tile, 256 thr, verified) with BK=32:
// LDS 32KB -> 4 blocks/CU, launch_bounds(256,4) for barrier/latency overlap.
// Grid 2048, XCD-pinned swizzle (verified round 5).
// ---------------------------------------------------------------------------
__global__ __launch_bounds__(256, 4) void k_scores_mfma(
    const unsigned short* __restrict__ pHi, const unsigned short* __restrict__ pLo,
    const float* __restrict__ words, float* __restrict__ sc) {
  __shared__ uint4 lds4[2048];   // 32KB
  char* const pAhi = (char*)lds4;            // 8KB: [128 rows][64B]
  char* const pAlo = (char*)lds4 + 8192;
  char* const pBhi = (char*)lds4 + 16384;
  char* const pBlo = (char*)lds4 + 24576;
  const int t = threadIdx.x, l = t & 63, wave = t >> 6;
  const int wm = (wave >> 1) * 64, wn = (wave & 1) * 64;
  const int g = blockIdx.x;
  const int xcd = g & 7;
  const int slot = g >> 3;            // 0..255
  const int b = xcd + 8 * (slot >> 6);
  const int inner = slot & 63;
  const int m0 = (inner & 3) * 128;
  const int n0 = (inner >> 2) * 128;
  const int mg = b * 512 + m0;
  const float* wB = words + (size_t)b * WN * D_;
  const int r = t >> 1, h = t & 1;

  f32x4 acc[4][4];
#pragma unroll
  for (int i = 0; i < 4; ++i)
#pragma unroll
    for (int j = 0; j < 4; ++j) acc[i][j] = (f32x4){0.f, 0.f, 0.f, 0.f};

  uint4 avh[2], avl[2];   // A: 32B per plane per thread (row r, half h)
  f32x4 br[4];            // B: 16 f32 (row r, half h)

  auto load_stage = [&](int s) {
    const unsigned short* ah_ = pHi + (size_t)(mg + r) * 1024 + s * 32 + h * 16;
    const unsigned short* al_ = pLo + (size_t)(mg + r) * 1024 + s * 32 + h * 16;
#pragma unroll
    for (int i = 0; i < 2; ++i) {
      avh[i] = ((const uint4*)ah_)[i];
      avl[i] = ((const uint4*)al_)[i];
    }
    const float* bs = wB + (size_t)(n0 + r) * 1024 + s * 32 + h * 16;
#pragma unroll
    for (int i = 0; i < 4; ++i) br[i] = *(const f32x4*)(bs + i * 4);
  };

  auto write_stage = [&]() {
#pragma unroll
    for (int i = 0; i < 2; ++i) {
      const int o = swz64(r, h * 32 + i * 16);
      *(uint4*)(pAhi + o) = avh[i];
      *(uint4*)(pAlo + o) = avl[i];
    }
    unsigned short hB[16], lB[16];
#pragma unroll
    for (int i = 0; i < 4; ++i)
#pragma unroll
      for (int j = 0; j < 4; ++j) {
        float y = br[i][j];
        unsigned short hb = f2bf(y);
        hB[i * 4 + j] = hb;
        lB[i * 4 + j] = f2bf(y - bf2f(hb));
      }
#pragma unroll
    for (int i = 0; i < 2; ++i) {
      const int o = swz64(r, h * 32 + i * 16);
      *(uint4*)(pBhi + o) = pack8(hB[i*8+0],hB[i*8+1],hB[i*8+2],hB[i*8+3],hB[i*8+4],hB[i*8+5],hB[i*8+6],hB[i*8+7]);
      *(uint4*)(pBlo + o) = pack8(lB[i*8+0],lB[i*8+1],lB[i*8+2],lB[i*8+3],lB[i*8+4],lB[i*8+5],lB[i*8+6],lB[i*8+7]);
    }
  };

  auto compute_stage = [&]() {
    const int kb = (l >> 4) * 16;
    short8 ah[4], al[4], bh[4], bl[4];
#pragma unroll
    for (int f = 0; f < 4; ++f) {
      const int oa = swz64(wm + f * 16 + (l & 15), kb);
      ah[f] = *(const short8*)(pAhi + oa);
      al[f] = *(const short8*)(pAlo + oa);
      const int ob = swz64(wn + f * 16 + (l & 15), kb);
      bh[f] = *(const short8*)(pBhi + ob);
      bl[f] = *(const short8*)(pBlo + ob);
    }
#pragma unroll
    for (int fm = 0; fm < 4; ++fm)
#pragma unroll
      for (int fn = 0; fn < 4; ++fn) {
        acc[fm][fn] = __builtin_amdgcn_mfma_f32_16x16x32_bf16(ah[fm], bh[fn], acc[fm][fn], 0, 0, 0);
        acc[fm][fn] = __builtin_amdgcn_mfma_f32_16x16x32_bf16(al[fm], bh[fn], acc[fm][fn], 0, 0, 0);
        acc[fm][fn] = __builtin_amdgcn_mfma_f32_16x16x32_bf16(ah[fm], bl[fn], acc[fm][fn], 0, 0, 0);
      }
  };

  load_stage(0);
  write_stage();
  __syncthreads();
  for (int s = 0; s < 31; ++s) {
    load_stage(s + 1);
    compute_stage();
    __syncthreads();
    write_stage();
    __syncthreads();
  }
  compute_stage();

  // store f32 scores
#pragma unroll
  for (int fm = 0; fm < 4; ++fm)
#pragma unroll
    for (int fn = 0; fn < 4; ++fn)
#pragma unroll
      for (int q = 0; q < 4; ++q) {
        const int rl = wm + fm * 16 + (l >> 4) * 4 + q;
        const int cl = wn + fn * 16 + (l & 15);
        sc[((size_t)b * 512 + m0 + rl) * 2048 + n0 + cl] = acc[fm][fn][q];
      }
}

// ---------------------------------------------------------------------------
// k_softmax: unchanged (verified).
// ---------------------------------------------------------------------------
__global__ __launch_bounds__(256) void k_softmax(float* __restrict__ ws,
                                                 const void* __restrict__ mask) {
  __shared__ float red[8];
  const int row = blockIdx.x;
  const int t = threadIdx.x;
  const int wave = t >> 6;
  float* rp = ws + (size_t)row * 2048;
  float v[8];
  {
    f32x4 v0 = *(const f32x4*)(rp + t * 8);
    f32x4 v1 = *(const f32x4*)(rp + t * 8 + 4);
#pragma unroll
    for (int i = 0; i < 4; ++i) { v[i] = v0[i]; v[4 + i] = v1[i]; }
  }
  if (g_mask_is_int) {
    const int* mp = (const int*)mask + (size_t)row * 2048 + t * 8;
    const int4 m0 = *(const int4*)mp;
    const int4 m1 = *(const int4*)(mp + 4);
    if (m0.x) v[0] = -INFINITY;
    if (m0.y) v[1] = -INFINITY;
    if (m0.z) v[2] = -INFINITY;
    if (m0.w) v[3] = -INFINITY;
    if (m1.x) v[4] = -INFINITY;
    if (m1.y) v[5] = -INFINITY;
    if (m1.z) v[6] = -INFINITY;
    if (m1.w) v[7] = -INFINITY;
  } else {
    const unsigned char* mp = (const unsigned char*)mask + (size_t)row * 2048 + t * 8;
    const uchar4 m0 = *(const uchar4*)mp;
    const uchar4 m1 = *(const uchar4*)(mp + 4);
    if (m0.x) v[0] = -INFINITY;
    if (m0.y) v[1] = -INFINITY;
    if (m0.z) v[2] = -INFINITY;
    if (m0.w) v[3] = -INFINITY;
    if (m1.x) v[4] = -INFINITY;
    if (m1.y) v[5] = -INFINITY;
    if (m1.z) v[6] = -INFINITY;
    if (m1.w) v[7] = -INFINITY;
  }
  float mx = v[0];
#pragma unroll
  for (int i = 1; i < 8; ++i) mx = fmaxf(mx, v[i]);
#pragma unroll
  for (int off = 32; off > 0; off >>= 1) mx = fmaxf(mx, __shfl_xor(mx, off));
  if ((t & 63) == 0) red[wave] = mx;
  __syncthreads();
  mx = fmaxf(fmaxf(red[0], red[1]), fmaxf(red[2], red[3]));
  float e[8];
  float sum = 0.0f;
#pragma unroll
  for (int i = 0; i < 8; ++i) {
    e[i] = __expf(v[i] - mx);
    sum += e[i];
  }
#pragma unroll
  for (int off = 32; off > 0; off >>= 1) sum += __shfl_xor(sum, off);
  if ((t & 63) == 0) red[4 + wave] = sum;
  __syncthreads();
  const float tot = (red[4] + red[5]) + (red[6] + red[7]);
  const float rinv = 1.0f / tot;
  unsigned short* op = (unsigned short*)rp;
  ushort4 o0, o1;
  o0.x = f2bf(e[0] * rinv); o0.y = f2bf(e[1] * rinv);
  o0.z = f2bf(e[2] * rinv); o0.w = f2bf(e[3] * rinv);
  o1.x = f2bf(e[4] * rinv); o1.y = f2bf(e[5] * rinv);
  o1.z = f2bf(e[6] * rinv); o1.w = f2bf(e[7] * rinv);
  *(ushort4*)(op + t * 8) = o0;
  *(ushort4*)(op + t * 8 + 4) = o1;
}

// ---------------------------------------------------------------------------
// k_pv: unchanged (verified round 5).
// ---------------------------------------------------------------------------
__global__ __launch_bounds__(512, 2) void k_pv(
    const unsigned short* __restrict__ att, const float* __restrict__ words,
    float* __restrict__ out) {
  __shared__ uint4 lds4[5120];            // 80 KB: A 64KB | B 16KB
  char* const pA = (char*)lds4;
  char* const pB = (char*)lds4 + 65536;

  const int g = blockIdx.x;
  const int b = (g & 7) + 8 * (g >> 6);   // XCD-pinned batch
  const int wt = (g >> 3) & 7;
  const int w0 = wt * 128;

  const int t = threadIdx.x, l = t & 63, wv = t >> 6;
  const int wm4 = wv >> 1;
  const int wn2 = wv & 1;

  f32x4 acc[8][4];
#pragma unroll
  for (int i = 0; i < 8; ++i)
#pragma unroll
    for (int j = 0; j < 4; ++j) acc[i][j] = (f32x4){0.f, 0.f, 0.f, 0.f};

  uint4 avA[8];
  f32x4 bv0a, bv0b, bv1a, bv1b;

  const int np2 = (t & 31) * 2;
  const int wc = (t >> 5) * 8;

  auto load_stage = [&](int s) {
    const unsigned short* ab =
        att + ((size_t)(b * 512) + (t >> 3)) * 4096 + s * 64 + (t & 7) * 8;
#pragma unroll
    for (int i = 0; i < 8; ++i)
      avA[i] = *(const uint4*)(ab + (size_t)i * 64 * 4096);
    const float* wp = words + (size_t)b * WN * D_ +
                      (size_t)(s * 64 + np2) * 1024 + w0 + wc;
    bv0a = *(const f32x4*)(wp);
    bv0b = *(const f32x4*)(wp + 4);
    bv1a = *(const f32x4*)(wp + 1024);
    bv1b = *(const f32x4*)(wp + 1028);
  };

  auto write_stage = [&]() {
#pragma unroll
    for (int i = 0; i < 8; ++i) {
      const int row = (t >> 3) + i * 64;
      *(uint4*)(pA + row * 128 + (((t & 7) * 16) ^ ((row & 7) << 4))) = avA[i];
    }
#pragma unroll
    for (int i = 0; i < 8; ++i) {
      const int w = wc + i;
      const float x0 = (i < 4) ? bv0a[i & 3] : bv0b[i & 3];
      const float x1 = (i < 4) ? bv1a[i & 3] : bv1b[i & 3];
      const unsigned int pk =
          (unsigned int)f2bf(x0) | ((unsigned int)f2bf(x1) << 16);
      *(unsigned int*)(pB + w * 128 + ((np2 * 2) ^ ((w & 7) << 4))) = pk;
    }
  };

  auto compute_stage = [&]() {
#pragma unroll
    for (int ks = 0; ks < 2; ++ks) {
      short8 a[8];
      const int kb = ks * 64 + (l >> 4) * 16;
#pragma unroll
      for (int f = 0; f < 8; ++f) {
        const int row = wm4 * 128 + f * 16 + (l & 15);
        a[f] = *(const short8*)(pA + swz(row, kb));
      }
      short8 bb[4];
#pragma unroll
      for (int f = 0; f < 4; ++f) {
        const int row = wn2 * 64 + f * 16 + (l & 15);
        bb[f] = *(const short8*)(pB + swz(row, kb));
      }
#pragma unroll
      for (int fm = 0; fm < 8; ++fm)
#pragma unroll
        for (int fn = 0; fn < 4; ++fn)
          acc[fm][fn] = __builtin_amdgcn_mfma_f32_16x16x32_bf16(a[fm], bb[fn], acc[fm][fn], 0, 0, 0);
    }
  };

  load_stage(0);
  for (int s = 0; s < 32; ++s) {
    __syncthreads();
    write_stage();
    __syncthreads();
    if (s < 31) load_stage(s + 1);
    compute_stage();
  }

#pragma unroll
  for (int fm = 0; fm < 8; ++fm)
#pragma unroll
    for (int fn = 0; fn < 4; ++fn)
#pragma unroll
      for (int q = 0; q < 4; ++q) {
        const int row = wm4 * 128 + fm * 16 + (l >> 4) * 4 + q;
        const int col = w0 + wn2 * 64 + fn * 16 + (l & 15);
        out[((size_t)b * 512 + row) * 1024 + col] = acc[fm][fn][q];
      }
}

// ===========================================================================
// FALLBACK PATH (round-2 verified kernels; used if ws too small)
// ===========================================================================
__global__ __launch_bounds__(256, 4) void k_proj(const float* __restrict__ A,
                                                 const float* __restrict__ W,
                                                 const float* __restrict__ bias,
                                                 float* __restrict__ out) {
  __shared__ float As[32][132];
  __shared__ float Bs[32][132];
  const int t = threadIdx.x;
  const int m0 = blockIdx.x * 128;
  const int n0 = blockIdx.y * 128;
  const int tm = t >> 4;
  const int tn = t & 15;
  const int lrow = t >> 1;
  const int lk = (t & 1) * 16;

  float acc[8][8];
#pragma unroll
  for (int i = 0; i < 8; ++i)
#pragma unroll
    for (int j = 0; j < 8; ++j) acc[i][j] = 0.0f;

  const float* Arow = A + (size_t)(m0 + lrow) * D_ + lk;
  const float* Wrow = W + (size_t)(n0 + lrow) * D_ + lk;

  for (int k0 = 0; k0 < D_; k0 += 32) {
    __syncthreads();
#pragma unroll
    for (int j = 0; j < 4; ++j) {
      const float4 va = *(const float4*)(Arow + k0 + j * 4);
      As[lk + j * 4 + 0][lrow] = va.x;
      As[lk + j * 4 + 1][lrow] = va.y;
      As[lk + j * 4 + 2][lrow] = va.z;
      As[lk + j * 4 + 3][lrow] = va.w;
      const float4 vb = *(const float4*)(Wrow + k0 + j * 4);
      Bs[lk + j * 4 + 0][lrow] = vb.x;
      Bs[lk + j * 4 + 1][lrow] = vb.y;
      Bs[lk + j * 4 + 2][lrow] = vb.z;
      Bs[lk + j * 4 + 3][lrow] = vb.w;
    }
    __syncthreads();
#pragma unroll 8
    for (int k = 0; k < 32; ++k) {
      float a[8], bb[8];
      *(float4*)(a + 0) = *(const float4*)&As[k][tm * 4];
      *(float4*)(a + 4) = *(const float4*)&As[k][tm * 4 + 64];
      *(float4*)(bb + 0) = *(const float4*)&Bs[k][tn * 4];
      *(float4*)(bb + 4) = *(const float4*)&Bs[k][tn * 4 + 64];
#pragma unroll
      for (int i = 0; i < 8; ++i)
#pragma unroll
        for (int j = 0; j < 8; ++j) acc[i][j] = fmaf(a[i], bb[j], acc[i][j]);
    }
  }

  float bn[8];
#pragma unroll
  for (int j = 0; j < 8; ++j) bn[j] = bias[n0 + tn * 4 + (j & 3) + (j >> 2) * 64];
#pragma unroll
  for (int i = 0; i < 8; ++i) {
    const int m = m0 + tm * 4 + (i & 3) + (i >> 2) * 64;
    float4 v0, v1;
    v0.x = tanhf(acc[i][0] + bn[0]);
    v0.y = tanhf(acc[i][1] + bn[1]);
    v0.z = tanhf(acc[i][2] + bn[2]);
    v0.w = tanhf(acc[i][3] + bn[3]);
    v1.x = tanhf(acc[i][4] + bn[4]);
    v1.y = tanhf(acc[i][5] + bn[5]);
    v1.z = tanhf(acc[i][6] + bn[6]);
    v1.w = tanhf(acc[i][7] + bn[7]);
    *(float4*)(out + (size_t)m * D_ + n0 + tn * 4) = v0;
    *(float4*)(out + (size_t)m * D_ + n0 + tn * 4 + 64) = v1;
  }
}

__global__ __launch_bounds__(256) void k_scores(const float* __restrict__ words,
                                                const void* __restrict__ mask,
                                                float* __restrict__ pa) {
  __shared__ float Pt[1024][18];
  __shared__ float Ws[64][268];
  const int t = threadIdx.x;
  const int b = blockIdx.x >> 5;
  const int et = blockIdx.x & 31;
  const int e0 = et * 16;
  const int eg = t >> 5;
  const int ng = t & 31;
  const int mask_is_int = g_mask_is_int;
  const float* wbase = words + (size_t)b * WN * D_;

  {
    const int row = t >> 4;
    const int dj = (t & 15) * 4;
    const float* pr = pa + (size_t)(b * E_ + e0 + row) * D_;
#pragma unroll
    for (int rr = 0; rr < 16; ++rr) {
      const float4 v = *(const float4*)(pr + dj + rr * 64);
      Pt[dj + rr * 64 + 0][row] = v.x;
      Pt[dj + rr * 64 + 1][row] = v.y;
      Pt[dj + rr * 64 + 2][row] = v.z;
      Pt[dj + rr * 64 + 3][row] = v.w;
    }
  }

  float s[2][64];
#pragma unroll
  for (int i = 0; i < 2; ++i)
#pragma unroll
    for (int u = 0; u < 64; ++u) s[i][u] = 0.0f;

  const int nl = t >> 3;
  const int d4 = (t & 7) * 4;

  for (int dk = 0; dk < D_; dk += 64) {
#pragma unroll
    for (int nb = 0; nb < 8; ++nb) {
      __syncthreads();
#pragma unroll
      for (int rr = 0; rr < 8; ++rr) {
#pragma unroll
        for (int hh = 0; hh < 2; ++hh) {
          const int n = nl + rr * 32;
          const int d = d4 + hh * 32;
          const float4 v = *(const float4*)(wbase + (size_t)(nb * 256 + n) * D_ + dk + d);
          Ws[d + 0][n] = v.x;
          Ws[d + 1][n] = v.y;
          Ws[d + 2][n] = v.z;
          Ws[d + 3][n] = v.w;
        }
      }
      __syncthreads();
#pragma unroll 2
      for (int k = 0; k < 64; ++k) {
        const float2 a = *(const float2*)&Pt[dk + k][eg * 2];
        const float4 b0 = *(const float4*)&Ws[k][ng * 4];
        const float4 b1 = *(const float4*)&Ws[k][128 + ng * 4];
        const float aa[2] = {a.x, a.y};
        const float bb[8] = {b0.x, b0.y, b0.z, b0.w, b1.x, b1.y, b1.z, b1.w};
#pragma unroll
        for (int i = 0; i < 2; ++i)
#pragma unroll
          for (int u = 0; u < 8; ++u)
            s[i][nb * 8 + u] = fmaf(aa[i], bb[u], s[i][nb * 8 + u]);
      }
    }
  }

#pragma unroll
  for (int i = 0; i < 2; ++i) {
    const int e = e0 + eg * 2 + i;
#pragma unroll
    for (int nb = 0; nb < 8; ++nb)
#pragma unroll
      for (int q = 0; q < 2; ++q) {
        const size_t moff = (size_t)(b * E_ + e) * WN + nb * 256 + q * 128 + ng * 4;
        int mx, my, mz, mw;
        if (mask_is_int) {
          const int4 mv = *(const int4*)((const int*)mask + moff);
          mx = mv.x; my = mv.y; mz = mv.z; mw = mv.w;
        } else {
          const uchar4 mv = *(const uchar4*)((const unsigned char*)mask + moff);
          mx = mv.x; my = mv.y; mz = mv.z; mw = mv.w;
        }
        if (mx) s[i][nb * 8 + q * 4 + 0] = -1e30f;
        if (my) s[i][nb * 8 + q * 4 + 1] = -1e30f;
        if (mz) s[i][nb * 8 + q * 4 + 2] = -1e30f;
        if (mw) s[i][nb * 8 + q * 4 + 3] = -1e30f;
      }
    float m = -1e30f;
#pragma unroll
    for (int u = 0; u < 64; ++u) m = fmaxf(m, s[i][u]);
#pragma unroll
    for (int off = 16; off > 0; off >>= 1) m = fmaxf(m, __shfl_xor(m, off));
    float sum = 0.0f;
#pragma unroll
    for (int u = 0; u < 64; ++u) {
      const float p = __expf(s[i][u] - m);
      s[i][u] = p;
      sum += p;
    }
#pragma unroll
    for (int off = 16; off > 0; off >>= 1) sum += __shfl_xor(sum, off);
    const float rinv = 1.0f / sum;

    unsigned short* ar2 = (unsigned short*)(pa + (size_t)(b * E_ + e) * WN / 2);
#pragma unroll
    for (int nb = 0; nb < 8; ++nb)
#pragma unroll
      for (int q = 0; q < 2; ++q) {
        ushort4 pk;
        pk.x = f2bf(s[i][nb * 8 + q * 4 + 0] * rinv);
        pk.y = f2bf(s[i][nb * 8 + q * 4 + 1] * rinv);
        pk.z = f2bf(s[i][nb * 8 + q * 4 + 2] * rinv);
        pk.w = f2bf(s[i][nb * 8 + q * 4 + 3] * rinv);
        *(ushort4*)(ar2 + nb * 256 + q * 128 + ng * 4) = pk;
      }
  }
}

__global__ __launch_bounds__(256) void k_ctx(const float* __restrict__ words,
                                             float* __restrict__ pa) {
  __shared__ unsigned short att_s[16][2048];
  __shared__ unsigned short Wb[256][132];
  const int t = threadIdx.x;
  const int b = blockIdx.x >> 5;
  const int et = blockIdx.x & 31;
  const int e0 = et * 16;
  const int eg = t >> 5;
  const int wg = t & 31;
  const float* wbase = words + (size_t)b * WN * D_;

  {
    const int row = t >> 4;
    const int cj = t & 15;
    const uint4* pr = (const uint4*)(pa + (size_t)(b * E_ + e0 + row) * D_);
#pragma unroll
    for (int rr = 0; rr < 16; ++rr) {
      const int c = cj + rr * 16;
      const uint4 v = pr[c];
      *(uint4*)&att_s[row][c * 8] = v;
    }
  }

  float acc[2][32];
#pragma unroll
  for (int i = 0; i < 2; ++i)
#pragma unroll
    for (int u = 0; u < 32; ++u) acc[i][u] = 0.0f;

  const int nlg = t >> 5;
  const int w4 = (t & 31) * 4;

  for (int nb = 0; nb < 8; ++nb) {
#pragma unroll
    for (int q = 0; q < 8; ++q) {
      __syncthreads();
#pragma unroll
      for (int rr = 0; rr < 32; ++rr) {
        const int n = nlg + rr * 8;
        const float4 v = *(const float4*)(wbase + (size_t)(nb * 256 + n) * D_ + q * 128 + w4);
        ushort4 pk;
        pk.x = f2bf(v.x);
        pk.y = f2bf(v.y);
        pk.z = f2bf(v.z);
        pk.w = f2bf(v.w);
        *(ushort4*)&Wb[n][w4] = pk;
      }
      __syncthreads();
#pragma unroll 4
      for (int n2 = 0; n2 < 128; ++n2) {
        const int n = n2 * 2;
        const ushort4 r0 = *(const ushort4*)&Wb[n][wg * 4];
        const ushort4 r1 = *(const ushort4*)&Wb[n + 1][wg * 4];
        const float w0[4] = {bf2f(r0.x), bf2f(r0.y), bf2f(r0.z), bf2f(r0.w)};
        const float w1[4] = {bf2f(r1.x), bf2f(r1.y), bf2f(r1.z), bf2f(r1.w)};
#pragma unroll
        for (int i = 0; i < 2; ++i) {
          const unsigned int aw = *(const unsigned int*)&att_s[eg * 2 + i][nb * 256 + n];
          const float a0 = bf2f((unsigned short)(aw & 0xffffu));
          const float a1 = bf2f((unsigned short)(aw >> 16));
#pragma unroll
          for (int j = 0; j < 4; ++j)
            acc[i][q * 4 + j] = fmaf(a0, w0[j], fmaf(a1, w1[j], acc[i][q * 4 + j]));
        }
      }
    }
  }

#pragma unroll
  for (int i = 0; i < 2; ++i) {
    float* orow = pa + (size_t)(b * E_ + e0 + eg * 2 + i) * D_;
#pragma unroll
    for (int q = 0; q < 8; ++q) {
      float4 v;
      v.x = acc[i][q * 4 + 0];
      v.y = acc[i][q * 4 + 1];
      v.z = acc[i][q * 4 + 2];
      v.w = acc[i][q * 4 + 3];
      *(float4*)(orow + q * 128 + wg * 4) = v;
    }
  }
}

extern "C" void kernel_launch(void* const* d_in, const int* in_sizes, int n_in,
                              void* d_out, int out_size, void* d_ws, size_t ws_size,
                              hipStream_t stream) {
  const float* ems = (const float*)d_in[0];
  const float* words = (const float*)d_in[1];
  const void* mask = d_in[2];
  const float* w_weight = (const float*)d_in[3];
  const float* w_bias = (const float*)d_in[4];

  k_detect<<<1, 64, 0, stream>>>((const unsigned char*)mask);

  const size_t ws_need = (size_t)16384 * 2048 * 4;
  if (ws_size >= ws_need) {
    unsigned short* hiP = (unsigned short*)d_out;
    unsigned short* loP = hiP + (size_t)16384 * 1024;
    float* ws = (float*)d_ws;
    k_proj_mfma<<<dim3(128, 8), 256, 0, stream>>>(ems, w_weight, w_bias, hiP, loP);
    k_scores_mfma<<<dim3(2048), 256, 0, stream>>>(hiP, loP, words, ws);
    k_softmax<<<dim3(16384), 256, 0, stream>>>(ws, mask);
    k_pv<<<dim3(256), 512, 0, stream>>>((const unsigned short*)d_ws, words,
                                        (float*)d_out);
  } else {
    float* out = (float*)d_out;
    k_proj<<<dim3(128, 8), 256, 0, stream>>>(ems, w_weight, w_bias, out);
    k_scores<<<dim3(B_ * (E_ / 16)), 256, 0, stream>>>(words, mask, out);
    k_ctx<<<dim3(B_ * (E_ / 16)), 256, 0, stream>>>(words, out);
  }
}

// Round 8
// 786.936 us; speedup vs baseline: 1.3971x; 1.2867x over previous
//
#include <hip/hip_runtime.h>
#include <hip/hip_bf16.h>
#include <stdint.h>

#define B_  32
#define E_  512
#define WN  2048
#define D_  1024

typedef __attribute__((ext_vector_type(8))) short short8;
typedef __attribute__((ext_vector_type(4))) float f32x4;

__device__ int g_mask_is_int;   // 1 if mask buffer is int32 per element, 0 if uint8

__device__ __forceinline__ unsigned short f2bf(float f) {
  unsigned int u = __float_as_uint(f);
  u += 0x7fffu + ((u >> 16) & 1u);   // round-to-nearest-even
  return (unsigned short)(u >> 16);
}
__device__ __forceinline__ float bf2f(unsigned short s) {
  return __uint_as_float(((unsigned int)s) << 16);
}
__device__ __forceinline__ float ftanh(float x) {
  float e = __expf(2.0f * x);
  return 1.0f - 2.0f / (e + 1.0f);
}
// XOR-swizzled byte offset within a [rows][128B] LDS plane
__device__ __forceinline__ int swz(int row, int kb) {
  return row * 128 + (kb ^ ((row & 7) << 4));
}
__device__ __forceinline__ uint4 pack8(unsigned short a0, unsigned short a1,
                                       unsigned short a2, unsigned short a3,
                                       unsigned short a4, unsigned short a5,
                                       unsigned short a6, unsigned short a7) {
  uint4 v;
  v.x = (unsigned int)a0 | ((unsigned int)a1 << 16);
  v.y = (unsigned int)a2 | ((unsigned int)a3 << 16);
  v.z = (unsigned int)a4 | ((unsigned int)a5 << 16);
  v.w = (unsigned int)a6 | ((unsigned int)a7 << 16);
  return v;
}
// async global->LDS, 16B per lane; LDS dst is wave-uniform base (+lane*16 HW)
__device__ __forceinline__ void gload_lds16(const void* g, void* l) {
  __builtin_amdgcn_global_load_lds(
      (const __attribute__((address_space(1))) unsigned int*)g,
      (__attribute__((address_space(3))) unsigned int*)l, 16, 0, 0);
}

// ---------------------------------------------------------------------------
// K0: detect mask dtype. int32 0/1 data => bytes at offset %4 != 0 are all 0.
// ---------------------------------------------------------------------------
__global__ void k_detect(const unsigned char* __restrict__ m) {
  if (threadIdx.x == 0) {
    int nz = 0;
    for (int i = 0; i < 1024; ++i)
      if ((i & 3) && m[i]) nz++;
    g_mask_is_int = (nz == 0) ? 1 : 0;
  }
}

// ===========================================================================
// FAST PATH
// ===========================================================================

// ---------------------------------------------------------------------------
// k_proj_mfma: proj = tanh(ems @ W^T + bias), split-bf16 3-term MFMA.
// Compute loop unchanged (verified). Epilogue writes hi/lo planes in BLOB
// layout: plane[T][s][slot], T = blockIdx.x (128-row tile), s = by*2+h
// (64-col stage), slot = swz(row, kb) -- so k_scores' global_load_lds
// (linear LDS write) lands pre-swizzled (m173 pattern).
// ---------------------------------------------------------------------------
__global__ __launch_bounds__(256, 2) void k_proj_mfma(
    const float* __restrict__ A, const float* __restrict__ W,
    const float* __restrict__ bias,
    unsigned short* __restrict__ outHi, unsigned short* __restrict__ outLo) {
  __shared__ unsigned short lds[32768];  // 64KB: Ahi|Alo|Bhi|Blo planes 16KB each
  char* const ldsb = (char*)lds;
  char* const pAhi = ldsb;
  char* const pAlo = ldsb + 16384;
  char* const pBhi = ldsb + 32768;
  char* const pBlo = ldsb + 49152;
  const int t = threadIdx.x, l = t & 63, wave = t >> 6;
  const int wm = (wave >> 1) * 64, wn = (wave & 1) * 64;
  const int m0 = blockIdx.x * 128, n0 = blockIdx.y * 128;
  const int r = t >> 1, h = t & 1;

  f32x4 acc[4][4];
#pragma unroll
  for (int i = 0; i < 4; ++i)
#pragma unroll
    for (int j = 0; j < 4; ++j) acc[i][j] = (f32x4){0.f, 0.f, 0.f, 0.f};

  f32x4 ar[8], br[8];

  auto load_stage = [&](int s) {
    const float* as = A + (size_t)(m0 + r) * 1024 + s * 64 + h * 32;
    const float* bs = W + (size_t)(n0 + r) * 1024 + s * 64 + h * 32;
#pragma unroll
    for (int i = 0; i < 8; ++i) {
      ar[i] = *(const f32x4*)(as + i * 4);
      br[i] = *(const f32x4*)(bs + i * 4);
    }
  };

  auto write_stage = [&]() {
    unsigned short hA[32], lA[32], hB[32], lB[32];
#pragma unroll
    for (int i = 0; i < 8; ++i)
#pragma unroll
      for (int j = 0; j < 4; ++j) {
        float x = ar[i][j];
        unsigned short hh = f2bf(x);
        hA[i * 4 + j] = hh;
        lA[i * 4 + j] = f2bf(x - bf2f(hh));
        float y = br[i][j];
        unsigned short hb = f2bf(y);
        hB[i * 4 + j] = hb;
        lB[i * 4 + j] = f2bf(y - bf2f(hb));
      }
#pragma unroll
    for (int i = 0; i < 4; ++i) {
      const int kb = h * 64 + i * 16;
      const int o = swz(r, kb);
      *(uint4*)(pAhi + o) = pack8(hA[i*8+0],hA[i*8+1],hA[i*8+2],hA[i*8+3],hA[i*8+4],hA[i*8+5],hA[i*8+6],hA[i*8+7]);
      *(uint4*)(pAlo + o) = pack8(lA[i*8+0],lA[i*8+1],lA[i*8+2],lA[i*8+3],lA[i*8+4],lA[i*8+5],lA[i*8+6],lA[i*8+7]);
      *(uint4*)(pBhi + o) = pack8(hB[i*8+0],hB[i*8+1],hB[i*8+2],hB[i*8+3],hB[i*8+4],hB[i*8+5],hB[i*8+6],hB[i*8+7]);
      *(uint4*)(pBlo + o) = pack8(lB[i*8+0],lB[i*8+1],lB[i*8+2],lB[i*8+3],lB[i*8+4],lB[i*8+5],lB[i*8+6],lB[i*8+7]);
    }
  };

  auto compute_stage = [&]() {
#pragma unroll
    for (int ks = 0; ks < 2; ++ks) {
      short8 ah[4], al[4], bh[4], bl[4];
      const int kb = ks * 64 + (l >> 4) * 16;
#pragma unroll
      for (int f = 0; f < 4; ++f) {
        const int oa = swz(wm + f * 16 + (l & 15), kb);
        ah[f] = *(const short8*)(pAhi + oa);
        al[f] = *(const short8*)(pAlo + oa);
        const int ob = swz(wn + f * 16 + (l & 15), kb);
        bh[f] = *(const short8*)(pBhi + ob);
        bl[f] = *(const short8*)(pBlo + ob);
      }
#pragma unroll
      for (int fm = 0; fm < 4; ++fm)
#pragma unroll
        for (int fn = 0; fn < 4; ++fn) {
          acc[fm][fn] = __builtin_amdgcn_mfma_f32_16x16x32_bf16(ah[fm], bh[fn], acc[fm][fn], 0, 0, 0);
          acc[fm][fn] = __builtin_amdgcn_mfma_f32_16x16x32_bf16(al[fm], bh[fn], acc[fm][fn], 0, 0, 0);
          acc[fm][fn] = __builtin_amdgcn_mfma_f32_16x16x32_bf16(ah[fm], bl[fn], acc[fm][fn], 0, 0, 0);
        }
    }
  };

  load_stage(0);
  write_stage();
  __syncthreads();
  for (int s = 0; s < 15; ++s) {
    load_stage(s + 1);
    compute_stage();
    __syncthreads();
    write_stage();
    __syncthreads();
  }
  compute_stage();

  float bcol[4];
#pragma unroll
  for (int fn = 0; fn < 4; ++fn) bcol[fn] = bias[n0 + wn + fn * 16 + (l & 15)];
#pragma unroll
  for (int fm = 0; fm < 4; ++fm)
#pragma unroll
    for (int fn = 0; fn < 4; ++fn)
#pragma unroll
      for (int q = 0; q < 4; ++q)
        acc[fm][fn][q] = ftanh(acc[fm][fn][q] + bcol[fn]);

  // epilogue: LDS transpose then BLOB stores (coalesced: slot = t*16)
  unsigned short* ldsT = lds;  // reused as [128][136]
  const size_t tbase = (size_t)blockIdx.x * 262144;  // 256KB per plane-tile
  __syncthreads();
  // hi plane
#pragma unroll
  for (int fm = 0; fm < 4; ++fm)
#pragma unroll
    for (int fn = 0; fn < 4; ++fn)
#pragma unroll
      for (int q = 0; q < 4; ++q) {
        const int rl = wm + fm * 16 + (l >> 4) * 4 + q;
        const int cl = wn + fn * 16 + (l & 15);
        ldsT[rl * 136 + cl] = f2bf(acc[fm][fn][q]);
      }
  __syncthreads();
#pragma unroll
  for (int hh = 0; hh < 2; ++hh)
#pragma unroll
    for (int p = 0; p < 4; ++p) {
      const int slot = p * 4096 + t * 16;
      const int row = slot >> 7;
      const int kb = (slot & 127) ^ ((row & 7) << 4);
      const int cl = hh * 64 + (kb >> 1);
      uint4 v = *(const uint4*)(ldsT + row * 136 + cl);
      *(uint4*)((char*)outHi + tbase + (size_t)(blockIdx.y * 2 + hh) * 16384 + slot) = v;
    }
  __syncthreads();
  // lo plane
#pragma unroll
  for (int fm = 0; fm < 4; ++fm)
#pragma unroll
    for (int fn = 0; fn < 4; ++fn)
#pragma unroll
      for (int q = 0; q < 4; ++q) {
        const int rl = wm + fm * 16 + (l >> 4) * 4 + q;
        const int cl = wn + fn * 16 + (l & 15);
        const float x = acc[fm][fn][q];
        const unsigned short hh2 = f2bf(x);
        ldsT[rl * 136 + cl] = f2bf(x - bf2f(hh2));
      }
  __syncthreads();
#pragma unroll
  for (int hh = 0; hh < 2; ++hh)
#pragma unroll
    for (int p = 0; p < 4; ++p) {
      const int slot = p * 4096 + t * 16;
      const int row = slot >> 7;
      const int kb = (slot & 127) ^ ((row & 7) << 4);
      const int cl = hh * 64 + (kb >> 1);
      uint4 v = *(const uint4*)(ldsT + row * 136 + cl);
      *(uint4*)((char*)outLo + tbase + (size_t)(blockIdx.y * 2 + hh) * 16384 + slot) = v;
    }
}

// ---------------------------------------------------------------------------
// k_scores_mfma: scores = proj @ words^T (split-bf16 3-term), f32 -> ws.
// R5 structure (128x128 tile, BK=64, 256 thr, 64KB LDS, 2 blk/CU, verified)
// with A-staging via global_load_lds from pre-swizzled blob planes:
// no A VGPR round trip, no A ds_writes, no A write conflicts.
// ---------------------------------------------------------------------------
__global__ __launch_bounds__(256, 2) void k_scores_mfma(
    const unsigned short* __restrict__ pHi, const unsigned short* __restrict__ pLo,
    const float* __restrict__ words, float* __restrict__ sc) {
  __shared__ uint4 lds4[4096];   // 64KB
  char* const pAhi = (char*)lds4;
  char* const pAlo = (char*)lds4 + 16384;
  char* const pBhi = (char*)lds4 + 32768;
  char* const pBlo = (char*)lds4 + 49152;
  const int t = threadIdx.x, l = t & 63, wave = t >> 6;
  const int wm = (wave >> 1) * 64, wn = (wave & 1) * 64;
  const int g = blockIdx.x;
  const int xcd = g & 7;
  const int slot = g >> 3;            // 0..255
  const int b = xcd + 8 * (slot >> 6);
  const int inner = slot & 63;
  const int m0 = (inner & 3) * 128;
  const int n0 = (inner >> 2) * 128;
  const int Tg = b * 4 + (m0 >> 7);   // global 128-row tile index
  const float* wB = words + (size_t)b * WN * D_;
  const int r = t >> 1, h = t & 1;

  f32x4 acc[4][4];
#pragma unroll
  for (int i = 0; i < 4; ++i)
#pragma unroll
    for (int j = 0; j < 4; ++j) acc[i][j] = (f32x4){0.f, 0.f, 0.f, 0.f};

  f32x4 br[8];

  auto load_B = [&](int s) {
    const float* bs = wB + (size_t)(n0 + r) * 1024 + s * 64 + h * 32;
#pragma unroll
    for (int i = 0; i < 8; ++i) br[i] = *(const f32x4*)(bs + i * 4);
  };

  auto dma_A = [&](int s) {
    const char* gh = (const char*)pHi + (size_t)Tg * 262144 + (size_t)s * 16384 +
                     (wave * 4) * 1024 + l * 16;
    const char* gl2 = (const char*)pLo + (size_t)Tg * 262144 + (size_t)s * 16384 +
                      (wave * 4) * 1024 + l * 16;
#pragma unroll
    for (int j = 0; j < 4; ++j) {
      gload_lds16(gh + j * 1024, pAhi + (wave * 4 + j) * 1024);
      gload_lds16(gl2 + j * 1024, pAlo + (wave * 4 + j) * 1024);
    }
  };

  auto write_B = [&]() {
    unsigned short hB[32], lB[32];
#pragma unroll
    for (int i = 0; i < 8; ++i)
#pragma unroll
      for (int j = 0; j < 4; ++j) {
        float y = br[i][j];
        unsigned short hb = f2bf(y);
        hB[i * 4 + j] = hb;
        lB[i * 4 + j] = f2bf(y - bf2f(hb));
      }
#pragma unroll
    for (int i = 0; i < 4; ++i) {
      const int o = swz(r, h * 64 + i * 16);
      *(uint4*)(pBhi + o) = pack8(hB[i*8+0],hB[i*8+1],hB[i*8+2],hB[i*8+3],hB[i*8+4],hB[i*8+5],hB[i*8+6],hB[i*8+7]);
      *(uint4*)(pBlo + o) = pack8(lB[i*8+0],lB[i*8+1],lB[i*8+2],lB[i*8+3],lB[i*8+4],lB[i*8+5],lB[i*8+6],lB[i*8+7]);
    }
  };

  auto compute_stage = [&]() {
#pragma unroll
    for (int ks = 0; ks < 2; ++ks) {
      short8 ah[4], al[4], bh[4], bl[4];
      const int kb = ks * 64 + (l >> 4) * 16;
#pragma unroll
      for (int f = 0; f < 4; ++f) {
        const int oa = swz(wm + f * 16 + (l & 15), kb);
        ah[f] = *(const short8*)(pAhi + oa);
        al[f] = *(const short8*)(pAlo + oa);
        const int ob = swz(wn + f * 16 + (l & 15), kb);
        bh[f] = *(const short8*)(pBhi + ob);
        bl[f] = *(const short8*)(pBlo + ob);
      }
#pragma unroll
      for (int fm = 0; fm < 4; ++fm)
#pragma unroll
        for (int fn = 0; fn < 4; ++fn) {
          acc[fm][fn] = __builtin_amdgcn_mfma_f32_16x16x32_bf16(ah[fm], bh[fn], acc[fm][fn], 0, 0, 0);
          acc[fm][fn] = __builtin_amdgcn_mfma_f32_16x16x32_bf16(al[fm], bh[fn], acc[fm][fn], 0, 0, 0);
          acc[fm][fn] = __builtin_amdgcn_mfma_f32_16x16x32_bf16(ah[fm], bl[fn], acc[fm][fn], 0, 0, 0);
        }
    }
  };

  load_B(0);
  dma_A(0);
  write_B();
  __syncthreads();
  for (int s = 0; s < 15; ++s) {
    load_B(s + 1);
    compute_stage();
    __syncthreads();
    dma_A(s + 1);
    write_B();
    __syncthreads();
  }
  compute_stage();

  // store f32 scores
#pragma unroll
  for (int fm = 0; fm < 4; ++fm)
#pragma unroll
    for (int fn = 0; fn < 4; ++fn)
#pragma unroll
      for (int q = 0; q < 4; ++q) {
        const int rl = wm + fm * 16 + (l >> 4) * 4 + q;
        const int cl = wn + fn * 16 + (l & 15);
        sc[((size_t)b * 512 + m0 + rl) * 2048 + n0 + cl] = acc[fm][fn][q];
      }
}

// ---------------------------------------------------------------------------
// k_softmax: unchanged (verified).
// ---------------------------------------------------------------------------
__global__ __launch_bounds__(256) void k_softmax(float* __restrict__ ws,
                                                 const void* __restrict__ mask) {
  __shared__ float red[8];
  const int row = blockIdx.x;
  const int t = threadIdx.x;
  const int wave = t >> 6;
  float* rp = ws + (size_t)row * 2048;
  float v[8];
  {
    f32x4 v0 = *(const f32x4*)(rp + t * 8);
    f32x4 v1 = *(const f32x4*)(rp + t * 8 + 4);
#pragma unroll
    for (int i = 0; i < 4; ++i) { v[i] = v0[i]; v[4 + i] = v1[i]; }
  }
  if (g_mask_is_int) {
    const int* mp = (const int*)mask + (size_t)row * 2048 + t * 8;
    const int4 m0 = *(const int4*)mp;
    const int4 m1 = *(const int4*)(mp + 4);
    if (m0.x) v[0] = -INFINITY;
    if (m0.y) v[1] = -INFINITY;
    if (m0.z) v[2] = -INFINITY;
    if (m0.w) v[3] = -INFINITY;
    if (m1.x) v[4] = -INFINITY;
    if (m1.y) v[5] = -INFINITY;
    if (m1.z) v[6] = -INFINITY;
    if (m1.w) v[7] = -INFINITY;
  } else {
    const unsigned char* mp = (const unsigned char*)mask + (size_t)row * 2048 + t * 8;
    const uchar4 m0 = *(const uchar4*)mp;
    const uchar4 m1 = *(const uchar4*)(mp + 4);
    if (m0.x) v[0] = -INFINITY;
    if (m0.y) v[1] = -INFINITY;
    if (m0.z) v[2] = -INFINITY;
    if (m0.w) v[3] = -INFINITY;
    if (m1.x) v[4] = -INFINITY;
    if (m1.y) v[5] = -INFINITY;
    if (m1.z) v[6] = -INFINITY;
    if (m1.w) v[7] = -INFINITY;
  }
  float mx = v[0];
#pragma unroll
  for (int i = 1; i < 8; ++i) mx = fmaxf(mx, v[i]);
#pragma unroll
  for (int off = 32; off > 0; off >>= 1) mx = fmaxf(mx, __shfl_xor(mx, off));
  if ((t & 63) == 0) red[wave] = mx;
  __syncthreads();
  mx = fmaxf(fmaxf(red[0], red[1]), fmaxf(red[2], red[3]));
  float e[8];
  float sum = 0.0f;
#pragma unroll
  for (int i = 0; i < 8; ++i) {
    e[i] = __expf(v[i] - mx);
    sum += e[i];
  }
#pragma unroll
  for (int off = 32; off > 0; off >>= 1) sum += __shfl_xor(sum, off);
  if ((t & 63) == 0) red[4 + wave] = sum;
  __syncthreads();
  const float tot = (red[4] + red[5]) + (red[6] + red[7]);
  const float rinv = 1.0f / tot;
  unsigned short* op = (unsigned short*)rp;
  ushort4 o0, o1;
  o0.x = f2bf(e[0] * rinv); o0.y = f2bf(e[1] * rinv);
  o0.z = f2bf(e[2] * rinv); o0.w = f2bf(e[3] * rinv);
  o1.x = f2bf(e[4] * rinv); o1.y = f2bf(e[5] * rinv);
  o1.z = f2bf(e[6] * rinv); o1.w = f2bf(e[7] * rinv);
  *(ushort4*)(op + t * 8) = o0;
  *(ushort4*)(op + t * 8 + 4) = o1;
}

// ---------------------------------------------------------------------------
// k_pv: unchanged (verified round 5).
// ---------------------------------------------------------------------------
__global__ __launch_bounds__(512, 2) void k_pv(
    const unsigned short* __restrict__ att, const float* __restrict__ words,
    float* __restrict__ out) {
  __shared__ uint4 lds4[5120];            // 80 KB: A 64KB | B 16KB
  char* const pA = (char*)lds4;
  char* const pB = (char*)lds4 + 65536;

  const int g = blockIdx.x;
  const int b = (g & 7) + 8 * (g >> 6);   // XCD-pinned batch
  const int wt = (g >> 3) & 7;
  const int w0 = wt * 128;

  const int t = threadIdx.x, l = t & 63, wv = t >> 6;
  const int wm4 = wv >> 1;
  const int wn2 = wv & 1;

  f32x4 acc[8][4];
#pragma unroll
  for (int i = 0; i < 8; ++i)
#pragma unroll
    for (int j = 0; j < 4; ++j) acc[i][j] = (f32x4){0.f, 0.f, 0.f, 0.f};

  uint4 avA[8];
  f32x4 bv0a, bv0b, bv1a, bv1b;

  const int np2 = (t & 31) * 2;
  const int wc = (t >> 5) * 8;

  auto load_stage = [&](int s) {
    const unsigned short* ab =
        att + ((size_t)(b * 512) + (t >> 3)) * 4096 + s * 64 + (t & 7) * 8;
#pragma unroll
    for (int i = 0; i < 8; ++i)
      avA[i] = *(const uint4*)(ab + (size_t)i * 64 * 4096);
    const float* wp = words + (size_t)b * WN * D_ +
                      (size_t)(s * 64 + np2) * 1024 + w0 + wc;
    bv0a = *(const f32x4*)(wp);
    bv0b = *(const f32x4*)(wp + 4);
    bv1a = *(const f32x4*)(wp + 1024);
    bv1b = *(const f32x4*)(wp + 1028);
  };

  auto write_stage = [&]() {
#pragma unroll
    for (int i = 0; i < 8; ++i) {
      const int row = (t >> 3) + i * 64;
      *(uint4*)(pA + row * 128 + (((t & 7) * 16) ^ ((row & 7) << 4))) = avA[i];
    }
#pragma unroll
    for (int i = 0; i < 8; ++i) {
      const int w = wc + i;
      const float x0 = (i < 4) ? bv0a[i & 3] : bv0b[i & 3];
      const float x1 = (i < 4) ? bv1a[i & 3] : bv1b[i & 3];
      const unsigned int pk =
          (unsigned int)f2bf(x0) | ((unsigned int)f2bf(x1) << 16);
      *(unsigned int*)(pB + w * 128 + ((np2 * 2) ^ ((w & 7) << 4))) = pk;
    }
  };

  auto compute_stage = [&]() {
#pragma unroll
    for (int ks = 0; ks < 2; ++ks) {
      short8 a[8];
      const int kb = ks * 64 + (l >> 4) * 16;
#pragma unroll
      for (int f = 0; f < 8; ++f) {
        const int row = wm4 * 128 + f * 16 + (l & 15);
        a[f] = *(const short8*)(pA + swz(row, kb));
      }
      short8 bb[4];
#pragma unroll
      for (int f = 0; f < 4; ++f) {
        const int row = wn2 * 64 + f * 16 + (l & 15);
        bb[f] = *(const short8*)(pB + swz(row, kb));
      }
#pragma unroll
      for (int fm = 0; fm < 8; ++fm)
#pragma unroll
        for (int fn = 0; fn < 4; ++fn)
          acc[fm][fn] = __builtin_amdgcn_mfma_f32_16x16x32_bf16(a[fm], bb[fn], acc[fm][fn], 0, 0, 0);
    }
  };

  load_stage(0);
  for (int s = 0; s < 32; ++s) {
    __syncthreads();
    write_stage();
    __syncthreads();
    if (s < 31) load_stage(s + 1);
    compute_stage();
  }

#pragma unroll
  for (int fm = 0; fm < 8; ++fm)
#pragma unroll
    for (int fn = 0; fn < 4; ++fn)
#pragma unroll
      for (int q = 0; q < 4; ++q) {
        const int row = wm4 * 128 + fm * 16 + (l >> 4) * 4 + q;
        const int col = w0 + wn2 * 64 + fn * 16 + (l & 15);
        out[((size_t)b * 512 + row) * 1024 + col] = acc[fm][fn][q];
      }
}

// ===========================================================================
// FALLBACK PATH (round-2 verified kernels; used if ws too small)
// ===========================================================================
__global__ __launch_bounds__(256, 4) void k_proj(const float* __restrict__ A,
                                                 const float* __restrict__ W,
                                                 const float* __restrict__ bias,
                                                 float* __restrict__ out) {
  __shared__ float As[32][132];
  __shared__ float Bs[32][132];
  const int t = threadIdx.x;
  const int m0 = blockIdx.x * 128;
  const int n0 = blockIdx.y * 128;
  const int tm = t >> 4;
  const int tn = t & 15;
  const int lrow = t >> 1;
  const int lk = (t & 1) * 16;

  float acc[8][8];
#pragma unroll
  for (int i = 0; i < 8; ++i)
#pragma unroll
    for (int j = 0; j < 8; ++j) acc[i][j] = 0.0f;

  const float* Arow = A + (size_t)(m0 + lrow) * D_ + lk;
  const float* Wrow = W + (size_t)(n0 + lrow) * D_ + lk;

  for (int k0 = 0; k0 < D_; k0 += 32) {
    __syncthreads();
#pragma unroll
    for (int j = 0; j < 4; ++j) {
      const float4 va = *(const float4*)(Arow + k0 + j * 4);
      As[lk + j * 4 + 0][lrow] = va.x;
      As[lk + j * 4 + 1][lrow] = va.y;
      As[lk + j * 4 + 2][lrow] = va.z;
      As[lk + j * 4 + 3][lrow] = va.w;
      const float4 vb = *(const float4*)(Wrow + k0 + j * 4);
      Bs[lk + j * 4 + 0][lrow] = vb.x;
      Bs[lk + j * 4 + 1][lrow] = vb.y;
      Bs[lk + j * 4 + 2][lrow] = vb.z;
      Bs[lk + j * 4 + 3][lrow] = vb.w;
    }
    __syncthreads();
#pragma unroll 8
    for (int k = 0; k < 32; ++k) {
      float a[8], bb[8];
      *(float4*)(a + 0) = *(const float4*)&As[k][tm * 4];
      *(float4*)(a + 4) = *(const float4*)&As[k][tm * 4 + 64];
      *(float4*)(bb + 0) = *(const float4*)&Bs[k][tn * 4];
      *(float4*)(bb + 4) = *(const float4*)&Bs[k][tn * 4 + 64];
#pragma unroll
      for (int i = 0; i < 8; ++i)
#pragma unroll
        for (int j = 0; j < 8; ++j) acc[i][j] = fmaf(a[i], bb[j], acc[i][j]);
    }
  }

  float bn[8];
#pragma unroll
  for (int j = 0; j < 8; ++j) bn[j] = bias[n0 + tn * 4 + (j & 3) + (j >> 2) * 64];
#pragma unroll
  for (int i = 0; i < 8; ++i) {
    const int m = m0 + tm * 4 + (i & 3) + (i >> 2) * 64;
    float4 v0, v1;
    v0.x = tanhf(acc[i][0] + bn[0]);
    v0.y = tanhf(acc[i][1] + bn[1]);
    v0.z = tanhf(acc[i][2] + bn[2]);
    v0.w = tanhf(acc[i][3] + bn[3]);
    v1.x = tanhf(acc[i][4] + bn[4]);
    v1.y = tanhf(acc[i][5] + bn[5]);
    v1.z = tanhf(acc[i][6] + bn[6]);
    v1.w = tanhf(acc[i][7] + bn[7]);
    *(float4*)(out + (size_t)m * D_ + n0 + tn * 4) = v0;
    *(float4*)(out + (size_t)m * D_ + n0 + tn * 4 + 64) = v1;
  }
}

__global__ __launch_bounds__(256) void k_scores(const float* __restrict__ words,
                                                const void* __restrict__ mask,
                                                float* __restrict__ pa) {
  __shared__ float Pt[1024][18];
  __shared__ float Ws[64][268];
  const int t = threadIdx.x;
  const int b = blockIdx.x >> 5;
  const int et = blockIdx.x & 31;
  const int e0 = et * 16;
  const int eg = t >> 5;
  const int ng = t & 31;
  const int mask_is_int = g_mask_is_int;
  const float* wbase = words + (size_t)b * WN * D_;

  {
    const int row = t >> 4;
    const int dj = (t & 15) * 4;
    const float* pr = pa + (size_t)(b * E_ + e0 + row) * D_;
#pragma unroll
    for (int rr = 0; rr < 16; ++rr) {
      const float4 v = *(const float4*)(pr + dj + rr * 64);
      Pt[dj + rr * 64 + 0][row] = v.x;
      Pt[dj + rr * 64 + 1][row] = v.y;
      Pt[dj + rr * 64 + 2][row] = v.z;
      Pt[dj + rr * 64 + 3][row] = v.w;
    }
  }

  float s[2][64];
#pragma unroll
  for (int i = 0; i < 2; ++i)
#pragma unroll
    for (int u = 0; u < 64; ++u) s[i][u] = 0.0f;

  const int nl = t >> 3;
  const int d4 = (t & 7) * 4;

  for (int dk = 0; dk < D_; dk += 64) {
#pragma unroll
    for (int nb = 0; nb < 8; ++nb) {
      __syncthreads();
#pragma unroll
      for (int rr = 0; rr < 8; ++rr) {
#pragma unroll
        for (int hh = 0; hh < 2; ++hh) {
          const int n = nl + rr * 32;
          const int d = d4 + hh * 32;
          const float4 v = *(const float4*)(wbase + (size_t)(nb * 256 + n) * D_ + dk + d);
          Ws[d + 0][n] = v.x;
          Ws[d + 1][n] = v.y;
          Ws[d + 2][n] = v.z;
          Ws[d + 3][n] = v.w;
        }
      }
      __syncthreads();
#pragma unroll 2
      for (int k = 0; k < 64; ++k) {
        const float2 a = *(const float2*)&Pt[dk + k][eg * 2];
        const float4 b0 = *(const float4*)&Ws[k][ng * 4];
        const float4 b1 = *(const float4*)&Ws[k][128 + ng * 4];
        const float aa[2] = {a.x, a.y};
        const float bb[8] = {b0.x, b0.y, b0.z, b0.w, b1.x, b1.y, b1.z, b1.w};
#pragma unroll
        for (int i = 0; i < 2; ++i)
#pragma unroll
          for (int u = 0; u < 8; ++u)
            s[i][nb * 8 + u] = fmaf(aa[i], bb[u], s[i][nb * 8 + u]);
      }
    }
  }

#pragma unroll
  for (int i = 0; i < 2; ++i) {
    const int e = e0 + eg * 2 + i;
#pragma unroll
    for (int nb = 0; nb < 8; ++nb)
#pragma unroll
      for (int q = 0; q < 2; ++q) {
        const size_t moff = (size_t)(b * E_ + e) * WN + nb * 256 + q * 128 + ng * 4;
        int mx, my, mz, mw;
        if (mask_is_int) {
          const int4 mv = *(const int4*)((const int*)mask + moff);
          mx = mv.x; my = mv.y; mz = mv.z; mw = mv.w;
        } else {
          const uchar4 mv = *(const uchar4*)((const unsigned char*)mask + moff);
          mx = mv.x; my = mv.y; mz = mv.z; mw = mv.w;
        }
        if (mx) s[i][nb * 8 + q * 4 + 0] = -1e30f;
        if (my) s[i][nb * 8 + q * 4 + 1] = -1e30f;
        if (mz) s[i][nb * 8 + q * 4 + 2] = -1e30f;
        if (mw) s[i][nb * 8 + q * 4 + 3] = -1e30f;
      }
    float m = -1e30f;
#pragma unroll
    for (int u = 0; u < 64; ++u) m = fmaxf(m, s[i][u]);
#pragma unroll
    for (int off = 16; off > 0; off >>= 1) m = fmaxf(m, __shfl_xor(m, off));
    float sum = 0.0f;
#pragma unroll
    for (int u = 0; u < 64; ++u) {
      const float p = __expf(s[i][u] - m);
      s[i][u] = p;
      sum += p;
    }
#pragma unroll
    for (int off = 16; off > 0; off >>= 1) sum += __shfl_xor(sum, off);
    const float rinv = 1.0f / sum;

    unsigned short* ar2 = (unsigned short*)(pa + (size_t)(b * E_ + e) * WN / 2);
#pragma unroll
    for (int nb = 0; nb < 8; ++nb)
#pragma unroll
      for (int q = 0; q < 2; ++q) {
        ushort4 pk;
        pk.x = f2bf(s[i][nb * 8 + q * 4 + 0] * rinv);
        pk.y = f2bf(s[i][nb * 8 + q * 4 + 1] * rinv);
        pk.z = f2bf(s[i][nb * 8 + q * 4 + 2] * rinv);
        pk.w = f2bf(s[i][nb * 8 + q * 4 + 3] * rinv);
        *(ushort4*)(ar2 + nb * 256 + q * 128 + ng * 4) = pk;
      }
  }
}

__global__ __launch_bounds__(256) void k_ctx(const float* __restrict__ words,
                                             float* __restrict__ pa) {
  __shared__ unsigned short att_s[16][2048];
  __shared__ unsigned short Wb[256][132];
  const int t = threadIdx.x;
  const int b = blockIdx.x >> 5;
  const int et = blockIdx.x & 31;
  const int e0 = et * 16;
  const int eg = t >> 5;
  const int wg = t & 31;
  const float* wbase = words + (size_t)b * WN * D_;

  {
    const int row = t >> 4;
    const int cj = t & 15;
    const uint4* pr = (const uint4*)(pa + (size_t)(b * E_ + e0 + row) * D_);
#pragma unroll
    for (int rr = 0; rr < 16; ++rr) {
      const int c = cj + rr * 16;
      const uint4 v = pr[c];
      *(uint4*)&att_s[row][c * 8] = v;
    }
  }

  float acc[2][32];
#pragma unroll
  for (int i = 0; i < 2; ++i)
#pragma unroll
    for (int u = 0; u < 32; ++u) acc[i][u] = 0.0f;

  const int nlg = t >> 5;
  const int w4 = (t & 31) * 4;

  for (int nb = 0; nb < 8; ++nb) {
#pragma unroll
    for (int q = 0; q < 8; ++q) {
      __syncthreads();
#pragma unroll
      for (int rr = 0; rr < 32; ++rr) {
        const int n = nlg + rr * 8;
        const float4 v = *(const float4*)(wbase + (size_t)(nb * 256 + n) * D_ + q * 128 + w4);
        ushort4 pk;
        pk.x = f2bf(v.x);
        pk.y = f2bf(v.y);
        pk.z = f2bf(v.z);
        pk.w = f2bf(v.w);
        *(ushort4*)&Wb[n][w4] = pk;
      }
      __syncthreads();
#pragma unroll 4
      for (int n2 = 0; n2 < 128; ++n2) {
        const int n = n2 * 2;
        const ushort4 r0 = *(const ushort4*)&Wb[n][wg * 4];
        const ushort4 r1 = *(const ushort4*)&Wb[n + 1][wg * 4];
        const float w0[4] = {bf2f(r0.x), bf2f(r0.y), bf2f(r0.z), bf2f(r0.w)};
        const float w1[4] = {bf2f(r1.x), bf2f(r1.y), bf2f(r1.z), bf2f(r1.w)};
#pragma unroll
        for (int i = 0; i < 2; ++i) {
          const unsigned int aw = *(const unsigned int*)&att_s[eg * 2 + i][nb * 256 + n];
          const float a0 = bf2f((unsigned short)(aw & 0xffffu));
          const float a1 = bf2f((unsigned short)(aw >> 16));
#pragma unroll
          for (int j = 0; j < 4; ++j)
            acc[i][q * 4 + j] = fmaf(a0, w0[j], fmaf(a1, w1[j], acc[i][q * 4 + j]));
        }
      }
    }
  }

#pragma unroll
  for (int i = 0; i < 2; ++i) {
    float* orow = pa + (size_t)(b * E_ + e0 + eg * 2 + i) * D_;
#pragma unroll
    for (int q = 0; q < 8; ++q) {
      float4 v;
      v.x = acc[i][q * 4 + 0];
      v.y = acc[i][q * 4 + 1];
      v.z = acc[i][q * 4 + 2];
      v.w = acc[i][q * 4 + 3];
      *(float4*)(orow + q * 128 + wg * 4) = v;
    }
  }
}

extern "C" void kernel_launch(void* const* d_in, const int* in_sizes, int n_in,
                              void* d_out, int out_size, void* d_ws, size_t ws_size,
                              hipStream_t stream) {
  const float* ems = (const float*)d_in[0];
  const float* words = (const float*)d_in[1];
  const void* mask = d_in[2];
  const float* w_weight = (const float*)d_in[3];
  const float* w_bias = (const float*)d_in[4];

  k_detect<<<1, 64, 0, stream>>>((const unsigned char*)mask);

  const size_t ws_need = (size_t)16384 * 2048 * 4;
  if (ws_size >= ws_need) {
    unsigned short* hiP = (unsigned short*)d_out;
    unsigned short* loP = hiP + (size_t)16384 * 1024;
    float* ws = (float*)d_ws;
    k_proj_mfma<<<dim3(128, 8), 256, 0, stream>>>(ems, w_weight, w_bias, hiP, loP);
    k_scores_mfma<<<dim3(2048), 256, 0, stream>>>(hiP, loP, words, ws);
    k_softmax<<<dim3(16384), 256, 0, stream>>>(ws, mask);
    k_pv<<<dim3(256), 512, 0, stream>>>((const unsigned short*)d_ws, words,
                                        (float*)d_out);
  } else {
    float* out = (float*)d_out;
    k_proj<<<dim3(128, 8), 256, 0, stream>>>(ems, w_weight, w_bias, out);
    k_scores<<<dim3(B_ * (E_ / 16)), 256, 0, stream>>>(words, mask, out);
    k_ctx<<<dim3(B_ * (E_ / 16)), 256, 0, stream>>>(words, out);
  }
}

// Round 9
// 672.476 us; speedup vs baseline: 1.6349x; 1.1702x over previous
//
#include <hip/hip_runtime.h>
#include <hip/hip_bf16.h>
#include <stdint.h>

#define B_  32
#define E_  512
#define WN  2048
#define D_  1024

typedef __attribute__((ext_vector_type(8))) short short8;
typedef __attribute__((ext_vector_type(4))) float f32x4;

__device__ int g_mask_is_int;   // 1 if mask buffer is int32 per element, 0 if uint8

__device__ __forceinline__ unsigned short f2bf(float f) {
  unsigned int u = __float_as_uint(f);
  u += 0x7fffu + ((u >> 16) & 1u);   // round-to-nearest-even
  return (unsigned short)(u >> 16);
}
__device__ __forceinline__ float bf2f(unsigned short s) {
  return __uint_as_float(((unsigned int)s) << 16);
}
__device__ __forceinline__ float ftanh(float x) {
  float e = __expf(2.0f * x);
  return 1.0f - 2.0f / (e + 1.0f);
}
// XOR-swizzled byte offset within a [rows][128B] LDS plane
__device__ __forceinline__ int swz(int row, int kb) {
  return row * 128 + (kb ^ ((row & 7) << 4));
}
__device__ __forceinline__ uint4 pack8(unsigned short a0, unsigned short a1,
                                       unsigned short a2, unsigned short a3,
                                       unsigned short a4, unsigned short a5,
                                       unsigned short a6, unsigned short a7) {
  uint4 v;
  v.x = (unsigned int)a0 | ((unsigned int)a1 << 16);
  v.y = (unsigned int)a2 | ((unsigned int)a3 << 16);
  v.z = (unsigned int)a4 | ((unsigned int)a5 << 16);
  v.w = (unsigned int)a6 | ((unsigned int)a7 << 16);
  return v;
}
// async global->LDS, 16B per lane; LDS dst is wave-uniform base (+lane*16 HW)
__device__ __forceinline__ void gload_lds16(const void* g, void* l) {
  __builtin_amdgcn_global_load_lds(
      (const __attribute__((address_space(1))) unsigned int*)g,
      (__attribute__((address_space(3))) unsigned int*)l, 16, 0, 0);
}

// ---------------------------------------------------------------------------
// K0: detect mask dtype. int32 0/1 data => bytes at offset %4 != 0 are all 0.
// ---------------------------------------------------------------------------
__global__ void k_detect(const unsigned char* __restrict__ m) {
  if (threadIdx.x == 0) {
    int nz = 0;
    for (int i = 0; i < 1024; ++i)
      if ((i & 3) && m[i]) nz++;
    g_mask_is_int = (nz == 0) ? 1 : 0;
  }
}

// ===========================================================================
// FAST PATH
// ===========================================================================

// ---------------------------------------------------------------------------
// k_proj_mfma: proj = tanh(ems @ W^T + bias), split-bf16 3-term MFMA.
// Epilogue writes hi/lo planes in BLOB layout (verified round 8).
// ---------------------------------------------------------------------------
__global__ __launch_bounds__(256, 2) void k_proj_mfma(
    const float* __restrict__ A, const float* __restrict__ W,
    const float* __restrict__ bias,
    unsigned short* __restrict__ outHi, unsigned short* __restrict__ outLo) {
  __shared__ unsigned short lds[32768];  // 64KB: Ahi|Alo|Bhi|Blo planes 16KB each
  char* const ldsb = (char*)lds;
  char* const pAhi = ldsb;
  char* const pAlo = ldsb + 16384;
  char* const pBhi = ldsb + 32768;
  char* const pBlo = ldsb + 49152;
  const int t = threadIdx.x, l = t & 63, wave = t >> 6;
  const int wm = (wave >> 1) * 64, wn = (wave & 1) * 64;
  const int m0 = blockIdx.x * 128, n0 = blockIdx.y * 128;
  const int r = t >> 1, h = t & 1;

  f32x4 acc[4][4];
#pragma unroll
  for (int i = 0; i < 4; ++i)
#pragma unroll
    for (int j = 0; j < 4; ++j) acc[i][j] = (f32x4){0.f, 0.f, 0.f, 0.f};

  f32x4 ar[8], br[8];

  auto load_stage = [&](int s) {
    const float* as = A + (size_t)(m0 + r) * 1024 + s * 64 + h * 32;
    const float* bs = W + (size_t)(n0 + r) * 1024 + s * 64 + h * 32;
#pragma unroll
    for (int i = 0; i < 8; ++i) {
      ar[i] = *(const f32x4*)(as + i * 4);
      br[i] = *(const f32x4*)(bs + i * 4);
    }
  };

  auto write_stage = [&]() {
    unsigned short hA[32], lA[32], hB[32], lB[32];
#pragma unroll
    for (int i = 0; i < 8; ++i)
#pragma unroll
      for (int j = 0; j < 4; ++j) {
        float x = ar[i][j];
        unsigned short hh = f2bf(x);
        hA[i * 4 + j] = hh;
        lA[i * 4 + j] = f2bf(x - bf2f(hh));
        float y = br[i][j];
        unsigned short hb = f2bf(y);
        hB[i * 4 + j] = hb;
        lB[i * 4 + j] = f2bf(y - bf2f(hb));
      }
#pragma unroll
    for (int i = 0; i < 4; ++i) {
      const int kb = h * 64 + i * 16;
      const int o = swz(r, kb);
      *(uint4*)(pAhi + o) = pack8(hA[i*8+0],hA[i*8+1],hA[i*8+2],hA[i*8+3],hA[i*8+4],hA[i*8+5],hA[i*8+6],hA[i*8+7]);
      *(uint4*)(pAlo + o) = pack8(lA[i*8+0],lA[i*8+1],lA[i*8+2],lA[i*8+3],lA[i*8+4],lA[i*8+5],lA[i*8+6],lA[i*8+7]);
      *(uint4*)(pBhi + o) = pack8(hB[i*8+0],hB[i*8+1],hB[i*8+2],hB[i*8+3],hB[i*8+4],hB[i*8+5],hB[i*8+6],hB[i*8+7]);
      *(uint4*)(pBlo + o) = pack8(lB[i*8+0],lB[i*8+1],lB[i*8+2],lB[i*8+3],lB[i*8+4],lB[i*8+5],lB[i*8+6],lB[i*8+7]);
    }
  };

  auto compute_stage = [&]() {
#pragma unroll
    for (int ks = 0; ks < 2; ++ks) {
      short8 ah[4], al[4], bh[4], bl[4];
      const int kb = ks * 64 + (l >> 4) * 16;
#pragma unroll
      for (int f = 0; f < 4; ++f) {
        const int oa = swz(wm + f * 16 + (l & 15), kb);
        ah[f] = *(const short8*)(pAhi + oa);
        al[f] = *(const short8*)(pAlo + oa);
        const int ob = swz(wn + f * 16 + (l & 15), kb);
        bh[f] = *(const short8*)(pBhi + ob);
        bl[f] = *(const short8*)(pBlo + ob);
      }
#pragma unroll
      for (int fm = 0; fm < 4; ++fm)
#pragma unroll
        for (int fn = 0; fn < 4; ++fn) {
          acc[fm][fn] = __builtin_amdgcn_mfma_f32_16x16x32_bf16(ah[fm], bh[fn], acc[fm][fn], 0, 0, 0);
          acc[fm][fn] = __builtin_amdgcn_mfma_f32_16x16x32_bf16(al[fm], bh[fn], acc[fm][fn], 0, 0, 0);
          acc[fm][fn] = __builtin_amdgcn_mfma_f32_16x16x32_bf16(ah[fm], bl[fn], acc[fm][fn], 0, 0, 0);
        }
    }
  };

  load_stage(0);
  write_stage();
  __syncthreads();
  for (int s = 0; s < 15; ++s) {
    load_stage(s + 1);
    compute_stage();
    __syncthreads();
    write_stage();
    __syncthreads();
  }
  compute_stage();

  float bcol[4];
#pragma unroll
  for (int fn = 0; fn < 4; ++fn) bcol[fn] = bias[n0 + wn + fn * 16 + (l & 15)];
#pragma unroll
  for (int fm = 0; fm < 4; ++fm)
#pragma unroll
    for (int fn = 0; fn < 4; ++fn)
#pragma unroll
      for (int q = 0; q < 4; ++q)
        acc[fm][fn][q] = ftanh(acc[fm][fn][q] + bcol[fn]);

  // epilogue: LDS transpose then BLOB stores (coalesced: slot = t*16)
  unsigned short* ldsT = lds;  // reused as [128][136]
  const size_t tbase = (size_t)blockIdx.x * 262144;  // 256KB per plane-tile
  __syncthreads();
  // hi plane
#pragma unroll
  for (int fm = 0; fm < 4; ++fm)
#pragma unroll
    for (int fn = 0; fn < 4; ++fn)
#pragma unroll
      for (int q = 0; q < 4; ++q) {
        const int rl = wm + fm * 16 + (l >> 4) * 4 + q;
        const int cl = wn + fn * 16 + (l & 15);
        ldsT[rl * 136 + cl] = f2bf(acc[fm][fn][q]);
      }
  __syncthreads();
#pragma unroll
  for (int hh = 0; hh < 2; ++hh)
#pragma unroll
    for (int p = 0; p < 4; ++p) {
      const int slot = p * 4096 + t * 16;
      const int row = slot >> 7;
      const int kb = (slot & 127) ^ ((row & 7) << 4);
      const int cl = hh * 64 + (kb >> 1);
      uint4 v = *(const uint4*)(ldsT + row * 136 + cl);
      *(uint4*)((char*)outHi + tbase + (size_t)(blockIdx.y * 2 + hh) * 16384 + slot) = v;
    }
  __syncthreads();
  // lo plane
#pragma unroll
  for (int fm = 0; fm < 4; ++fm)
#pragma unroll
    for (int fn = 0; fn < 4; ++fn)
#pragma unroll
      for (int q = 0; q < 4; ++q) {
        const int rl = wm + fm * 16 + (l >> 4) * 4 + q;
        const int cl = wn + fn * 16 + (l & 15);
        const float x = acc[fm][fn][q];
        const unsigned short hh2 = f2bf(x);
        ldsT[rl * 136 + cl] = f2bf(x - bf2f(hh2));
      }
  __syncthreads();
#pragma unroll
  for (int hh = 0; hh < 2; ++hh)
#pragma unroll
    for (int p = 0; p < 4; ++p) {
      const int slot = p * 4096 + t * 16;
      const int row = slot >> 7;
      const int kb = (slot & 127) ^ ((row & 7) << 4);
      const int cl = hh * 64 + (kb >> 1);
      uint4 v = *(const uint4*)(ldsT + row * 136 + cl);
      *(uint4*)((char*)outLo + tbase + (size_t)(blockIdx.y * 2 + hh) * 16384 + slot) = v;
    }
}

// ---------------------------------------------------------------------------
// k_scores_mfma: scores = proj @ words^T (split-bf16 3-term), f32 -> ws.
// (unchanged, verified round 8: DMA A from blob planes, 324 us)
// ---------------------------------------------------------------------------
__global__ __launch_bounds__(256, 2) void k_scores_mfma(
    const unsigned short* __restrict__ pHi, const unsigned short* __restrict__ pLo,
    const float* __restrict__ words, float* __restrict__ sc) {
  __shared__ uint4 lds4[4096];   // 64KB
  char* const pAhi = (char*)lds4;
  char* const pAlo = (char*)lds4 + 16384;
  char* const pBhi = (char*)lds4 + 32768;
  char* const pBlo = (char*)lds4 + 49152;
  const int t = threadIdx.x, l = t & 63, wave = t >> 6;
  const int wm = (wave >> 1) * 64, wn = (wave & 1) * 64;
  const int g = blockIdx.x;
  const int xcd = g & 7;
  const int slot = g >> 3;            // 0..255
  const int b = xcd + 8 * (slot >> 6);
  const int inner = slot & 63;
  const int m0 = (inner & 3) * 128;
  const int n0 = (inner >> 2) * 128;
  const int Tg = b * 4 + (m0 >> 7);   // global 128-row tile index
  const float* wB = words + (size_t)b * WN * D_;
  const int r = t >> 1, h = t & 1;

  f32x4 acc[4][4];
#pragma unroll
  for (int i = 0; i < 4; ++i)
#pragma unroll
    for (int j = 0; j < 4; ++j) acc[i][j] = (f32x4){0.f, 0.f, 0.f, 0.f};

  f32x4 br[8];

  auto load_B = [&](int s) {
    const float* bs = wB + (size_t)(n0 + r) * 1024 + s * 64 + h * 32;
#pragma unroll
    for (int i = 0; i < 8; ++i) br[i] = *(const f32x4*)(bs + i * 4);
  };

  auto dma_A = [&](int s) {
    const char* gh = (const char*)pHi + (size_t)Tg * 262144 + (size_t)s * 16384 +
                     (wave * 4) * 1024 + l * 16;
    const char* gl2 = (const char*)pLo + (size_t)Tg * 262144 + (size_t)s * 16384 +
                      (wave * 4) * 1024 + l * 16;
#pragma unroll
    for (int j = 0; j < 4; ++j) {
      gload_lds16(gh + j * 1024, pAhi + (wave * 4 + j) * 1024);
      gload_lds16(gl2 + j * 1024, pAlo + (wave * 4 + j) * 1024);
    }
  };

  auto write_B = [&]() {
    unsigned short hB[32], lB[32];
#pragma unroll
    for (int i = 0; i < 8; ++i)
#pragma unroll
      for (int j = 0; j < 4; ++j) {
        float y = br[i][j];
        unsigned short hb = f2bf(y);
        hB[i * 4 + j] = hb;
        lB[i * 4 + j] = f2bf(y - bf2f(hb));
      }
#pragma unroll
    for (int i = 0; i < 4; ++i) {
      const int o = swz(r, h * 64 + i * 16);
      *(uint4*)(pBhi + o) = pack8(hB[i*8+0],hB[i*8+1],hB[i*8+2],hB[i*8+3],hB[i*8+4],hB[i*8+5],hB[i*8+6],hB[i*8+7]);
      *(uint4*)(pBlo + o) = pack8(lB[i*8+0],lB[i*8+1],lB[i*8+2],lB[i*8+3],lB[i*8+4],lB[i*8+5],lB[i*8+6],lB[i*8+7]);
    }
  };

  auto compute_stage = [&]() {
#pragma unroll
    for (int ks = 0; ks < 2; ++ks) {
      short8 ah[4], al[4], bh[4], bl[4];
      const int kb = ks * 64 + (l >> 4) * 16;
#pragma unroll
      for (int f = 0; f < 4; ++f) {
        const int oa = swz(wm + f * 16 + (l & 15), kb);
        ah[f] = *(const short8*)(pAhi + oa);
        al[f] = *(const short8*)(pAlo + oa);
        const int ob = swz(wn + f * 16 + (l & 15), kb);
        bh[f] = *(const short8*)(pBhi + ob);
        bl[f] = *(const short8*)(pBlo + ob);
      }
#pragma unroll
      for (int fm = 0; fm < 4; ++fm)
#pragma unroll
        for (int fn = 0; fn < 4; ++fn) {
          acc[fm][fn] = __builtin_amdgcn_mfma_f32_16x16x32_bf16(ah[fm], bh[fn], acc[fm][fn], 0, 0, 0);
          acc[fm][fn] = __builtin_amdgcn_mfma_f32_16x16x32_bf16(al[fm], bh[fn], acc[fm][fn], 0, 0, 0);
          acc[fm][fn] = __builtin_amdgcn_mfma_f32_16x16x32_bf16(ah[fm], bl[fn], acc[fm][fn], 0, 0, 0);
        }
    }
  };

  load_B(0);
  dma_A(0);
  write_B();
  __syncthreads();
  for (int s = 0; s < 15; ++s) {
    load_B(s + 1);
    compute_stage();
    __syncthreads();
    dma_A(s + 1);
    write_B();
    __syncthreads();
  }
  compute_stage();

  // store f32 scores
#pragma unroll
  for (int fm = 0; fm < 4; ++fm)
#pragma unroll
    for (int fn = 0; fn < 4; ++fn)
#pragma unroll
      for (int q = 0; q < 4; ++q) {
        const int rl = wm + fm * 16 + (l >> 4) * 4 + q;
        const int cl = wn + fn * 16 + (l & 15);
        sc[((size_t)b * 512 + m0 + rl) * 2048 + n0 + cl] = acc[fm][fn][q];
      }
}

// ---------------------------------------------------------------------------
// k_softmax: reads f32 scores from ws, writes bf16 att in BLOB layout to
// d_out (proj planes dead): blob[b][stage s][slot = e*128 + (c16^((e&7)<<4))]
// -- exactly k_pv's swizzled LDS image so its global_load_lds lands right.
// ---------------------------------------------------------------------------
__global__ __launch_bounds__(256) void k_softmax(const float* __restrict__ ws,
                                                 const void* __restrict__ mask,
                                                 unsigned short* __restrict__ blob) {
  __shared__ float red[8];
  const int row = blockIdx.x;
  const int t = threadIdx.x;
  const int wave = t >> 6;
  const float* rp = ws + (size_t)row * 2048;
  float v[8];
  {
    f32x4 v0 = *(const f32x4*)(rp + t * 8);
    f32x4 v1 = *(const f32x4*)(rp + t * 8 + 4);
#pragma unroll
    for (int i = 0; i < 4; ++i) { v[i] = v0[i]; v[4 + i] = v1[i]; }
  }
  if (g_mask_is_int) {
    const int* mp = (const int*)mask + (size_t)row * 2048 + t * 8;
    const int4 m0 = *(const int4*)mp;
    const int4 m1 = *(const int4*)(mp + 4);
    if (m0.x) v[0] = -INFINITY;
    if (m0.y) v[1] = -INFINITY;
    if (m0.z) v[2] = -INFINITY;
    if (m0.w) v[3] = -INFINITY;
    if (m1.x) v[4] = -INFINITY;
    if (m1.y) v[5] = -INFINITY;
    if (m1.z) v[6] = -INFINITY;
    if (m1.w) v[7] = -INFINITY;
  } else {
    const unsigned char* mp = (const unsigned char*)mask + (size_t)row * 2048 + t * 8;
    const uchar4 m0 = *(const uchar4*)mp;
    const uchar4 m1 = *(const uchar4*)(mp + 4);
    if (m0.x) v[0] = -INFINITY;
    if (m0.y) v[1] = -INFINITY;
    if (m0.z) v[2] = -INFINITY;
    if (m0.w) v[3] = -INFINITY;
    if (m1.x) v[4] = -INFINITY;
    if (m1.y) v[5] = -INFINITY;
    if (m1.z) v[6] = -INFINITY;
    if (m1.w) v[7] = -INFINITY;
  }
  float mx = v[0];
#pragma unroll
  for (int i = 1; i < 8; ++i) mx = fmaxf(mx, v[i]);
#pragma unroll
  for (int off = 32; off > 0; off >>= 1) mx = fmaxf(mx, __shfl_xor(mx, off));
  if ((t & 63) == 0) red[wave] = mx;
  __syncthreads();
  mx = fmaxf(fmaxf(red[0], red[1]), fmaxf(red[2], red[3]));
  float e[8];
  float sum = 0.0f;
#pragma unroll
  for (int i = 0; i < 8; ++i) {
    e[i] = __expf(v[i] - mx);
    sum += e[i];
  }
#pragma unroll
  for (int off = 32; off > 0; off >>= 1) sum += __shfl_xor(sum, off);
  if ((t & 63) == 0) red[4 + wave] = sum;
  __syncthreads();
  const float tot = (red[4] + red[5]) + (red[6] + red[7]);
  const float rinv = 1.0f / tot;

  const int b = row >> 9, ee = row & 511;
  const uint4 pk = pack8(f2bf(e[0] * rinv), f2bf(e[1] * rinv),
                         f2bf(e[2] * rinv), f2bf(e[3] * rinv),
                         f2bf(e[4] * rinv), f2bf(e[5] * rinv),
                         f2bf(e[6] * rinv), f2bf(e[7] * rinv));
  char* dst = (char*)blob + (size_t)b * 2097152 + (size_t)(t >> 3) * 65536 +
              ee * 128 + (((t & 7) * 16) ^ ((ee & 7) << 4));
  *(uint4*)dst = pk;
}

// ---------------------------------------------------------------------------
// k_pv: ctx = att @ words. BM=512 x BW=128, K=2048, 512 thr / 8 waves.
// Double-buffered LDS (160KB): A via global_load_lds from att blob (d_out),
// B (words^T bf16) manual transposed staging. ONE barrier per stage.
// ctx written to ws; k_copy moves it to d_out.
// ---------------------------------------------------------------------------
__global__ __launch_bounds__(512) void k_pv(
    const unsigned short* __restrict__ blob, const float* __restrict__ words,
    float* __restrict__ ctx) {
  __shared__ uint4 lds4[10240];           // 160KB: A0 64K | A1 64K | B0 16K | B1 16K
  char* pAc = (char*)lds4;
  char* pAn = (char*)lds4 + 65536;
  char* pBc = (char*)lds4 + 131072;
  char* pBn = (char*)lds4 + 147456;

  const int g = blockIdx.x;
  const int b = (g & 7) + 8 * (g >> 6);   // XCD-pinned batch
  const int wt = (g >> 3) & 7;
  const int w0 = wt * 128;

  const int t = threadIdx.x, l = t & 63, wv = t >> 6;
  const int wm4 = wv >> 1;    // 0..3 -> m base = wm4*128
  const int wn2 = wv & 1;     // 0..1 -> w base (local) = wn2*64

  const char* blobB = (const char*)blob + (size_t)b * 2097152;

  f32x4 acc[8][4];
#pragma unroll
  for (int i = 0; i < 8; ++i)
#pragma unroll
    for (int j = 0; j < 4; ++j) acc[i][j] = (f32x4){0.f, 0.f, 0.f, 0.f};

  f32x4 bv0a, bv0b, bv1a, bv1b;
  const int np2 = (t & 31) * 2;        // n-pair base within stage (0..62)
  const int wc = (t >> 5) * 8;         // w-chunk base (0..120)

  auto dma_A = [&](int s, char* pA) {
    const char* gp = blobB + (size_t)s * 65536 + wv * 8192 + l * 16;
#pragma unroll
    for (int j = 0; j < 8; ++j)
      gload_lds16(gp + j * 1024, pA + wv * 8192 + j * 1024);
  };

  auto load_B = [&](int s) {
    const float* wp = words + (size_t)b * WN * D_ +
                      (size_t)(s * 64 + np2) * 1024 + w0 + wc;
    bv0a = *(const f32x4*)(wp);
    bv0b = *(const f32x4*)(wp + 4);
    bv1a = *(const f32x4*)(wp + 1024);
    bv1b = *(const f32x4*)(wp + 1028);
  };

  auto write_B = [&](char* pB) {
#pragma unroll
    for (int i = 0; i < 8; ++i) {
      const int w = wc + i;
      const float x0 = (i < 4) ? bv0a[i & 3] : bv0b[i & 3];
      const float x1 = (i < 4) ? bv1a[i & 3] : bv1b[i & 3];
      const unsigned int pk =
          (unsigned int)f2bf(x0) | ((unsigned int)f2bf(x1) << 16);
      *(unsigned int*)(pB + w * 128 + ((np2 * 2) ^ ((w & 7) << 4))) = pk;
    }
  };

  auto compute_stage = [&](const char* pA, const char* pB) {
#pragma unroll
    for (int ks = 0; ks < 2; ++ks) {
      short8 a[8];
      const int kb = ks * 64 + (l >> 4) * 16;
#pragma unroll
      for (int f = 0; f < 8; ++f) {
        const int row = wm4 * 128 + f * 16 + (l & 15);
        a[f] = *(const short8*)(pA + swz(row, kb));
      }
      short8 bb[4];
#pragma unroll
      for (int f = 0; f < 4; ++f) {
        const int row = wn2 * 64 + f * 16 + (l & 15);
        bb[f] = *(const short8*)(pB + swz(row, kb));
      }
#pragma unroll
      for (int fm = 0; fm < 8; ++fm)
#pragma unroll
        for (int fn = 0; fn < 4; ++fn)
          acc[fm][fn] = __builtin_amdgcn_mfma_f32_16x16x32_bf16(a[fm], bb[fn], acc[fm][fn], 0, 0, 0);
    }
  };

  // prologue: fill buffer 0
  load_B(0);
  dma_A(0, pAc);
  write_B(pBc);
  __syncthreads();

  for (int s = 0; s < 32; ++s) {
    if (s < 31) {
      load_B(s + 1);       // global->regs (latency hidden under compute)
      dma_A(s + 1, pAn);   // async DMA into next buffer
    }
    compute_stage(pAc, pBc);
    if (s < 31) write_B(pBn);
    __syncthreads();       // drains DMA (vmcnt) + ds_writes (lgkm)
    char* t1 = pAc; pAc = pAn; pAn = t1;
    char* t2 = pBc; pBc = pBn; pBn = t2;
  }

  // epilogue: ctx into ws
#pragma unroll
  for (int fm = 0; fm < 8; ++fm)
#pragma unroll
    for (int fn = 0; fn < 4; ++fn)
#pragma unroll
      for (int q = 0; q < 4; ++q) {
        const int row = wm4 * 128 + fm * 16 + (l >> 4) * 4 + q;
        const int col = w0 + wn2 * 64 + fn * 16 + (l & 15);
        ctx[((size_t)b * 512 + row) * 1024 + col] = acc[fm][fn][q];
      }
}

// ---------------------------------------------------------------------------
// k_copy: ctx (ws) -> d_out, float4 grid-stride.
// ---------------------------------------------------------------------------
__global__ __launch_bounds__(256) void k_copy(const float4* __restrict__ src,
                                              float4* __restrict__ dst) {
  const int n4 = 16384 * 1024 / 4;
  int i = blockIdx.x * 256 + threadIdx.x;
  const int stride = gridDim.x * 256;
  for (; i < n4; i += stride) dst[i] = src[i];
}

// ===========================================================================
// FALLBACK PATH (round-2 verified kernels; used if ws too small)
// ===========================================================================
__global__ __launch_bounds__(256, 4) void k_proj(const float* __restrict__ A,
                                                 const float* __restrict__ W,
                                                 const float* __restrict__ bias,
                                                 float* __restrict__ out) {
  __shared__ float As[32][132];
  __shared__ float Bs[32][132];
  const int t = threadIdx.x;
  const int m0 = blockIdx.x * 128;
  const int n0 = blockIdx.y * 128;
  const int tm = t >> 4;
  const int tn = t & 15;
  const int lrow = t >> 1;
  const int lk = (t & 1) * 16;

  float acc[8][8];
#pragma unroll
  for (int i = 0; i < 8; ++i)
#pragma unroll
    for (int j = 0; j < 8; ++j) acc[i][j] = 0.0f;

  const float* Arow = A + (size_t)(m0 + lrow) * D_ + lk;
  const float* Wrow = W + (size_t)(n0 + lrow) * D_ + lk;

  for (int k0 = 0; k0 < D_; k0 += 32) {
    __syncthreads();
#pragma unroll
    for (int j = 0; j < 4; ++j) {
      const float4 va = *(const float4*)(Arow + k0 + j * 4);
      As[lk + j * 4 + 0][lrow] = va.x;
      As[lk + j * 4 + 1][lrow] = va.y;
      As[lk + j * 4 + 2][lrow] = va.z;
      As[lk + j * 4 + 3][lrow] = va.w;
      const float4 vb = *(const float4*)(Wrow + k0 + j * 4);
      Bs[lk + j * 4 + 0][lrow] = vb.x;
      Bs[lk + j * 4 + 1][lrow] = vb.y;
      Bs[lk + j * 4 + 2][lrow] = vb.z;
      Bs[lk + j * 4 + 3][lrow] = vb.w;
    }
    __syncthreads();
#pragma unroll 8
    for (int k = 0; k < 32; ++k) {
      float a[8], bb[8];
      *(float4*)(a + 0) = *(const float4*)&As[k][tm * 4];
      *(float4*)(a + 4) = *(const float4*)&As[k][tm * 4 + 64];
      *(float4*)(bb + 0) = *(const float4*)&Bs[k][tn * 4];
      *(float4*)(bb + 4) = *(const float4*)&Bs[k][tn * 4 + 64];
#pragma unroll
      for (int i = 0; i < 8; ++i)
#pragma unroll
        for (int j = 0; j < 8; ++j) acc[i][j] = fmaf(a[i], bb[j], acc[i][j]);
    }
  }

  float bn[8];
#pragma unroll
  for (int j = 0; j < 8; ++j) bn[j] = bias[n0 + tn * 4 + (j & 3) + (j >> 2) * 64];
#pragma unroll
  for (int i = 0; i < 8; ++i) {
    const int m = m0 + tm * 4 + (i & 3) + (i >> 2) * 64;
    float4 v0, v1;
    v0.x = tanhf(acc[i][0] + bn[0]);
    v0.y = tanhf(acc[i][1] + bn[1]);
    v0.z = tanhf(acc[i][2] + bn[2]);
    v0.w = tanhf(acc[i][3] + bn[3]);
    v1.x = tanhf(acc[i][4] + bn[4]);
    v1.y = tanhf(acc[i][5] + bn[5]);
    v1.z = tanhf(acc[i][6] + bn[6]);
    v1.w = tanhf(acc[i][7] + bn[7]);
    *(float4*)(out + (size_t)m * D_ + n0 + tn * 4) = v0;
    *(float4*)(out + (size_t)m * D_ + n0 + tn * 4 + 64) = v1;
  }
}

__global__ __launch_bounds__(256) void k_scores(const float* __restrict__ words,
                                                const void* __restrict__ mask,
                                                float* __restrict__ pa) {
  __shared__ float Pt[1024][18];
  __shared__ float Ws[64][268];
  const int t = threadIdx.x;
  const int b = blockIdx.x >> 5;
  const int et = blockIdx.x & 31;
  const int e0 = et * 16;
  const int eg = t >> 5;
  const int ng = t & 31;
  const int mask_is_int = g_mask_is_int;
  const float* wbase = words + (size_t)b * WN * D_;

  {
    const int row = t >> 4;
    const int dj = (t & 15) * 4;
    const float* pr = pa + (size_t)(b * E_ + e0 + row) * D_;
#pragma unroll
    for (int rr = 0; rr < 16; ++rr) {
      const float4 v = *(const float4*)(pr + dj + rr * 64);
      Pt[dj + rr * 64 + 0][row] = v.x;
      Pt[dj + rr * 64 + 1][row] = v.y;
      Pt[dj + rr * 64 + 2][row] = v.z;
      Pt[dj + rr * 64 + 3][row] = v.w;
    }
  }

  float s[2][64];
#pragma unroll
  for (int i = 0; i < 2; ++i)
#pragma unroll
    for (int u = 0; u < 64; ++u) s[i][u] = 0.0f;

  const int nl = t >> 3;
  const int d4 = (t & 7) * 4;

  for (int dk = 0; dk < D_; dk += 64) {
#pragma unroll
    for (int nb = 0; nb < 8; ++nb) {
      __syncthreads();
#pragma unroll
      for (int rr = 0; rr < 8; ++rr) {
#pragma unroll
        for (int hh = 0; hh < 2; ++hh) {
          const int n = nl + rr * 32;
          const int d = d4 + hh * 32;
          const float4 v = *(const float4*)(wbase + (size_t)(nb * 256 + n) * D_ + dk + d);
          Ws[d + 0][n] = v.x;
          Ws[d + 1][n] = v.y;
          Ws[d + 2][n] = v.z;
          Ws[d + 3][n] = v.w;
        }
      }
      __syncthreads();
#pragma unroll 2
      for (int k = 0; k < 64; ++k) {
        const float2 a = *(const float2*)&Pt[dk + k][eg * 2];
        const float4 b0 = *(const float4*)&Ws[k][ng * 4];
        const float4 b1 = *(const float4*)&Ws[k][128 + ng * 4];
        const float aa[2] = {a.x, a.y};
        const float bb[8] = {b0.x, b0.y, b0.z, b0.w, b1.x, b1.y, b1.z, b1.w};
#pragma unroll
        for (int i = 0; i < 2; ++i)
#pragma unroll
          for (int u = 0; u < 8; ++u)
            s[i][nb * 8 + u] = fmaf(aa[i], bb[u], s[i][nb * 8 + u]);
      }
    }
  }

#pragma unroll
  for (int i = 0; i < 2; ++i) {
    const int e = e0 + eg * 2 + i;
#pragma unroll
    for (int nb = 0; nb < 8; ++nb)
#pragma unroll
      for (int q = 0; q < 2; ++q) {
        const size_t moff = (size_t)(b * E_ + e) * WN + nb * 256 + q * 128 + ng * 4;
        int mx, my, mz, mw;
        if (mask_is_int) {
          const int4 mv = *(const int4*)((const int*)mask + moff);
          mx = mv.x; my = mv.y; mz = mv.z; mw = mv.w;
        } else {
          const uchar4 mv = *(const uchar4*)((const unsigned char*)mask + moff);
          mx = mv.x; my = mv.y; mz = mv.z; mw = mv.w;
        }
        if (mx) s[i][nb * 8 + q * 4 + 0] = -1e30f;
        if (my) s[i][nb * 8 + q * 4 + 1] = -1e30f;
        if (mz) s[i][nb * 8 + q * 4 + 2] = -1e30f;
        if (mw) s[i][nb * 8 + q * 4 + 3] = -1e30f;
      }
    float m = -1e30f;
#pragma unroll
    for (int u = 0; u < 64; ++u) m = fmaxf(m, s[i][u]);
#pragma unroll
    for (int off = 16; off > 0; off >>= 1) m = fmaxf(m, __shfl_xor(m, off));
    float sum = 0.0f;
#pragma unroll
    for (int u = 0; u < 64; ++u) {
      const float p = __expf(s[i][u] - m);
      s[i][u] = p;
      sum += p;
    }
#pragma unroll
    for (int off = 16; off > 0; off >>= 1) sum += __shfl_xor(sum, off);
    const float rinv = 1.0f / sum;

    unsigned short* ar2 = (unsigned short*)(pa + (size_t)(b * E_ + e) * WN / 2);
#pragma unroll
    for (int nb = 0; nb < 8; ++nb)
#pragma unroll
      for (int q = 0; q < 2; ++q) {
        ushort4 pk;
        pk.x = f2bf(s[i][nb * 8 + q * 4 + 0] * rinv);
        pk.y = f2bf(s[i][nb * 8 + q * 4 + 1] * rinv);
        pk.z = f2bf(s[i][nb * 8 + q * 4 + 2] * rinv);
        pk.w = f2bf(s[i][nb * 8 + q * 4 + 3] * rinv);
        *(ushort4*)(ar2 + nb * 256 + q * 128 + ng * 4) = pk;
      }
  }
}

__global__ __launch_bounds__(256) void k_ctx(const float* __restrict__ words,
                                             float* __restrict__ pa) {
  __shared__ unsigned short att_s[16][2048];
  __shared__ unsigned short Wb[256][132];
  const int t = threadIdx.x;
  const int b = blockIdx.x >> 5;
  const int et = blockIdx.x & 31;
  const int e0 = et * 16;
  const int eg = t >> 5;
  const int wg = t & 31;
  const float* wbase = words + (size_t)b * WN * D_;

  {
    const int row = t >> 4;
    const int cj = t & 15;
    const uint4* pr = (const uint4*)(pa + (size_t)(b * E_ + e0 + row) * D_);
#pragma unroll
    for (int rr = 0; rr < 16; ++rr) {
      const int c = cj + rr * 16;
      const uint4 v = pr[c];
      *(uint4*)&att_s[row][c * 8] = v;
    }
  }

  float acc[2][32];
#pragma unroll
  for (int i = 0; i < 2; ++i)
#pragma unroll
    for (int u = 0; u < 32; ++u) acc[i][u] = 0.0f;

  const int nlg = t >> 5;
  const int w4 = (t & 31) * 4;

  for (int nb = 0; nb < 8; ++nb) {
#pragma unroll
    for (int q = 0; q < 8; ++q) {
      __syncthreads();
#pragma unroll
      for (int rr = 0; rr < 32; ++rr) {
        const int n = nlg + rr * 8;
        const float4 v = *(const float4*)(wbase + (size_t)(nb * 256 + n) * D_ + q * 128 + w4);
        ushort4 pk;
        pk.x = f2bf(v.x);
        pk.y = f2bf(v.y);
        pk.z = f2bf(v.z);
        pk.w = f2bf(v.w);
        *(ushort4*)&Wb[n][w4] = pk;
      }
      __syncthreads();
#pragma unroll 4
      for (int n2 = 0; n2 < 128; ++n2) {
        const int n = n2 * 2;
        const ushort4 r0 = *(const ushort4*)&Wb[n][wg * 4];
        const ushort4 r1 = *(const ushort4*)&Wb[n + 1][wg * 4];
        const float w0[4] = {bf2f(r0.x), bf2f(r0.y), bf2f(r0.z), bf2f(r0.w)};
        const float w1[4] = {bf2f(r1.x), bf2f(r1.y), bf2f(r1.z), bf2f(r1.w)};
#pragma unroll
        for (int i = 0; i < 2; ++i) {
          const unsigned int aw = *(const unsigned int*)&att_s[eg * 2 + i][nb * 256 + n];
          const float a0 = bf2f((unsigned short)(aw & 0xffffu));
          const float a1 = bf2f((unsigned short)(aw >> 16));
#pragma unroll
          for (int j = 0; j < 4; ++j)
            acc[i][q * 4 + j] = fmaf(a0, w0[j], fmaf(a1, w1[j], acc[i][q * 4 + j]));
        }
      }
    }
  }

#pragma unroll
  for (int i = 0; i < 2; ++i) {
    float* orow = pa + (size_t)(b * E_ + e0 + eg * 2 + i) * D_;
#pragma unroll
    for (int q = 0; q < 8; ++q) {
      float4 v;
      v.x = acc[i][q * 4 + 0];
      v.y = acc[i][q * 4 + 1];
      v.z = acc[i][q * 4 + 2];
      v.w = acc[i][q * 4 + 3];
      *(float4*)(orow + q * 128 + wg * 4) = v;
    }
  }
}

extern "C" void kernel_launch(void* const* d_in, const int* in_sizes, int n_in,
                              void* d_out, int out_size, void* d_ws, size_t ws_size,
                              hipStream_t stream) {
  const float* ems = (const float*)d_in[0];
  const float* words = (const float*)d_in[1];
  const void* mask = d_in[2];
  const float* w_weight = (const float*)d_in[3];
  const float* w_bias = (const float*)d_in[4];

  k_detect<<<1, 64, 0, stream>>>((const unsigned char*)mask);

  const size_t ws_need = (size_t)16384 * 2048 * 4;
  if (ws_size >= ws_need) {
    unsigned short* hiP = (unsigned short*)d_out;
    unsigned short* loP = hiP + (size_t)16384 * 1024;
    float* ws = (float*)d_ws;
    // 1. proj planes (blob layout) -> d_out
    k_proj_mfma<<<dim3(128, 8), 256, 0, stream>>>(ems, w_weight, w_bias, hiP, loP);
    // 2. scores (f32) -> ws
    k_scores_mfma<<<dim3(2048), 256, 0, stream>>>(hiP, loP, words, ws);
    // 3. softmax: ws scores -> att blob in d_out (planes dead)
    k_softmax<<<dim3(16384), 256, 0, stream>>>(ws, mask, (unsigned short*)d_out);
    // 4. pv: att blob (d_out) @ words -> ctx in ws (scores dead)
    k_pv<<<dim3(256), 512, 0, stream>>>((const unsigned short*)d_out, words, ws);
    // 5. ctx ws -> d_out
    k_copy<<<dim3(2048), 256, 0, stream>>>((const float4*)d_ws, (float4*)d_out);
  } else {
    float* out = (float*)d_out;
    k_proj<<<dim3(128, 8), 256, 0, stream>>>(ems, w_weight, w_bias, out);
    k_scores<<<dim3(B_ * (E_ / 16)), 256, 0, stream>>>(words, mask, out);
    k_ctx<<<dim3(B_ * (E_ / 16)), 256, 0, stream>>>(words, out);
  }
}

// Round 10
// 579.660 us; speedup vs baseline: 1.8966x; 1.1601x over previous
//
#include <hip/hip_runtime.h>
#include <hip/hip_bf16.h>
#include <stdint.h>

#define B_  32
#define E_  512
#define WN  2048
#define D_  1024

typedef __attribute__((ext_vector_type(8))) short short8;
typedef __attribute__((ext_vector_type(4))) float f32x4;

__device__ int g_mask_is_int;   // 1 if mask buffer is int32 per element, 0 if uint8

__device__ __forceinline__ unsigned short f2bf(float f) {
  unsigned int u = __float_as_uint(f);
  u += 0x7fffu + ((u >> 16) & 1u);   // round-to-nearest-even
  return (unsigned short)(u >> 16);
}
__device__ __forceinline__ float bf2f(unsigned short s) {
  return __uint_as_float(((unsigned int)s) << 16);
}
__device__ __forceinline__ float ftanh(float x) {
  float e = __expf(2.0f * x);
  return 1.0f - 2.0f / (e + 1.0f);
}
// XOR-swizzled byte offset within a [rows][128B] LDS plane
__device__ __forceinline__ int swz(int row, int kb) {
  return row * 128 + (kb ^ ((row & 7) << 4));
}
// 64B-row swizzle: F(X) = X ^ ((X>>6 & 7) << 4), X = row*64 + kb (kb<64)
__device__ __forceinline__ int swz64x(int row, int kb) {
  const int X = row * 64 + kb;
  return X ^ (((X >> 6) & 7) << 4);
}
__device__ __forceinline__ uint4 pack8(unsigned short a0, unsigned short a1,
                                       unsigned short a2, unsigned short a3,
                                       unsigned short a4, unsigned short a5,
                                       unsigned short a6, unsigned short a7) {
  uint4 v;
  v.x = (unsigned int)a0 | ((unsigned int)a1 << 16);
  v.y = (unsigned int)a2 | ((unsigned int)a3 << 16);
  v.z = (unsigned int)a4 | ((unsigned int)a5 << 16);
  v.w = (unsigned int)a6 | ((unsigned int)a7 << 16);
  return v;
}
// async global->LDS, 16B per lane; LDS dst is wave-uniform base (+lane*16 HW)
__device__ __forceinline__ void gload_lds16(const void* g, void* l) {
  __builtin_amdgcn_global_load_lds(
      (const __attribute__((address_space(1))) unsigned int*)g,
      (__attribute__((address_space(3))) unsigned int*)l, 16, 0, 0);
}

// ---------------------------------------------------------------------------
// K0: detect mask dtype. int32 0/1 data => bytes at offset %4 != 0 are all 0.
// ---------------------------------------------------------------------------
__global__ void k_detect(const unsigned char* __restrict__ m) {
  if (threadIdx.x == 0) {
    int nz = 0;
    for (int i = 0; i < 1024; ++i)
      if ((i & 3) && m[i]) nz++;
    g_mask_is_int = (nz == 0) ? 1 : 0;
  }
}

// ===========================================================================
// FAST PATH
// ===========================================================================

// ---------------------------------------------------------------------------
// k_proj_mfma: proj = tanh(ems @ W^T + bias), split-bf16 3-term MFMA.
// Epilogue writes hi/lo planes in BLOB layout for k_scores' DMA:
// plane[T=bx][S=by*4+sb : 32-k stage][L], where blob[L] holds element at
// X = inverse-swz64x(L): row = X>>6, w_local = sb*32 + (X&63)/2.
// ---------------------------------------------------------------------------
__global__ __launch_bounds__(256, 2) void k_proj_mfma(
    const float* __restrict__ A, const float* __restrict__ W,
    const float* __restrict__ bias,
    unsigned short* __restrict__ outHi, unsigned short* __restrict__ outLo) {
  __shared__ unsigned short lds[32768];  // 64KB: Ahi|Alo|Bhi|Blo planes 16KB each
  char* const ldsb = (char*)lds;
  char* const pAhi = ldsb;
  char* const pAlo = ldsb + 16384;
  char* const pBhi = ldsb + 32768;
  char* const pBlo = ldsb + 49152;
  const int t = threadIdx.x, l = t & 63, wave = t >> 6;
  const int wm = (wave >> 1) * 64, wn = (wave & 1) * 64;
  const int m0 = blockIdx.x * 128, n0 = blockIdx.y * 128;
  const int r = t >> 1, h = t & 1;

  f32x4 acc[4][4];
#pragma unroll
  for (int i = 0; i < 4; ++i)
#pragma unroll
    for (int j = 0; j < 4; ++j) acc[i][j] = (f32x4){0.f, 0.f, 0.f, 0.f};

  f32x4 ar[8], br[8];

  auto load_stage = [&](int s) {
    const float* as = A + (size_t)(m0 + r) * 1024 + s * 64 + h * 32;
    const float* bs = W + (size_t)(n0 + r) * 1024 + s * 64 + h * 32;
#pragma unroll
    for (int i = 0; i < 8; ++i) {
      ar[i] = *(const f32x4*)(as + i * 4);
      br[i] = *(const f32x4*)(bs + i * 4);
    }
  };

  auto write_stage = [&]() {
    unsigned short hA[32], lA[32], hB[32], lB[32];
#pragma unroll
    for (int i = 0; i < 8; ++i)
#pragma unroll
      for (int j = 0; j < 4; ++j) {
        float x = ar[i][j];
        unsigned short hh = f2bf(x);
        hA[i * 4 + j] = hh;
        lA[i * 4 + j] = f2bf(x - bf2f(hh));
        float y = br[i][j];
        unsigned short hb = f2bf(y);
        hB[i * 4 + j] = hb;
        lB[i * 4 + j] = f2bf(y - bf2f(hb));
      }
#pragma unroll
    for (int i = 0; i < 4; ++i) {
      const int kb = h * 64 + i * 16;
      const int o = swz(r, kb);
      *(uint4*)(pAhi + o) = pack8(hA[i*8+0],hA[i*8+1],hA[i*8+2],hA[i*8+3],hA[i*8+4],hA[i*8+5],hA[i*8+6],hA[i*8+7]);
      *(uint4*)(pAlo + o) = pack8(lA[i*8+0],lA[i*8+1],lA[i*8+2],lA[i*8+3],lA[i*8+4],lA[i*8+5],lA[i*8+6],lA[i*8+7]);
      *(uint4*)(pBhi + o) = pack8(hB[i*8+0],hB[i*8+1],hB[i*8+2],hB[i*8+3],hB[i*8+4],hB[i*8+5],hB[i*8+6],hB[i*8+7]);
      *(uint4*)(pBlo + o) = pack8(lB[i*8+0],lB[i*8+1],lB[i*8+2],lB[i*8+3],lB[i*8+4],lB[i*8+5],lB[i*8+6],lB[i*8+7]);
    }
  };

  auto compute_stage = [&]() {
#pragma unroll
    for (int ks = 0; ks < 2; ++ks) {
      short8 ah[4], al[4], bh[4], bl[4];
      const int kb = ks * 64 + (l >> 4) * 16;
#pragma unroll
      for (int f = 0; f < 4; ++f) {
        const int oa = swz(wm + f * 16 + (l & 15), kb);
        ah[f] = *(const short8*)(pAhi + oa);
        al[f] = *(const short8*)(pAlo + oa);
        const int ob = swz(wn + f * 16 + (l & 15), kb);
        bh[f] = *(const short8*)(pBhi + ob);
        bl[f] = *(const short8*)(pBlo + ob);
      }
#pragma unroll
      for (int fm = 0; fm < 4; ++fm)
#pragma unroll
        for (int fn = 0; fn < 4; ++fn) {
          acc[fm][fn] = __builtin_amdgcn_mfma_f32_16x16x32_bf16(ah[fm], bh[fn], acc[fm][fn], 0, 0, 0);
          acc[fm][fn] = __builtin_amdgcn_mfma_f32_16x16x32_bf16(al[fm], bh[fn], acc[fm][fn], 0, 0, 0);
          acc[fm][fn] = __builtin_amdgcn_mfma_f32_16x16x32_bf16(ah[fm], bl[fn], acc[fm][fn], 0, 0, 0);
        }
    }
  };

  load_stage(0);
  write_stage();
  __syncthreads();
  for (int s = 0; s < 15; ++s) {
    load_stage(s + 1);
    compute_stage();
    __syncthreads();
    write_stage();
    __syncthreads();
  }
  compute_stage();

  float bcol[4];
#pragma unroll
  for (int fn = 0; fn < 4; ++fn) bcol[fn] = bias[n0 + wn + fn * 16 + (l & 15)];
#pragma unroll
  for (int fm = 0; fm < 4; ++fm)
#pragma unroll
    for (int fn = 0; fn < 4; ++fn)
#pragma unroll
      for (int q = 0; q < 4; ++q)
        acc[fm][fn][q] = ftanh(acc[fm][fn][q] + bcol[fn]);

  // epilogue: LDS transpose then BLOB stores (coalesced: L = p*4096 + t*16)
  unsigned short* ldsT = lds;  // reused as [128][136]
  const size_t tbase = (size_t)blockIdx.x * 262144;  // 256KB per plane-tile
  __syncthreads();
  // hi plane
#pragma unroll
  for (int fm = 0; fm < 4; ++fm)
#pragma unroll
    for (int fn = 0; fn < 4; ++fn)
#pragma unroll
      for (int q = 0; q < 4; ++q) {
        const int rl = wm + fm * 16 + (l >> 4) * 4 + q;
        const int cl = wn + fn * 16 + (l & 15);
        ldsT[rl * 136 + cl] = f2bf(acc[fm][fn][q]);
      }
  __syncthreads();
#pragma unroll
  for (int sb = 0; sb < 4; ++sb)
#pragma unroll
    for (int p = 0; p < 2; ++p) {
      const int L = p * 4096 + t * 16;
      const int x6 = ((L >> 6) ^ (L >> 8)) & 1;
      const int x5 = ((L >> 5) ^ (L >> 7)) & 1;
      const int x4 = ((L >> 4) ^ (L >> 6) ^ (L >> 8)) & 1;
      const int X = (L & ~0x70) | (x6 << 6) | (x5 << 5) | (x4 << 4);
      const int row = X >> 6;
      const int cl = sb * 32 + ((X & 63) >> 1);
      uint4 v = *(const uint4*)(ldsT + row * 136 + cl);
      *(uint4*)((char*)outHi + tbase + (size_t)(blockIdx.y * 4 + sb) * 8192 + L) = v;
    }
  __syncthreads();
  // lo plane
#pragma unroll
  for (int fm = 0; fm < 4; ++fm)
#pragma unroll
    for (int fn = 0; fn < 4; ++fn)
#pragma unroll
      for (int q = 0; q < 4; ++q) {
        const int rl = wm + fm * 16 + (l >> 4) * 4 + q;
        const int cl = wn + fn * 16 + (l & 15);
        const float x = acc[fm][fn][q];
        const unsigned short hh2 = f2bf(x);
        ldsT[rl * 136 + cl] = f2bf(x - bf2f(hh2));
      }
  __syncthreads();
#pragma unroll
  for (int sb = 0; sb < 4; ++sb)
#pragma unroll
    for (int p = 0; p < 2; ++p) {
      const int L = p * 4096 + t * 16;
      const int x6 = ((L >> 6) ^ (L >> 8)) & 1;
      const int x5 = ((L >> 5) ^ (L >> 7)) & 1;
      const int x4 = ((L >> 4) ^ (L >> 6) ^ (L >> 8)) & 1;
      const int X = (L & ~0x70) | (x6 << 6) | (x5 << 5) | (x4 << 4);
      const int row = X >> 6;
      const int cl = sb * 32 + ((X & 63) >> 1);
      uint4 v = *(const uint4*)(ldsT + row * 136 + cl);
      *(uint4*)((char*)outLo + tbase + (size_t)(blockIdx.y * 4 + sb) * 8192 + L) = v;
    }
}

// ---------------------------------------------------------------------------
// k_scores_mfma: scores = proj @ words^T (split-bf16 3-term), f32 -> ws.
// v3 (pv-structure): BM=512 (all E per block) x BN=128, BK=32, 512 thr /
// 8 waves (4m x 2n). Double-buffered 160KB LDS, ONE barrier per stage.
// A fully via global_load_lds from 32k-stage blob planes; B split once
// per (b,n0) (was 4x). Grid 512 = 32 b x 16 n-tiles, XCD-pinned.
// ---------------------------------------------------------------------------
__global__ __launch_bounds__(512) void k_scores_mfma(
    const unsigned short* __restrict__ pHi, const unsigned short* __restrict__ pLo,
    const float* __restrict__ words, float* __restrict__ sc) {
  __shared__ uint4 lds4[10240];  // 160KB
  char* pAhi_c = (char*)lds4;             // 32KB: [4 tiles][8KB swz64x]
  char* pAlo_c = (char*)lds4 + 32768;
  char* pAhi_n = (char*)lds4 + 65536;
  char* pAlo_n = (char*)lds4 + 98304;
  char* pBhi_c = (char*)lds4 + 131072;    // 8KB: [128 n][64B swz64x]
  char* pBlo_c = (char*)lds4 + 139264;
  char* pBhi_n = (char*)lds4 + 147456;
  char* pBlo_n = (char*)lds4 + 155648;

  const int g = blockIdx.x;
  const int b = (g & 7) + 8 * (g >> 7);   // XCD-pinned batch (bijective)
  const int n0 = ((g >> 3) & 15) * 128;

  const int t = threadIdx.x, l = t & 63, wv = t >> 6;
  const int wm4 = wv >> 1;    // 0..3 -> m tile (128 rows each)
  const int wn2 = wv & 1;     // 0..1 -> n base local = wn2*64

  f32x4 acc[8][4];
#pragma unroll
  for (int i = 0; i < 8; ++i)
#pragma unroll
    for (int j = 0; j < 4; ++j) acc[i][j] = (f32x4){0.f, 0.f, 0.f, 0.f};

  f32x4 br0, br1;
  const int bn = t >> 2;          // B n-row 0..127
  const int bc = (t & 3) * 8;     // f32 col base within 32

  auto dma_A = [&](int s, char* pH, char* pL) {
#pragma unroll
    for (int j = 0; j < 4; ++j) {
      const size_t gb = (size_t)(b * 4 + j) * 262144 + (size_t)s * 8192 +
                        wv * 1024 + l * 16;
      gload_lds16((const char*)pHi + gb, pH + j * 8192 + wv * 1024);
      gload_lds16((const char*)pLo + gb, pL + j * 8192 + wv * 1024);
    }
  };

  auto load_B = [&](int s) {
    const float* bs = words + (size_t)b * WN * D_ + (size_t)(n0 + bn) * 1024 +
                      s * 32 + bc;
    br0 = *(const f32x4*)(bs);
    br1 = *(const f32x4*)(bs + 4);
  };

  auto write_B = [&](char* pH, char* pL) {
    unsigned short hB[8], lB[8];
#pragma unroll
    for (int j = 0; j < 4; ++j) {
      float y0 = br0[j];
      unsigned short h0 = f2bf(y0);
      hB[j] = h0;
      lB[j] = f2bf(y0 - bf2f(h0));
      float y1 = br1[j];
      unsigned short h1 = f2bf(y1);
      hB[4 + j] = h1;
      lB[4 + j] = f2bf(y1 - bf2f(h1));
    }
    const int o = swz64x(bn, (t & 3) * 16);
    *(uint4*)(pH + o) = pack8(hB[0], hB[1], hB[2], hB[3], hB[4], hB[5], hB[6], hB[7]);
    *(uint4*)(pL + o) = pack8(lB[0], lB[1], lB[2], lB[3], lB[4], lB[5], lB[6], lB[7]);
  };

  auto compute_stage = [&](const char* pAh, const char* pAl,
                           const char* pBh, const char* pBl) {
    const int kb0 = (l >> 4) * 16;
    short8 bh[4], bl[4];
#pragma unroll
    for (int f = 0; f < 4; ++f) {
      const int n = wn2 * 64 + f * 16 + (l & 15);
      const int o = swz64x(n, kb0);
      bh[f] = *(const short8*)(pBh + o);
      bl[f] = *(const short8*)(pBl + o);
    }
#pragma unroll
    for (int fm = 0; fm < 8; ++fm) {
      const int row = fm * 16 + (l & 15);
      const int oa = wm4 * 8192 + swz64x(row, kb0);
      const short8 ah = *(const short8*)(pAh + oa);
      const short8 al = *(const short8*)(pAl + oa);
#pragma unroll
      for (int fn = 0; fn < 4; ++fn) {
        acc[fm][fn] = __builtin_amdgcn_mfma_f32_16x16x32_bf16(ah, bh[fn], acc[fm][fn], 0, 0, 0);
        acc[fm][fn] = __builtin_amdgcn_mfma_f32_16x16x32_bf16(al, bh[fn], acc[fm][fn], 0, 0, 0);
        acc[fm][fn] = __builtin_amdgcn_mfma_f32_16x16x32_bf16(ah, bl[fn], acc[fm][fn], 0, 0, 0);
      }
    }
  };

  // prologue
  load_B(0);
  dma_A(0, pAhi_c, pAlo_c);
  write_B(pBhi_c, pBlo_c);
  __syncthreads();

  for (int s = 0; s < 32; ++s) {
    if (s < 31) {
      load_B(s + 1);
      dma_A(s + 1, pAhi_n, pAlo_n);
    }
    compute_stage(pAhi_c, pAlo_c, pBhi_c, pBlo_c);
    if (s < 31) write_B(pBhi_n, pBlo_n);
    __syncthreads();  // drains DMA (vmcnt) + ds_writes (lgkm)
    char* x;
    x = pAhi_c; pAhi_c = pAhi_n; pAhi_n = x;
    x = pAlo_c; pAlo_c = pAlo_n; pAlo_n = x;
    x = pBhi_c; pBhi_c = pBhi_n; pBhi_n = x;
    x = pBlo_c; pBlo_c = pBlo_n; pBlo_n = x;
  }

  // store f32 scores
#pragma unroll
  for (int fm = 0; fm < 8; ++fm)
#pragma unroll
    for (int fn = 0; fn < 4; ++fn)
#pragma unroll
      for (int q = 0; q < 4; ++q) {
        const int row = wm4 * 128 + fm * 16 + (l >> 4) * 4 + q;
        const int col = n0 + wn2 * 64 + fn * 16 + (l & 15);
        sc[((size_t)b * 512 + row) * 2048 + col] = acc[fm][fn][q];
      }
}

// ---------------------------------------------------------------------------
// k_softmax: reads f32 scores from ws, writes bf16 att in BLOB layout to
// d_out (proj planes dead): blob[b][stage s][slot = e*128 + (c16^((e&7)<<4))]
// -- exactly k_pv's swizzled LDS image so its global_load_lds lands right.
// ---------------------------------------------------------------------------
__global__ __launch_bounds__(256) void k_softmax(const float* __restrict__ ws,
                                                 const void* __restrict__ mask,
                                                 unsigned short* __restrict__ blob) {
  __shared__ float red[8];
  const int row = blockIdx.x;
  const int t = threadIdx.x;
  const int wave = t >> 6;
  const float* rp = ws + (size_t)row * 2048;
  float v[8];
  {
    f32x4 v0 = *(const f32x4*)(rp + t * 8);
    f32x4 v1 = *(const f32x4*)(rp + t * 8 + 4);
#pragma unroll
    for (int i = 0; i < 4; ++i) { v[i] = v0[i]; v[4 + i] = v1[i]; }
  }
  if (g_mask_is_int) {
    const int* mp = (const int*)mask + (size_t)row * 2048 + t * 8;
    const int4 m0 = *(const int4*)mp;
    const int4 m1 = *(const int4*)(mp + 4);
    if (m0.x) v[0] = -INFINITY;
    if (m0.y) v[1] = -INFINITY;
    if (m0.z) v[2] = -INFINITY;
    if (m0.w) v[3] = -INFINITY;
    if (m1.x) v[4] = -INFINITY;
    if (m1.y) v[5] = -INFINITY;
    if (m1.z) v[6] = -INFINITY;
    if (m1.w) v[7] = -INFINITY;
  } else {
    const unsigned char* mp = (const unsigned char*)mask + (size_t)row * 2048 + t * 8;
    const uchar4 m0 = *(const uchar4*)mp;
    const uchar4 m1 = *(const uchar4*)(mp + 4);
    if (m0.x) v[0] = -INFINITY;
    if (m0.y) v[1] = -INFINITY;
    if (m0.z) v[2] = -INFINITY;
    if (m0.w) v[3] = -INFINITY;
    if (m1.x) v[4] = -INFINITY;
    if (m1.y) v[5] = -INFINITY;
    if (m1.z) v[6] = -INFINITY;
    if (m1.w) v[7] = -INFINITY;
  }
  float mx = v[0];
#pragma unroll
  for (int i = 1; i < 8; ++i) mx = fmaxf(mx, v[i]);
#pragma unroll
  for (int off = 32; off > 0; off >>= 1) mx = fmaxf(mx, __shfl_xor(mx, off));
  if ((t & 63) == 0) red[wave] = mx;
  __syncthreads();
  mx = fmaxf(fmaxf(red[0], red[1]), fmaxf(red[2], red[3]));
  float e[8];
  float sum = 0.0f;
#pragma unroll
  for (int i = 0; i < 8; ++i) {
    e[i] = __expf(v[i] - mx);
    sum += e[i];
  }
#pragma unroll
  for (int off = 32; off > 0; off >>= 1) sum += __shfl_xor(sum, off);
  if ((t & 63) == 0) red[4 + wave] = sum;
  __syncthreads();
  const float tot = (red[4] + red[5]) + (red[6] + red[7]);
  const float rinv = 1.0f / tot;

  const int b = row >> 9, ee = row & 511;
  const uint4 pk = pack8(f2bf(e[0] * rinv), f2bf(e[1] * rinv),
                         f2bf(e[2] * rinv), f2bf(e[3] * rinv),
                         f2bf(e[4] * rinv), f2bf(e[5] * rinv),
                         f2bf(e[6] * rinv), f2bf(e[7] * rinv));
  char* dst = (char*)blob + (size_t)b * 2097152 + (size_t)(t >> 3) * 65536 +
              ee * 128 + (((t & 7) * 16) ^ ((ee & 7) << 4));
  *(uint4*)dst = pk;
}

// ---------------------------------------------------------------------------
// k_pv: ctx = att @ words (unchanged, verified round 9).
// ---------------------------------------------------------------------------
__global__ __launch_bounds__(512) void k_pv(
    const unsigned short* __restrict__ blob, const float* __restrict__ words,
    float* __restrict__ ctx) {
  __shared__ uint4 lds4[10240];           // 160KB: A0 64K | A1 64K | B0 16K | B1 16K
  char* pAc = (char*)lds4;
  char* pAn = (char*)lds4 + 65536;
  char* pBc = (char*)lds4 + 131072;
  char* pBn = (char*)lds4 + 147456;

  const int g = blockIdx.x;
  const int b = (g & 7) + 8 * (g >> 6);   // XCD-pinned batch
  const int wt = (g >> 3) & 7;
  const int w0 = wt * 128;

  const int t = threadIdx.x, l = t & 63, wv = t >> 6;
  const int wm4 = wv >> 1;
  const int wn2 = wv & 1;

  const char* blobB = (const char*)blob + (size_t)b * 2097152;

  f32x4 acc[8][4];
#pragma unroll
  for (int i = 0; i < 8; ++i)
#pragma unroll
    for (int j = 0; j < 4; ++j) acc[i][j] = (f32x4){0.f, 0.f, 0.f, 0.f};

  f32x4 bv0a, bv0b, bv1a, bv1b;
  const int np2 = (t & 31) * 2;
  const int wc = (t >> 5) * 8;

  auto dma_A = [&](int s, char* pA) {
    const char* gp = blobB + (size_t)s * 65536 + wv * 8192 + l * 16;
#pragma unroll
    for (int j = 0; j < 8; ++j)
      gload_lds16(gp + j * 1024, pA + wv * 8192 + j * 1024);
  };

  auto load_B = [&](int s) {
    const float* wp = words + (size_t)b * WN * D_ +
                      (size_t)(s * 64 + np2) * 1024 + w0 + wc;
    bv0a = *(const f32x4*)(wp);
    bv0b = *(const f32x4*)(wp + 4);
    bv1a = *(const f32x4*)(wp + 1024);
    bv1b = *(const f32x4*)(wp + 1028);
  };

  auto write_B = [&](char* pB) {
#pragma unroll
    for (int i = 0; i < 8; ++i) {
      const int w = wc + i;
      const float x0 = (i < 4) ? bv0a[i & 3] : bv0b[i & 3];
      const float x1 = (i < 4) ? bv1a[i & 3] : bv1b[i & 3];
      const unsigned int pk =
          (unsigned int)f2bf(x0) | ((unsigned int)f2bf(x1) << 16);
      *(unsigned int*)(pB + w * 128 + ((np2 * 2) ^ ((w & 7) << 4))) = pk;
    }
  };

  auto compute_stage = [&](const char* pA, const char* pB) {
#pragma unroll
    for (int ks = 0; ks < 2; ++ks) {
      short8 a[8];
      const int kb = ks * 64 + (l >> 4) * 16;
#pragma unroll
      for (int f = 0; f < 8; ++f) {
        const int row = wm4 * 128 + f * 16 + (l & 15);
        a[f] = *(const short8*)(pA + swz(row, kb));
      }
      short8 bb[4];
#pragma unroll
      for (int f = 0; f < 4; ++f) {
        const int row = wn2 * 64 + f * 16 + (l & 15);
        bb[f] = *(const short8*)(pB + swz(row, kb));
      }
#pragma unroll
      for (int fm = 0; fm < 8; ++fm)
#pragma unroll
        for (int fn = 0; fn < 4; ++fn)
          acc[fm][fn] = __builtin_amdgcn_mfma_f32_16x16x32_bf16(a[fm], bb[fn], acc[fm][fn], 0, 0, 0);
    }
  };

  load_B(0);
  dma_A(0, pAc);
  write_B(pBc);
  __syncthreads();

  for (int s = 0; s < 32; ++s) {
    if (s < 31) {
      load_B(s + 1);
      dma_A(s + 1, pAn);
    }
    compute_stage(pAc, pBc);
    if (s < 31) write_B(pBn);
    __syncthreads();
    char* t1 = pAc; pAc = pAn; pAn = t1;
    char* t2 = pBc; pBc = pBn; pBn = t2;
  }

#pragma unroll
  for (int fm = 0; fm < 8; ++fm)
#pragma unroll
    for (int fn = 0; fn < 4; ++fn)
#pragma unroll
      for (int q = 0; q < 4; ++q) {
        const int row = wm4 * 128 + fm * 16 + (l >> 4) * 4 + q;
        const int col = w0 + wn2 * 64 + fn * 16 + (l & 15);
        ctx[((size_t)b * 512 + row) * 1024 + col] = acc[fm][fn][q];
      }
}

// ---------------------------------------------------------------------------
// k_copy: ctx (ws) -> d_out, float4 grid-stride.
// ---------------------------------------------------------------------------
__global__ __launch_bounds__(256) void k_copy(const float4* __restrict__ src,
                                              float4* __restrict__ dst) {
  const int n4 = 16384 * 1024 / 4;
  int i = blockIdx.x * 256 + threadIdx.x;
  const int stride = gridDim.x * 256;
  for (; i < n4; i += stride) dst[i] = src[i];
}

// ===========================================================================
// FALLBACK PATH (round-2 verified kernels; used if ws too small)
// ===========================================================================
__global__ __launch_bounds__(256, 4) void k_proj(const float* __restrict__ A,
                                                 const float* __restrict__ W,
                                                 const float* __restrict__ bias,
                                                 float* __restrict__ out) {
  __shared__ float As[32][132];
  __shared__ float Bs[32][132];
  const int t = threadIdx.x;
  const int m0 = blockIdx.x * 128;
  const int n0 = blockIdx.y * 128;
  const int tm = t >> 4;
  const int tn = t & 15;
  const int lrow = t >> 1;
  const int lk = (t & 1) * 16;

  float acc[8][8];
#pragma unroll
  for (int i = 0; i < 8; ++i)
#pragma unroll
    for (int j = 0; j < 8; ++j) acc[i][j] = 0.0f;

  const float* Arow = A + (size_t)(m0 + lrow) * D_ + lk;
  const float* Wrow = W + (size_t)(n0 + lrow) * D_ + lk;

  for (int k0 = 0; k0 < D_; k0 += 32) {
    __syncthreads();
#pragma unroll
    for (int j = 0; j < 4; ++j) {
      const float4 va = *(const float4*)(Arow + k0 + j * 4);
      As[lk + j * 4 + 0][lrow] = va.x;
      As[lk + j * 4 + 1][lrow] = va.y;
      As[lk + j * 4 + 2][lrow] = va.z;
      As[lk + j * 4 + 3][lrow] = va.w;
      const float4 vb = *(const float4*)(Wrow + k0 + j * 4);
      Bs[lk + j * 4 + 0][lrow] = vb.x;
      Bs[lk + j * 4 + 1][lrow] = vb.y;
      Bs[lk + j * 4 + 2][lrow] = vb.z;
      Bs[lk + j * 4 + 3][lrow] = vb.w;
    }
    __syncthreads();
#pragma unroll 8
    for (int k = 0; k < 32; ++k) {
      float a[8], bb[8];
      *(float4*)(a + 0) = *(const float4*)&As[k][tm * 4];
      *(float4*)(a + 4) = *(const float4*)&As[k][tm * 4 + 64];
      *(float4*)(bb + 0) = *(const float4*)&Bs[k][tn * 4];
      *(float4*)(bb + 4) = *(const float4*)&Bs[k][tn * 4 + 64];
#pragma unroll
      for (int i = 0; i < 8; ++i)
#pragma unroll
        for (int j = 0; j < 8; ++j) acc[i][j] = fmaf(a[i], bb[j], acc[i][j]);
    }
  }

  float bn[8];
#pragma unroll
  for (int j = 0; j < 8; ++j) bn[j] = bias[n0 + tn * 4 + (j & 3) + (j >> 2) * 64];
#pragma unroll
  for (int i = 0; i < 8; ++i) {
    const int m = m0 + tm * 4 + (i & 3) + (i >> 2) * 64;
    float4 v0, v1;
    v0.x = tanhf(acc[i][0] + bn[0]);
    v0.y = tanhf(acc[i][1] + bn[1]);
    v0.z = tanhf(acc[i][2] + bn[2]);
    v0.w = tanhf(acc[i][3] + bn[3]);
    v1.x = tanhf(acc[i][4] + bn[4]);
    v1.y = tanhf(acc[i][5] + bn[5]);
    v1.z = tanhf(acc[i][6] + bn[6]);
    v1.w = tanhf(acc[i][7] + bn[7]);
    *(float4*)(out + (size_t)m * D_ + n0 + tn * 4) = v0;
    *(float4*)(out + (size_t)m * D_ + n0 + tn * 4 + 64) = v1;
  }
}

__global__ __launch_bounds__(256) void k_scores(const float* __restrict__ words,
                                                const void* __restrict__ mask,
                                                float* __restrict__ pa) {
  __shared__ float Pt[1024][18];
  __shared__ float Ws[64][268];
  const int t = threadIdx.x;
  const int b = blockIdx.x >> 5;
  const int et = blockIdx.x & 31;
  const int e0 = et * 16;
  const int eg = t >> 5;
  const int ng = t & 31;
  const int mask_is_int = g_mask_is_int;
  const float* wbase = words + (size_t)b * WN * D_;

  {
    const int row = t >> 4;
    const int dj = (t & 15) * 4;
    const float* pr = pa + (size_t)(b * E_ + e0 + row) * D_;
#pragma unroll
    for (int rr = 0; rr < 16; ++rr) {
      const float4 v = *(const float4*)(pr + dj + rr * 64);
      Pt[dj + rr * 64 + 0][row] = v.x;
      Pt[dj + rr * 64 + 1][row] = v.y;
      Pt[dj + rr * 64 + 2][row] = v.z;
      Pt[dj + rr * 64 + 3][row] = v.w;
    }
  }

  float s[2][64];
#pragma unroll
  for (int i = 0; i < 2; ++i)
#pragma unroll
    for (int u = 0; u < 64; ++u) s[i][u] = 0.0f;

  const int nl = t >> 3;
  const int d4 = (t & 7) * 4;

  for (int dk = 0; dk < D_; dk += 64) {
#pragma unroll
    for (int nb = 0; nb < 8; ++nb) {
      __syncthreads();
#pragma unroll
      for (int rr = 0; rr < 8; ++rr) {
#pragma unroll
        for (int hh = 0; hh < 2; ++hh) {
          const int n = nl + rr * 32;
          const int d = d4 + hh * 32;
          const float4 v = *(const float4*)(wbase + (size_t)(nb * 256 + n) * D_ + dk + d);
          Ws[d + 0][n] = v.x;
          Ws[d + 1][n] = v.y;
          Ws[d + 2][n] = v.z;
          Ws[d + 3][n] = v.w;
        }
      }
      __syncthreads();
#pragma unroll 2
      for (int k = 0; k < 64; ++k) {
        const float2 a = *(const float2*)&Pt[dk + k][eg * 2];
        const float4 b0 = *(const float4*)&Ws[k][ng * 4];
        const float4 b1 = *(const float4*)&Ws[k][128 + ng * 4];
        const float aa[2] = {a.x, a.y};
        const float bb[8] = {b0.x, b0.y, b0.z, b0.w, b1.x, b1.y, b1.z, b1.w};
#pragma unroll
        for (int i = 0; i < 2; ++i)
#pragma unroll
          for (int u = 0; u < 8; ++u)
            s[i][nb * 8 + u] = fmaf(aa[i], bb[u], s[i][nb * 8 + u]);
      }
    }
  }

#pragma unroll
  for (int i = 0; i < 2; ++i) {
    const int e = e0 + eg * 2 + i;
#pragma unroll
    for (int nb = 0; nb < 8; ++nb)
#pragma unroll
      for (int q = 0; q < 2; ++q) {
        const size_t moff = (size_t)(b * E_ + e) * WN + nb * 256 + q * 128 + ng * 4;
        int mx, my, mz, mw;
        if (mask_is_int) {
          const int4 mv = *(const int4*)((const int*)mask + moff);
          mx = mv.x; my = mv.y; mz = mv.z; mw = mv.w;
        } else {
          const uchar4 mv = *(const uchar4*)((const unsigned char*)mask + moff);
          mx = mv.x; my = mv.y; mz = mv.z; mw = mv.w;
        }
        if (mx) s[i][nb * 8 + q * 4 + 0] = -1e30f;
        if (my) s[i][nb * 8 + q * 4 + 1] = -1e30f;
        if (mz) s[i][nb * 8 + q * 4 + 2] = -1e30f;
        if (mw) s[i][nb * 8 + q * 4 + 3] = -1e30f;
      }
    float m = -1e30f;
#pragma unroll
    for (int u = 0; u < 64; ++u) m = fmaxf(m, s[i][u]);
#pragma unroll
    for (int off = 16; off > 0; off >>= 1) m = fmaxf(m, __shfl_xor(m, off));
    float sum = 0.0f;
#pragma unroll
    for (int u = 0; u < 64; ++u) {
      const float p = __expf(s[i][u] - m);
      s[i][u] = p;
      sum += p;
    }
#pragma unroll
    for (int off = 16; off > 0; off >>= 1) sum += __shfl_xor(sum, off);
    const float rinv = 1.0f / sum;

    unsigned short* ar2 = (unsigned short*)(pa + (size_t)(b * E_ + e) * WN / 2);
#pragma unroll
    for (int nb = 0; nb < 8; ++nb)
#pragma unroll
      for (int q = 0; q < 2; ++q) {
        ushort4 pk;
        pk.x = f2bf(s[i][nb * 8 + q * 4 + 0] * rinv);
        pk.y = f2bf(s[i][nb * 8 + q * 4 + 1] * rinv);
        pk.z = f2bf(s[i][nb * 8 + q * 4 + 2] * rinv);
        pk.w = f2bf(s[i][nb * 8 + q * 4 + 3] * rinv);
        *(ushort4*)(ar2 + nb * 256 + q * 128 + ng * 4) = pk;
      }
  }
}

__global__ __launch_bounds__(256) void k_ctx(const float* __restrict__ words,
                                             float* __restrict__ pa) {
  __shared__ unsigned short att_s[16][2048];
  __shared__ unsigned short Wb[256][132];
  const int t = threadIdx.x;
  const int b = blockIdx.x >> 5;
  const int et = blockIdx.x & 31;
  const int e0 = et * 16;
  const int eg = t >> 5;
  const int wg = t & 31;
  const float* wbase = words + (size_t)b * WN * D_;

  {
    const int row = t >> 4;
    const int cj = t & 15;
    const uint4* pr = (const uint4*)(pa + (size_t)(b * E_ + e0 + row) * D_);
#pragma unroll
    for (int rr = 0; rr < 16; ++rr) {
      const int c = cj + rr * 16;
      const uint4 v = pr[c];
      *(uint4*)&att_s[row][c * 8] = v;
    }
  }

  float acc[2][32];
#pragma unroll
  for (int i = 0; i < 2; ++i)
#pragma unroll
    for (int u = 0; u < 32; ++u) acc[i][u] = 0.0f;

  const int nlg = t >> 5;
  const int w4 = (t & 31) * 4;

  for (int nb = 0; nb < 8; ++nb) {
#pragma unroll
    for (int q = 0; q < 8; ++q) {
      __syncthreads();
#pragma unroll
      for (int rr = 0; rr < 32; ++rr) {
        const int n = nlg + rr * 8;
        const float4 v = *(const float4*)(wbase + (size_t)(nb * 256 + n) * D_ + q * 128 + w4);
        ushort4 pk;
        pk.x = f2bf(v.x);
        pk.y = f2bf(v.y);
        pk.z = f2bf(v.z);
        pk.w = f2bf(v.w);
        *(ushort4*)&Wb[n][w4] = pk;
      }
      __syncthreads();
#pragma unroll 4
      for (int n2 = 0; n2 < 128; ++n2) {
        const int n = n2 * 2;
        const ushort4 r0 = *(const ushort4*)&Wb[n][wg * 4];
        const ushort4 r1 = *(const ushort4*)&Wb[n + 1][wg * 4];
        const float w0[4] = {bf2f(r0.x), bf2f(r0.y), bf2f(r0.z), bf2f(r0.w)};
        const float w1[4] = {bf2f(r1.x), bf2f(r1.y), bf2f(r1.z), bf2f(r1.w)};
#pragma unroll
        for (int i = 0; i < 2; ++i) {
          const unsigned int aw = *(const unsigned int*)&att_s[eg * 2 + i][nb * 256 + n];
          const float a0 = bf2f((unsigned short)(aw & 0xffffu));
          const float a1 = bf2f((unsigned short)(aw >> 16));
#pragma unroll
          for (int j = 0; j < 4; ++j)
            acc[i][q * 4 + j] = fmaf(a0, w0[j], fmaf(a1, w1[j], acc[i][q * 4 + j]));
        }
      }
    }
  }

#pragma unroll
  for (int i = 0; i < 2; ++i) {
    float* orow = pa + (size_t)(b * E_ + e0 + eg * 2 + i) * D_;
#pragma unroll
    for (int q = 0; q < 8; ++q) {
      float4 v;
      v.x = acc[i][q * 4 + 0];
      v.y = acc[i][q * 4 + 1];
      v.z = acc[i][q * 4 + 2];
      v.w = acc[i][q * 4 + 3];
      *(float4*)(orow + q * 128 + wg * 4) = v;
    }
  }
}

extern "C" void kernel_launch(void* const* d_in, const int* in_sizes, int n_in,
                              void* d_out, int out_size, void* d_ws, size_t ws_size,
                              hipStream_t stream) {
  const float* ems = (const float*)d_in[0];
  const float* words = (const float*)d_in[1];
  const void* mask = d_in[2];
  const float* w_weight = (const float*)d_in[3];
  const float* w_bias = (const float*)d_in[4];

  k_detect<<<1, 64, 0, stream>>>((const unsigned char*)mask);

  const size_t ws_need = (size_t)16384 * 2048 * 4;
  if (ws_size >= ws_need) {
    unsigned short* hiP = (unsigned short*)d_out;
    unsigned short* loP = hiP + (size_t)16384 * 1024;
    float* ws = (float*)d_ws;
    // 1. proj planes (32k-stage blob layout) -> d_out
    k_proj_mfma<<<dim3(128, 8), 256, 0, stream>>>(ems, w_weight, w_bias, hiP, loP);
    // 2. scores (f32) -> ws  (BM=512 pv-structure, DMA A, dbuf, 1 barrier)
    k_scores_mfma<<<dim3(512), 512, 0, stream>>>(hiP, loP, words, ws);
    // 3. softmax: ws scores -> att blob in d_out (planes dead)
    k_softmax<<<dim3(16384), 256, 0, stream>>>(ws, mask, (unsigned short*)d_out);
    // 4. pv: att blob (d_out) @ words -> ctx in ws (scores dead)
    k_pv<<<dim3(256), 512, 0, stream>>>((const unsigned short*)d_out, words, ws);
    // 5. ctx ws -> d_out
    k_copy<<<dim3(2048), 256, 0, stream>>>((const float4*)d_ws, (float4*)d_out);
  } else {
    float* out = (float*)d_out;
    k_proj<<<dim3(128, 8), 256, 0, stream>>>(ems, w_weight, w_bias, out);
    k_scores<<<dim3(B_ * (E_ / 16)), 256, 0, stream>>>(words, mask, out);
    k_ctx<<<dim3(B_ * (E_ / 16)), 256, 0, stream>>>(words, out);
  }
}

// Round 11
// 517.565 us; speedup vs baseline: 2.1242x; 1.1200x over previous
//
#include <hip/hip_runtime.h>
#include <hip/hip_bf16.h>
#include <stdint.h>

#define B_  32
#define E_  512
#define WN  2048
#define D_  1024

typedef __attribute__((ext_vector_type(8))) short short8;
typedef __attribute__((ext_vector_type(4))) float f32x4;

__device__ int g_mask_is_int;   // 1 if mask buffer is int32 per element, 0 if uint8

__device__ __forceinline__ unsigned short f2bf(float f) {
  unsigned int u = __float_as_uint(f);
  u += 0x7fffu + ((u >> 16) & 1u);   // round-to-nearest-even
  return (unsigned short)(u >> 16);
}
__device__ __forceinline__ float bf2f(unsigned short s) {
  return __uint_as_float(((unsigned int)s) << 16);
}
__device__ __forceinline__ float ftanh(float x) {
  float e = __expf(2.0f * x);
  return 1.0f - 2.0f / (e + 1.0f);
}
// XOR-swizzled byte offset within a [rows][128B] LDS plane
__device__ __forceinline__ int swz(int row, int kb) {
  return row * 128 + (kb ^ ((row & 7) << 4));
}
// 64B-row swizzle: F(X) = X ^ ((X>>6 & 7) << 4)
__device__ __forceinline__ int swz64x(int row, int kb) {
  const int X = row * 64 + kb;
  return X ^ (((X >> 6) & 7) << 4);
}
__device__ __forceinline__ uint4 pack8(unsigned short a0, unsigned short a1,
                                       unsigned short a2, unsigned short a3,
                                       unsigned short a4, unsigned short a5,
                                       unsigned short a6, unsigned short a7) {
  uint4 v;
  v.x = (unsigned int)a0 | ((unsigned int)a1 << 16);
  v.y = (unsigned int)a2 | ((unsigned int)a3 << 16);
  v.z = (unsigned int)a4 | ((unsigned int)a5 << 16);
  v.w = (unsigned int)a6 | ((unsigned int)a7 << 16);
  return v;
}
// async global->LDS, 16B per lane; LDS dst is wave-uniform base (+lane*16 HW)
__device__ __forceinline__ void gload_lds16(const void* g, void* l) {
  __builtin_amdgcn_global_load_lds(
      (const __attribute__((address_space(1))) unsigned int*)g,
      (__attribute__((address_space(3))) unsigned int*)l, 16, 0, 0);
}

// ---------------------------------------------------------------------------
// K0: detect mask dtype. int32 0/1 data => bytes at offset %4 != 0 are all 0.
// ---------------------------------------------------------------------------
__global__ void k_detect(const unsigned char* __restrict__ m) {
  if (threadIdx.x == 0) {
    int nz = 0;
    for (int i = 0; i < 1024; ++i)
      if ((i & 3) && m[i]) nz++;
    g_mask_is_int = (nz == 0) ? 1 : 0;
  }
}

// ===========================================================================
// FAST PATH
// ===========================================================================

// ---------------------------------------------------------------------------
// k_split: src f32 [nTiles*128 rows][1024] -> hi/lo bf16 blobs in proj's
// swizzled LDS-image layout: blob[T][s][16KB], image offset swz(row, kk*2).
// Each thread writes blob-linear 16B granules (coalesced), gathering the
// inverse-swizzled 8 f32 from src. Grid: nGranules/1024 blocks, 256 thr, 4/t.
// ---------------------------------------------------------------------------
__global__ __launch_bounds__(256) void k_split(const float* __restrict__ src,
                                               unsigned short* __restrict__ hi,
                                               unsigned short* __restrict__ lo) {
#pragma unroll
  for (int j = 0; j < 4; ++j) {
    const size_t Lg = ((size_t)blockIdx.x * 1024 + j * 256 + threadIdx.x) * 16;
    const int Lloc = (int)(Lg & 16383);
    const int TS = (int)(Lg >> 14);
    const int T = TS >> 4, s = TS & 15;
    const int row = Lloc >> 7;
    const int kb = (Lloc & 127) ^ ((row & 7) << 4);
    const int kk = kb >> 1;
    const float* sp = src + ((size_t)(T * 128 + row)) * 1024 + s * 64 + kk;
    const f32x4 v0 = *(const f32x4*)(sp);
    const f32x4 v1 = *(const f32x4*)(sp + 4);
    unsigned short h[8], l[8];
#pragma unroll
    for (int i = 0; i < 4; ++i) {
      unsigned short hh = f2bf(v0[i]);
      h[i] = hh;
      l[i] = f2bf(v0[i] - bf2f(hh));
      unsigned short h2 = f2bf(v1[i]);
      h[4 + i] = h2;
      l[4 + i] = f2bf(v1[i] - bf2f(h2));
    }
    *(uint4*)((char*)hi + Lg) = pack8(h[0], h[1], h[2], h[3], h[4], h[5], h[6], h[7]);
    *(uint4*)((char*)lo + Lg) = pack8(l[0], l[1], l[2], l[3], l[4], l[5], l[6], l[7]);
  }
}

// ---------------------------------------------------------------------------
// k_proj_dma: proj = tanh(ems @ W^T + bias), split-bf16 3-term MFMA.
// Main loop: pure global_load_lds from pre-split blobs (A: ems planes,
// B: W planes), double-buffered 128KB LDS, ONE barrier per stage, no
// staging VALU. 512 thr / 8 waves (4m x 2n), tile 128x128, BK=64.
// Epilogue writes proj hi/lo planes in 32-k-stage blob layout for
// k_scores' DMA (verified round 10).
// ---------------------------------------------------------------------------
__global__ __launch_bounds__(512) void k_proj_dma(
    const unsigned short* __restrict__ eHi, const unsigned short* __restrict__ eLo,
    const unsigned short* __restrict__ wHi, const unsigned short* __restrict__ wLo,
    const float* __restrict__ bias,
    unsigned short* __restrict__ outHi, unsigned short* __restrict__ outLo) {
  __shared__ uint4 lds4[8192];   // 128KB: c{Ahi,Alo,Bhi,Blo 16K each} | n{...}
  char* pAhi_c = (char*)lds4;
  char* pAlo_c = (char*)lds4 + 16384;
  char* pBhi_c = (char*)lds4 + 32768;
  char* pBlo_c = (char*)lds4 + 49152;
  char* pAhi_n = (char*)lds4 + 65536;
  char* pAlo_n = (char*)lds4 + 81920;
  char* pBhi_n = (char*)lds4 + 98304;
  char* pBlo_n = (char*)lds4 + 114688;

  const int Tm = blockIdx.x >> 3;   // 0..127 m-tile
  const int Tn = blockIdx.x & 7;    // 0..7  n-tile
  const int t = threadIdx.x, l = t & 63, wv = t >> 6;
  const int wm2 = wv >> 1;   // 0..3 -> rows wm2*32
  const int wn2 = wv & 1;    // 0..1 -> cols wn2*64

  f32x4 acc[2][4];
#pragma unroll
  for (int i = 0; i < 2; ++i)
#pragma unroll
    for (int j = 0; j < 4; ++j) acc[i][j] = (f32x4){0.f, 0.f, 0.f, 0.f};

  auto dma_stage = [&](int s, char* pAh, char* pAl, char* pBh, char* pBl) {
#pragma unroll
    for (int j = 0; j < 2; ++j) {
      const size_t ga = (size_t)Tm * 262144 + (size_t)s * 16384 + j * 8192 +
                        wv * 1024 + l * 16;
      gload_lds16((const char*)eHi + ga, pAh + j * 8192 + wv * 1024);
      gload_lds16((const char*)eLo + ga, pAl + j * 8192 + wv * 1024);
      const size_t gb = (size_t)Tn * 262144 + (size_t)s * 16384 + j * 8192 +
                        wv * 1024 + l * 16;
      gload_lds16((const char*)wHi + gb, pBh + j * 8192 + wv * 1024);
      gload_lds16((const char*)wLo + gb, pBl + j * 8192 + wv * 1024);
    }
  };

  auto compute_stage = [&](const char* pAh, const char* pAl,
                           const char* pBh, const char* pBl) {
#pragma unroll
    for (int ks = 0; ks < 2; ++ks) {
      const int kb = ks * 64 + (l >> 4) * 16;
      short8 ah[2], al[2], bh[4], bl[4];
#pragma unroll
      for (int f = 0; f < 2; ++f) {
        const int o = swz(wm2 * 32 + f * 16 + (l & 15), kb);
        ah[f] = *(const short8*)(pAh + o);
        al[f] = *(const short8*)(pAl + o);
      }
#pragma unroll
      for (int f = 0; f < 4; ++f) {
        const int o = swz(wn2 * 64 + f * 16 + (l & 15), kb);
        bh[f] = *(const short8*)(pBh + o);
        bl[f] = *(const short8*)(pBl + o);
      }
#pragma unroll
      for (int fm = 0; fm < 2; ++fm)
#pragma unroll
        for (int fn = 0; fn < 4; ++fn) {
          acc[fm][fn] = __builtin_amdgcn_mfma_f32_16x16x32_bf16(ah[fm], bh[fn], acc[fm][fn], 0, 0, 0);
          acc[fm][fn] = __builtin_amdgcn_mfma_f32_16x16x32_bf16(al[fm], bh[fn], acc[fm][fn], 0, 0, 0);
          acc[fm][fn] = __builtin_amdgcn_mfma_f32_16x16x32_bf16(ah[fm], bl[fn], acc[fm][fn], 0, 0, 0);
        }
    }
  };

  dma_stage(0, pAhi_c, pAlo_c, pBhi_c, pBlo_c);
  __syncthreads();
  for (int s = 0; s < 16; ++s) {
    if (s < 15) dma_stage(s + 1, pAhi_n, pAlo_n, pBhi_n, pBlo_n);
    compute_stage(pAhi_c, pAlo_c, pBhi_c, pBlo_c);
    __syncthreads();   // drains DMA (vmcnt); all waves done reading cur
    char* x;
    x = pAhi_c; pAhi_c = pAhi_n; pAhi_n = x;
    x = pAlo_c; pAlo_c = pAlo_n; pAlo_n = x;
    x = pBhi_c; pBhi_c = pBhi_n; pBhi_n = x;
    x = pBlo_c; pBlo_c = pBlo_n; pBlo_n = x;
  }

  // epilogue: bias + tanh
  float bcol[4];
#pragma unroll
  for (int fn = 0; fn < 4; ++fn)
    bcol[fn] = bias[Tn * 128 + wn2 * 64 + fn * 16 + (l & 15)];
#pragma unroll
  for (int fm = 0; fm < 2; ++fm)
#pragma unroll
    for (int fn = 0; fn < 4; ++fn)
#pragma unroll
      for (int q = 0; q < 4; ++q)
        acc[fm][fn][q] = ftanh(acc[fm][fn][q] + bcol[fn]);

  // LDS transpose then 32-k-stage blob stores (round-10 layout, 512 thr)
  unsigned short* ldsT = (unsigned short*)lds4;  // [128][136]
  __syncthreads();
  // hi plane
#pragma unroll
  for (int fm = 0; fm < 2; ++fm)
#pragma unroll
    for (int fn = 0; fn < 4; ++fn)
#pragma unroll
      for (int q = 0; q < 4; ++q) {
        const int rl = wm2 * 32 + fm * 16 + (l >> 4) * 4 + q;
        const int cl = wn2 * 64 + fn * 16 + (l & 15);
        ldsT[rl * 136 + cl] = f2bf(acc[fm][fn][q]);
      }
  __syncthreads();
#pragma unroll
  for (int sb = 0; sb < 4; ++sb) {
    const int L = t * 16;
    const int x6 = ((L >> 6) ^ (L >> 8)) & 1;
    const int x5 = ((L >> 5) ^ (L >> 7)) & 1;
    const int x4 = ((L >> 4) ^ (L >> 6) ^ (L >> 8)) & 1;
    const int X = (L & ~0x70) | (x6 << 6) | (x5 << 5) | (x4 << 4);
    const int row = X >> 6;
    const int cl = sb * 32 + ((X & 63) >> 1);
    uint4 v = *(const uint4*)(ldsT + row * 136 + cl);
    *(uint4*)((char*)outHi + (size_t)Tm * 262144 +
              (size_t)(Tn * 4 + sb) * 8192 + L) = v;
  }
  __syncthreads();
  // lo plane
#pragma unroll
  for (int fm = 0; fm < 2; ++fm)
#pragma unroll
    for (int fn = 0; fn < 4; ++fn)
#pragma unroll
      for (int q = 0; q < 4; ++q) {
        const int rl = wm2 * 32 + fm * 16 + (l >> 4) * 4 + q;
        const int cl = wn2 * 64 + fn * 16 + (l & 15);
        const float x = acc[fm][fn][q];
        const unsigned short hh2 = f2bf(x);
        ldsT[rl * 136 + cl] = f2bf(x - bf2f(hh2));
      }
  __syncthreads();
#pragma unroll
  for (int sb = 0; sb < 4; ++sb) {
    const int L = t * 16;
    const int x6 = ((L >> 6) ^ (L >> 8)) & 1;
    const int x5 = ((L >> 5) ^ (L >> 7)) & 1;
    const int x4 = ((L >> 4) ^ (L >> 6) ^ (L >> 8)) & 1;
    const int X = (L & ~0x70) | (x6 << 6) | (x5 << 5) | (x4 << 4);
    const int row = X >> 6;
    const int cl = sb * 32 + ((X & 63) >> 1);
    uint4 v = *(const uint4*)(ldsT + row * 136 + cl);
    *(uint4*)((char*)outLo + (size_t)Tm * 262144 +
              (size_t)(Tn * 4 + sb) * 8192 + L) = v;
  }
}

// ---------------------------------------------------------------------------
// k_scores_mfma: scores = proj @ words^T (split-bf16 3-term), f32 -> ws.
// (unchanged, verified round 10)
// ---------------------------------------------------------------------------
__global__ __launch_bounds__(512) void k_scores_mfma(
    const unsigned short* __restrict__ pHi, const unsigned short* __restrict__ pLo,
    const float* __restrict__ words, float* __restrict__ sc) {
  __shared__ uint4 lds4[10240];  // 160KB
  char* pAhi_c = (char*)lds4;             // 32KB: [4 tiles][8KB swz64x]
  char* pAlo_c = (char*)lds4 + 32768;
  char* pAhi_n = (char*)lds4 + 65536;
  char* pAlo_n = (char*)lds4 + 98304;
  char* pBhi_c = (char*)lds4 + 131072;    // 8KB: [128 n][64B swz64x]
  char* pBlo_c = (char*)lds4 + 139264;
  char* pBhi_n = (char*)lds4 + 147456;
  char* pBlo_n = (char*)lds4 + 155648;

  const int g = blockIdx.x;
  const int b = (g & 7) + 8 * (g >> 7);   // XCD-pinned batch (bijective)
  const int n0 = ((g >> 3) & 15) * 128;

  const int t = threadIdx.x, l = t & 63, wv = t >> 6;
  const int wm4 = wv >> 1;    // 0..3 -> m tile (128 rows each)
  const int wn2 = wv & 1;     // 0..1 -> n base local = wn2*64

  f32x4 acc[8][4];
#pragma unroll
  for (int i = 0; i < 8; ++i)
#pragma unroll
    for (int j = 0; j < 4; ++j) acc[i][j] = (f32x4){0.f, 0.f, 0.f, 0.f};

  f32x4 br0, br1;
  const int bn = t >> 2;          // B n-row 0..127
  const int bc = (t & 3) * 8;     // f32 col base within 32

  auto dma_A = [&](int s, char* pH, char* pL) {
#pragma unroll
    for (int j = 0; j < 4; ++j) {
      const size_t gb = (size_t)(b * 4 + j) * 262144 + (size_t)s * 8192 +
                        wv * 1024 + l * 16;
      gload_lds16((const char*)pHi + gb, pH + j * 8192 + wv * 1024);
      gload_lds16((const char*)pLo + gb, pL + j * 8192 + wv * 1024);
    }
  };

  auto load_B = [&](int s) {
    const float* bs = words + (size_t)b * WN * D_ + (size_t)(n0 + bn) * 1024 +
                      s * 32 + bc;
    br0 = *(const f32x4*)(bs);
    br1 = *(const f32x4*)(bs + 4);
  };

  auto write_B = [&](char* pH, char* pL) {
    unsigned short hB[8], lB[8];
#pragma unroll
    for (int j = 0; j < 4; ++j) {
      float y0 = br0[j];
      unsigned short h0 = f2bf(y0);
      hB[j] = h0;
      lB[j] = f2bf(y0 - bf2f(h0));
      float y1 = br1[j];
      unsigned short h1 = f2bf(y1);
      hB[4 + j] = h1;
      lB[4 + j] = f2bf(y1 - bf2f(h1));
    }
    const int o = swz64x(bn, (t & 3) * 16);
    *(uint4*)(pH + o) = pack8(hB[0], hB[1], hB[2], hB[3], hB[4], hB[5], hB[6], hB[7]);
    *(uint4*)(pL + o) = pack8(lB[0], lB[1], lB[2], lB[3], lB[4], lB[5], lB[6], lB[7]);
  };

  auto compute_stage = [&](const char* pAh, const char* pAl,
                           const char* pBh, const char* pBl) {
    const int kb0 = (l >> 4) * 16;
    short8 bh[4], bl[4];
#pragma unroll
    for (int f = 0; f < 4; ++f) {
      const int n = wn2 * 64 + f * 16 + (l & 15);
      const int o = swz64x(n, kb0);
      bh[f] = *(const short8*)(pBh + o);
      bl[f] = *(const short8*)(pBl + o);
    }
#pragma unroll
    for (int fm = 0; fm < 8; ++fm) {
      const int row = fm * 16 + (l & 15);
      const int oa = wm4 * 8192 + swz64x(row, kb0);
      const short8 ah = *(const short8*)(pAh + oa);
      const short8 al = *(const short8*)(pAl + oa);
#pragma unroll
      for (int fn = 0; fn < 4; ++fn) {
        acc[fm][fn] = __builtin_amdgcn_mfma_f32_16x16x32_bf16(ah, bh[fn], acc[fm][fn], 0, 0, 0);
        acc[fm][fn] = __builtin_amdgcn_mfma_f32_16x16x32_bf16(al, bh[fn], acc[fm][fn], 0, 0, 0);
        acc[fm][fn] = __builtin_amdgcn_mfma_f32_16x16x32_bf16(ah, bl[fn], acc[fm][fn], 0, 0, 0);
      }
    }
  };

  // prologue
  load_B(0);
  dma_A(0, pAhi_c, pAlo_c);
  write_B(pBhi_c, pBlo_c);
  __syncthreads();

  for (int s = 0; s < 32; ++s) {
    if (s < 31) {
      load_B(s + 1);
      dma_A(s + 1, pAhi_n, pAlo_n);
    }
    compute_stage(pAhi_c, pAlo_c, pBhi_c, pBlo_c);
    if (s < 31) write_B(pBhi_n, pBlo_n);
    __syncthreads();  // drains DMA (vmcnt) + ds_writes (lgkm)
    char* x;
    x = pAhi_c; pAhi_c = pAhi_n; pAhi_n = x;
    x = pAlo_c; pAlo_c = pAlo_n; pAlo_n = x;
    x = pBhi_c; pBhi_c = pBhi_n; pBhi_n = x;
    x = pBlo_c; pBlo_c = pBlo_n; pBlo_n = x;
  }

  // store f32 scores
#pragma unroll
  for (int fm = 0; fm < 8; ++fm)
#pragma unroll
    for (int fn = 0; fn < 4; ++fn)
#pragma unroll
      for (int q = 0; q < 4; ++q) {
        const int row = wm4 * 128 + fm * 16 + (l >> 4) * 4 + q;
        const int col = n0 + wn2 * 64 + fn * 16 + (l & 15);
        sc[((size_t)b * 512 + row) * 2048 + col] = acc[fm][fn][q];
      }
}

// ---------------------------------------------------------------------------
// k_softmax: reads f32 scores from ws, writes bf16 att in BLOB layout to
// d_out (unchanged, verified round 9/10).
// ---------------------------------------------------------------------------
__global__ __launch_bounds__(256) void k_softmax(const float* __restrict__ ws,
                                                 const void* __restrict__ mask,
                                                 unsigned short* __restrict__ blob) {
  __shared__ float red[8];
  const int row = blockIdx.x;
  const int t = threadIdx.x;
  const int wave = t >> 6;
  const float* rp = ws + (size_t)row * 2048;
  float v[8];
  {
    f32x4 v0 = *(const f32x4*)(rp + t * 8);
    f32x4 v1 = *(const f32x4*)(rp + t * 8 + 4);
#pragma unroll
    for (int i = 0; i < 4; ++i) { v[i] = v0[i]; v[4 + i] = v1[i]; }
  }
  if (g_mask_is_int) {
    const int* mp = (const int*)mask + (size_t)row * 2048 + t * 8;
    const int4 m0 = *(const int4*)mp;
    const int4 m1 = *(const int4*)(mp + 4);
    if (m0.x) v[0] = -INFINITY;
    if (m0.y) v[1] = -INFINITY;
    if (m0.z) v[2] = -INFINITY;
    if (m0.w) v[3] = -INFINITY;
    if (m1.x) v[4] = -INFINITY;
    if (m1.y) v[5] = -INFINITY;
    if (m1.z) v[6] = -INFINITY;
    if (m1.w) v[7] = -INFINITY;
  } else {
    const unsigned char* mp = (const unsigned char*)mask + (size_t)row * 2048 + t * 8;
    const uchar4 m0 = *(const uchar4*)mp;
    const uchar4 m1 = *(const uchar4*)(mp + 4);
    if (m0.x) v[0] = -INFINITY;
    if (m0.y) v[1] = -INFINITY;
    if (m0.z) v[2] = -INFINITY;
    if (m0.w) v[3] = -INFINITY;
    if (m1.x) v[4] = -INFINITY;
    if (m1.y) v[5] = -INFINITY;
    if (m1.z) v[6] = -INFINITY;
    if (m1.w) v[7] = -INFINITY;
  }
  float mx = v[0];
#pragma unroll
  for (int i = 1; i < 8; ++i) mx = fmaxf(mx, v[i]);
#pragma unroll
  for (int off = 32; off > 0; off >>= 1) mx = fmaxf(mx, __shfl_xor(mx, off));
  if ((t & 63) == 0) red[wave] = mx;
  __syncthreads();
  mx = fmaxf(fmaxf(red[0], red[1]), fmaxf(red[2], red[3]));
  float e[8];
  float sum = 0.0f;
#pragma unroll
  for (int i = 0; i < 8; ++i) {
    e[i] = __expf(v[i] - mx);
    sum += e[i];
  }
#pragma unroll
  for (int off = 32; off > 0; off >>= 1) sum += __shfl_xor(sum, off);
  if ((t & 63) == 0) red[4 + wave] = sum;
  __syncthreads();
  const float tot = (red[4] + red[5]) + (red[6] + red[7]);
  const float rinv = 1.0f / tot;

  const int b = row >> 9, ee = row & 511;
  const uint4 pk = pack8(f2bf(e[0] * rinv), f2bf(e[1] * rinv),
                         f2bf(e[2] * rinv), f2bf(e[3] * rinv),
                         f2bf(e[4] * rinv), f2bf(e[5] * rinv),
                         f2bf(e[6] * rinv), f2bf(e[7] * rinv));
  char* dst = (char*)blob + (size_t)b * 2097152 + (size_t)(t >> 3) * 65536 +
              ee * 128 + (((t & 7) * 16) ^ ((ee & 7) << 4));
  *(uint4*)dst = pk;
}

// ---------------------------------------------------------------------------
// k_pv: ctx = att @ words (unchanged, verified round 9).
// ---------------------------------------------------------------------------
__global__ __launch_bounds__(512) void k_pv(
    const unsigned short* __restrict__ blob, const float* __restrict__ words,
    float* __restrict__ ctx) {
  __shared__ uint4 lds4[10240];           // 160KB: A0 64K | A1 64K | B0 16K | B1 16K
  char* pAc = (char*)lds4;
  char* pAn = (char*)lds4 + 65536;
  char* pBc = (char*)lds4 + 131072;
  char* pBn = (char*)lds4 + 147456;

  const int g = blockIdx.x;
  const int b = (g & 7) + 8 * (g >> 6);   // XCD-pinned batch
  const int wt = (g >> 3) & 7;
  const int w0 = wt * 128;

  const int t = threadIdx.x, l = t & 63, wv = t >> 6;
  const int wm4 = wv >> 1;
  const int wn2 = wv & 1;

  const char* blobB = (const char*)blob + (size_t)b * 2097152;

  f32x4 acc[8][4];
#pragma unroll
  for (int i = 0; i < 8; ++i)
#pragma unroll
    for (int j = 0; j < 4; ++j) acc[i][j] = (f32x4){0.f, 0.f, 0.f, 0.f};

  f32x4 bv0a, bv0b, bv1a, bv1b;
  const int np2 = (t & 31) * 2;
  const int wc = (t >> 5) * 8;

  auto dma_A = [&](int s, char* pA) {
    const char* gp = blobB + (size_t)s * 65536 + wv * 8192 + l * 16;
#pragma unroll
    for (int j = 0; j < 8; ++j)
      gload_lds16(gp + j * 1024, pA + wv * 8192 + j * 1024);
  };

  auto load_B = [&](int s) {
    const float* wp = words + (size_t)b * WN * D_ +
                      (size_t)(s * 64 + np2) * 1024 + w0 + wc;
    bv0a = *(const f32x4*)(wp);
    bv0b = *(const f32x4*)(wp + 4);
    bv1a = *(const f32x4*)(wp + 1024);
    bv1b = *(const f32x4*)(wp + 1028);
  };

  auto write_B = [&](char* pB) {
#pragma unroll
    for (int i = 0; i < 8; ++i) {
      const int w = wc + i;
      const float x0 = (i < 4) ? bv0a[i & 3] : bv0b[i & 3];
      const float x1 = (i < 4) ? bv1a[i & 3] : bv1b[i & 3];
      const unsigned int pk =
          (unsigned int)f2bf(x0) | ((unsigned int)f2bf(x1) << 16);
      *(unsigned int*)(pB + w * 128 + ((np2 * 2) ^ ((w & 7) << 4))) = pk;
    }
  };

  auto compute_stage = [&](const char* pA, const char* pB) {
#pragma unroll
    for (int ks = 0; ks < 2; ++ks) {
      short8 a[8];
      const int kb = ks * 64 + (l >> 4) * 16;
#pragma unroll
      for (int f = 0; f < 8; ++f) {
        const int row = wm4 * 128 + f * 16 + (l & 15);
        a[f] = *(const short8*)(pA + swz(row, kb));
      }
      short8 bb[4];
#pragma unroll
      for (int f = 0; f < 4; ++f) {
        const int row = wn2 * 64 + f * 16 + (l & 15);
        bb[f] = *(const short8*)(pB + swz(row, kb));
      }
#pragma unroll
      for (int fm = 0; fm < 8; ++fm)
#pragma unroll
        for (int fn = 0; fn < 4; ++fn)
          acc[fm][fn] = __builtin_amdgcn_mfma_f32_16x16x32_bf16(a[fm], bb[fn], acc[fm][fn], 0, 0, 0);
    }
  };

  load_B(0);
  dma_A(0, pAc);
  write_B(pBc);
  __syncthreads();

  for (int s = 0; s < 32; ++s) {
    if (s < 31) {
      load_B(s + 1);
      dma_A(s + 1, pAn);
    }
    compute_stage(pAc, pBc);
    if (s < 31) write_B(pBn);
    __syncthreads();
    char* t1 = pAc; pAc = pAn; pAn = t1;
    char* t2 = pBc; pBc = pBn; pBn = t2;
  }

#pragma unroll
  for (int fm = 0; fm < 8; ++fm)
#pragma unroll
    for (int fn = 0; fn < 4; ++fn)
#pragma unroll
      for (int q = 0; q < 4; ++q) {
        const int row = wm4 * 128 + fm * 16 + (l >> 4) * 4 + q;
        const int col = w0 + wn2 * 64 + fn * 16 + (l & 15);
        ctx[((size_t)b * 512 + row) * 1024 + col] = acc[fm][fn][q];
      }
}

// ---------------------------------------------------------------------------
// k_copy: ctx (ws) -> d_out, float4 grid-stride.
// ---------------------------------------------------------------------------
__global__ __launch_bounds__(256) void k_copy(const float4* __restrict__ src,
                                              float4* __restrict__ dst) {
  const int n4 = 16384 * 1024 / 4;
  int i = blockIdx.x * 256 + threadIdx.x;
  const int stride = gridDim.x * 256;
  for (; i < n4; i += stride) dst[i] = src[i];
}

// ===========================================================================
// FALLBACK PATH (round-2 verified kernels; used if ws too small)
// ===========================================================================
__global__ __launch_bounds__(256, 4) void k_proj(const float* __restrict__ A,
                                                 const float* __restrict__ W,
                                                 const float* __restrict__ bias,
                                                 float* __restrict__ out) {
  __shared__ float As[32][132];
  __shared__ float Bs[32][132];
  const int t = threadIdx.x;
  const int m0 = blockIdx.x * 128;
  const int n0 = blockIdx.y * 128;
  const int tm = t >> 4;
  const int tn = t & 15;
  const int lrow = t >> 1;
  const int lk = (t & 1) * 16;

  float acc[8][8];
#pragma unroll
  for (int i = 0; i < 8; ++i)
#pragma unroll
    for (int j = 0; j < 8; ++j) acc[i][j] = 0.0f;

  const float* Arow = A + (size_t)(m0 + lrow) * D_ + lk;
  const float* Wrow = W + (size_t)(n0 + lrow) * D_ + lk;

  for (int k0 = 0; k0 < D_; k0 += 32) {
    __syncthreads();
#pragma unroll
    for (int j = 0; j < 4; ++j) {
      const float4 va = *(const float4*)(Arow + k0 + j * 4);
      As[lk + j * 4 + 0][lrow] = va.x;
      As[lk + j * 4 + 1][lrow] = va.y;
      As[lk + j * 4 + 2][lrow] = va.z;
      As[lk + j * 4 + 3][lrow] = va.w;
      const float4 vb = *(const float4*)(Wrow + k0 + j * 4);
      Bs[lk + j * 4 + 0][lrow] = vb.x;
      Bs[lk + j * 4 + 1][lrow] = vb.y;
      Bs[lk + j * 4 + 2][lrow] = vb.z;
      Bs[lk + j * 4 + 3][lrow] = vb.w;
    }
    __syncthreads();
#pragma unroll 8
    for (int k = 0; k < 32; ++k) {
      float a[8], bb[8];
      *(float4*)(a + 0) = *(const float4*)&As[k][tm * 4];
      *(float4*)(a + 4) = *(const float4*)&As[k][tm * 4 + 64];
      *(float4*)(bb + 0) = *(const float4*)&Bs[k][tn * 4];
      *(float4*)(bb + 4) = *(const float4*)&Bs[k][tn * 4 + 64];
#pragma unroll
      for (int i = 0; i < 8; ++i)
#pragma unroll
        for (int j = 0; j < 8; ++j) acc[i][j] = fmaf(a[i], bb[j], acc[i][j]);
    }
  }

  float bn[8];
#pragma unroll
  for (int j = 0; j < 8; ++j) bn[j] = bias[n0 + tn * 4 + (j & 3) + (j >> 2) * 64];
#pragma unroll
  for (int i = 0; i < 8; ++i) {
    const int m = m0 + tm * 4 + (i & 3) + (i >> 2) * 64;
    float4 v0, v1;
    v0.x = tanhf(acc[i][0] + bn[0]);
    v0.y = tanhf(acc[i][1] + bn[1]);
    v0.z = tanhf(acc[i][2] + bn[2]);
    v0.w = tanhf(acc[i][3] + bn[3]);
    v1.x = tanhf(acc[i][4] + bn[4]);
    v1.y = tanhf(acc[i][5] + bn[5]);
    v1.z = tanhf(acc[i][6] + bn[6]);
    v1.w = tanhf(acc[i][7] + bn[7]);
    *(float4*)(out + (size_t)m * D_ + n0 + tn * 4) = v0;
    *(float4*)(out + (size_t)m * D_ + n0 + tn * 4 + 64) = v1;
  }
}

__global__ __launch_bounds__(256) void k_scores(const float* __restrict__ words,
                                                const void* __restrict__ mask,
                                                float* __restrict__ pa) {
  __shared__ float Pt[1024][18];
  __shared__ float Ws[64][268];
  const int t = threadIdx.x;
  const int b = blockIdx.x >> 5;
  const int et = blockIdx.x & 31;
  const int e0 = et * 16;
  const int eg = t >> 5;
  const int ng = t & 31;
  const int mask_is_int = g_mask_is_int;
  const float* wbase = words + (size_t)b * WN * D_;

  {
    const int row = t >> 4;
    const int dj = (t & 15) * 4;
    const float* pr = pa + (size_t)(b * E_ + e0 + row) * D_;
#pragma unroll
    for (int rr = 0; rr < 16; ++rr) {
      const float4 v = *(const float4*)(pr + dj + rr * 64);
      Pt[dj + rr * 64 + 0][row] = v.x;
      Pt[dj + rr * 64 + 1][row] = v.y;
      Pt[dj + rr * 64 + 2][row] = v.z;
      Pt[dj + rr * 64 + 3][row] = v.w;
    }
  }

  float s[2][64];
#pragma unroll
  for (int i = 0; i < 2; ++i)
#pragma unroll
    for (int u = 0; u < 64; ++u) s[i][u] = 0.0f;

  const int nl = t >> 3;
  const int d4 = (t & 7) * 4;

  for (int dk = 0; dk < D_; dk += 64) {
#pragma unroll
    for (int nb = 0; nb < 8; ++nb) {
      __syncthreads();
#pragma unroll
      for (int rr = 0; rr < 8; ++rr) {
#pragma unroll
        for (int hh = 0; hh < 2; ++hh) {
          const int n = nl + rr * 32;
          const int d = d4 + hh * 32;
          const float4 v = *(const float4*)(wbase + (size_t)(nb * 256 + n) * D_ + dk + d);
          Ws[d + 0][n] = v.x;
          Ws[d + 1][n] = v.y;
          Ws[d + 2][n] = v.z;
          Ws[d + 3][n] = v.w;
        }
      }
      __syncthreads();
#pragma unroll 2
      for (int k = 0; k < 64; ++k) {
        const float2 a = *(const float2*)&Pt[dk + k][eg * 2];
        const float4 b0 = *(const float4*)&Ws[k][ng * 4];
        const float4 b1 = *(const float4*)&Ws[k][128 + ng * 4];
        const float aa[2] = {a.x, a.y};
        const float bb[8] = {b0.x, b0.y, b0.z, b0.w, b1.x, b1.y, b1.z, b1.w};
#pragma unroll
        for (int i = 0; i < 2; ++i)
#pragma unroll
          for (int u = 0; u < 8; ++u)
            s[i][nb * 8 + u] = fmaf(aa[i], bb[u], s[i][nb * 8 + u]);
      }
    }
  }

#pragma unroll
  for (int i = 0; i < 2; ++i) {
    const int e = e0 + eg * 2 + i;
#pragma unroll
    for (int nb = 0; nb < 8; ++nb)
#pragma unroll
      for (int q = 0; q < 2; ++q) {
        const size_t moff = (size_t)(b * E_ + e) * WN + nb * 256 + q * 128 + ng * 4;
        int mx, my, mz, mw;
        if (mask_is_int) {
          const int4 mv = *(const int4*)((const int*)mask + moff);
          mx = mv.x; my = mv.y; mz = mv.z; mw = mv.w;
        } else {
          const uchar4 mv = *(const uchar4*)((const unsigned char*)mask + moff);
          mx = mv.x; my = mv.y; mz = mv.z; mw = mv.w;
        }
        if (mx) s[i][nb * 8 + q * 4 + 0] = -1e30f;
        if (my) s[i][nb * 8 + q * 4 + 1] = -1e30f;
        if (mz) s[i][nb * 8 + q * 4 + 2] = -1e30f;
        if (mw) s[i][nb * 8 + q * 4 + 3] = -1e30f;
      }
    float m = -1e30f;
#pragma unroll
    for (int u = 0; u < 64; ++u) m = fmaxf(m, s[i][u]);
#pragma unroll
    for (int off = 16; off > 0; off >>= 1) m = fmaxf(m, __shfl_xor(m, off));
    float sum = 0.0f;
#pragma unroll
    for (int u = 0; u < 64; ++u) {
      const float p = __expf(s[i][u] - m);
      s[i][u] = p;
      sum += p;
    }
#pragma unroll
    for (int off = 16; off > 0; off >>= 1) sum += __shfl_xor(sum, off);
    const float rinv = 1.0f / sum;

    unsigned short* ar2 = (unsigned short*)(pa + (size_t)(b * E_ + e) * WN / 2);
#pragma unroll
    for (int nb = 0; nb < 8; ++nb)
#pragma unroll
      for (int q = 0; q < 2; ++q) {
        ushort4 pk;
        pk.x = f2bf(s[i][nb * 8 + q * 4 + 0] * rinv);
        pk.y = f2bf(s[i][nb * 8 + q * 4 + 1] * rinv);
        pk.z = f2bf(s[i][nb * 8 + q * 4 + 2] * rinv);
        pk.w = f2bf(s[i][nb * 8 + q * 4 + 3] * rinv);
        *(ushort4*)(ar2 + nb * 256 + q * 128 + ng * 4) = pk;
      }
  }
}

__global__ __launch_bounds__(256) void k_ctx(const float* __restrict__ words,
                                             float* __restrict__ pa) {
  __shared__ unsigned short att_s[16][2048];
  __shared__ unsigned short Wb[256][132];
  const int t = threadIdx.x;
  const int b = blockIdx.x >> 5;
  const int et = blockIdx.x & 31;
  const int e0 = et * 16;
  const int eg = t >> 5;
  const int wg = t & 31;
  const float* wbase = words + (size_t)b * WN * D_;

  {
    const int row = t >> 4;
    const int cj = t & 15;
    const uint4* pr = (const uint4*)(pa + (size_t)(b * E_ + e0 + row) * D_);
#pragma unroll
    for (int rr = 0; rr < 16; ++rr) {
      const int c = cj + rr * 16;
      const uint4 v = pr[c];
      *(uint4*)&att_s[row][c * 8] = v;
    }
  }

  float acc[2][32];
#pragma unroll
  for (int i = 0; i < 2; ++i)
#pragma unroll
    for (int u = 0; u < 32; ++u) acc[i][u] = 0.0f;

  const int nlg = t >> 5;
  const int w4 = (t & 31) * 4;

  for (int nb = 0; nb < 8; ++nb) {
#pragma unroll
    for (int q = 0; q < 8; ++q) {
      __syncthreads();
#pragma unroll
      for (int rr = 0; rr < 32; ++rr) {
        const int n = nlg + rr * 8;
        const float4 v = *(const float4*)(wbase + (size_t)(nb * 256 + n) * D_ + q * 128 + w4);
        ushort4 pk;
        pk.x = f2bf(v.x);
        pk.y = f2bf(v.y);
        pk.z = f2bf(v.z);
        pk.w = f2bf(v.w);
        *(ushort4*)&Wb[n][w4] = pk;
      }
      __syncthreads();
#pragma unroll 4
      for (int n2 = 0; n2 < 128; ++n2) {
        const int n = n2 * 2;
        const ushort4 r0 = *(const ushort4*)&Wb[n][wg * 4];
        const ushort4 r1 = *(const ushort4*)&Wb[n + 1][wg * 4];
        const float w0[4] = {bf2f(r0.x), bf2f(r0.y), bf2f(r0.z), bf2f(r0.w)};
        const float w1[4] = {bf2f(r1.x), bf2f(r1.y), bf2f(r1.z), bf2f(r1.w)};
#pragma unroll
        for (int i = 0; i < 2; ++i) {
          const unsigned int aw = *(const unsigned int*)&att_s[eg * 2 + i][nb * 256 + n];
          const float a0 = bf2f((unsigned short)(aw & 0xffffu));
          const float a1 = bf2f((unsigned short)(aw >> 16));
#pragma unroll
          for (int j = 0; j < 4; ++j)
            acc[i][q * 4 + j] = fmaf(a0, w0[j], fmaf(a1, w1[j], acc[i][q * 4 + j]));
        }
      }
    }
  }

#pragma unroll
  for (int i = 0; i < 2; ++i) {
    float* orow = pa + (size_t)(b * E_ + e0 + eg * 2 + i) * D_;
#pragma unroll
    for (int q = 0; q < 8; ++q) {
      float4 v;
      v.x = acc[i][q * 4 + 0];
      v.y = acc[i][q * 4 + 1];
      v.z = acc[i][q * 4 + 2];
      v.w = acc[i][q * 4 + 3];
      *(float4*)(orow + q * 128 + wg * 4) = v;
    }
  }
}

extern "C" void kernel_launch(void* const* d_in, const int* in_sizes, int n_in,
                              void* d_out, int out_size, void* d_ws, size_t ws_size,
                              hipStream_t stream) {
  const float* ems = (const float*)d_in[0];
  const float* words = (const float*)d_in[1];
  const void* mask = d_in[2];
  const float* w_weight = (const float*)d_in[3];
  const float* w_bias = (const float*)d_in[4];

  k_detect<<<1, 64, 0, stream>>>((const unsigned char*)mask);

  const size_t ws_need = (size_t)16384 * 2048 * 4;
  if (ws_size >= ws_need) {
    unsigned short* hiP = (unsigned short*)d_out;
    unsigned short* loP = hiP + (size_t)16384 * 1024;
    float* ws = (float*)d_ws;
    // ws scratch layout during proj phase (dead before k_scores overwrites):
    unsigned short* eHi = (unsigned short*)d_ws;                    // 32MB
    unsigned short* eLo = eHi + (size_t)16384 * 1024;               // 32MB
    unsigned short* wHi = eLo + (size_t)16384 * 1024;               // 2MB
    unsigned short* wLo = wHi + (size_t)1024 * 1024;                // 2MB
    // 0. pre-split ems (128 tiles) and W (8 tiles) into swizzled blobs
    k_split<<<dim3(2048), 256, 0, stream>>>(ems, eHi, eLo);
    k_split<<<dim3(128), 256, 0, stream>>>(w_weight, wHi, wLo);
    // 1. proj (pure-DMA dbuf) -> proj planes (32k-stage blob) in d_out
    k_proj_dma<<<dim3(1024), 512, 0, stream>>>(eHi, eLo, wHi, wLo, w_bias,
                                               hiP, loP);
    // 2. scores (f32) -> ws (overwrites ems/W blobs; they're dead)
    k_scores_mfma<<<dim3(512), 512, 0, stream>>>(hiP, loP, words, ws);
    // 3. softmax: ws scores -> att blob in d_out (planes dead)
    k_softmax<<<dim3(16384), 256, 0, stream>>>(ws, mask, (unsigned short*)d_out);
    // 4. pv: att blob (d_out) @ words -> ctx in ws (scores dead)
    k_pv<<<dim3(256), 512, 0, stream>>>((const unsigned short*)d_out, words, ws);
    // 5. ctx ws -> d_out
    k_copy<<<dim3(2048), 256, 0, stream>>>((const float4*)d_ws, (float4*)d_out);
  } else {
    float* out = (float*)d_out;
    k_proj<<<dim3(128, 8), 256, 0, stream>>>(ems, w_weight, w_bias, out);
    k_scores<<<dim3(B_ * (E_ / 16)), 256, 0, stream>>>(words, mask, out);
    k_ctx<<<dim3(B_ * (E_ / 16)), 256, 0, stream>>>(words, out);
  }
}